// Round 13
// baseline (1867.513 us; speedup 1.0000x reference)
//
#include <hip/hip_runtime.h>

#define B_   8
#define N_   1024
#define C_   768
#define H_   12
#define HD_  64
#define BH_  96
#define SCALE_ 0.125f
#define NIT_ 5

typedef __attribute__((ext_vector_type(8))) short bfrag;   // 8 bf16 (4 VGPR)
typedef __attribute__((ext_vector_type(4))) float facc;    // 4 f32  (4 VGPR)

__device__ __forceinline__ unsigned short bfhi(float x)
{
    return (unsigned short)(__float_as_uint(x) >> 16);
}
__device__ __forceinline__ unsigned short bflo(float x)
{
    const unsigned hu = __float_as_uint(x) & 0xffff0000u;
    return (unsigned short)(__float_as_uint(x - __uint_as_float(hu)) >> 16);
}
__device__ __forceinline__ unsigned int packhl(float v)
{
    return (unsigned int)bfhi(v) | ((unsigned int)bflo(v) << 16);
}
__device__ __forceinline__ bfrag pack_hi(float4 a, float4 b)
{
    bfrag r;
    r[0] = (short)bfhi(a.x); r[1] = (short)bfhi(a.y);
    r[2] = (short)bfhi(a.z); r[3] = (short)bfhi(a.w);
    r[4] = (short)bfhi(b.x); r[5] = (short)bfhi(b.y);
    r[6] = (short)bfhi(b.z); r[7] = (short)bfhi(b.w);
    return r;
}
__device__ __forceinline__ bfrag pack_lo(float4 a, float4 b)
{
    bfrag r;
    r[0] = (short)bflo(a.x); r[1] = (short)bflo(a.y);
    r[2] = (short)bflo(a.z); r[3] = (short)bflo(a.w);
    r[4] = (short)bflo(b.x); r[5] = (short)bflo(b.y);
    r[6] = (short)bflo(b.z); r[7] = (short)bflo(b.w);
    return r;
}

// ---------------------------------------------------------------------------
// split_flat: fp32 array -> bf16 hi/lo arrays, same layout.  grid 3072 x 256.
// ---------------------------------------------------------------------------
__global__ __launch_bounds__(256)
void split_flat(const float* __restrict__ In,
                unsigned short* __restrict__ Oh, unsigned short* __restrict__ Ol)
{
    const size_t i = ((size_t)blockIdx.x * 256 + threadIdx.x) * 8;
    const float4 a = *(const float4*)(In + i);
    const float4 b = *(const float4*)(In + i + 4);
    *(bfrag*)(Oh + i) = pack_hi(a, b);
    *(bfrag*)(Ol + i) = pack_lo(a, b);
}

// ---------------------------------------------------------------------------
// split_wt: W [768][ncols] fp32 -> Wt hi/lo [ncols][768] bf16 (transposed).
// grid (ncols/64, 768/64=12) x 256.  Run once per weight.
// ---------------------------------------------------------------------------
__global__ __launch_bounds__(256)
void split_wt(const float* __restrict__ W, int ncols,
              unsigned short* __restrict__ Th, unsigned short* __restrict__ Tl)
{
    __shared__ float Ts[64][68];
    const int tid = threadIdx.x;
    const int c0 = blockIdx.x * 64;
    const int k0 = blockIdx.y * 64;

    {
        int e = tid;
#pragma unroll
        for (int t = 0; t < 4; ++t, e += 256) {
            const int r = e >> 4, c4 = (e & 15) << 2;
            *(float4*)&Ts[r][c4] =
                *(const float4*)(W + (size_t)(k0 + r) * ncols + c0 + c4);
        }
    }
    __syncthreads();

#pragma unroll
    for (int t = 0; t < 2; ++t) {
        const int idx = t * 2048 + tid * 8;
        const int cr = idx >> 6, ck = idx & 63;
        bfrag h8, l8;
#pragma unroll
        for (int q = 0; q < 8; ++q) {
            const float v = Ts[ck + q][cr];
            h8[q] = (short)bfhi(v);
            l8[q] = (short)bflo(v);
        }
        const size_t go = (size_t)(c0 + cr) * 768 + k0 + ck;
        *(bfrag*)(Th + go) = h8;
        *(bfrag*)(Tl + go) = l8;
    }
}

// ---------------------------------------------------------------------------
// K1 qkv_mfma (unchanged, verified).
// ---------------------------------------------------------------------------
__global__ __launch_bounds__(256)
void qkv_mfma(const unsigned short* __restrict__ Xh, const unsigned short* __restrict__ Xl,
              const unsigned short* __restrict__ Wth, const unsigned short* __restrict__ Wtl,
              const float* __restrict__ bias,
              float* __restrict__ Kb, float* __restrict__ Vb)
{
    __shared__ short Ahs[64][72];
    __shared__ short Als[64][72];
    __shared__ short Bhs[64][72];
    __shared__ short Bls[64][72];

    const int tid  = threadIdx.x;
    const int lane = tid & 63;
    const int w    = tid >> 6;
    const int g    = lane >> 4;
    const int r16  = lane & 15;
    const int m0   = blockIdx.y * 64;
    const int c0   = blockIdx.x * 64;     // [0,1536)

    facc o0 = {0.f, 0.f, 0.f, 0.f};
    facc o1 = {0.f, 0.f, 0.f, 0.f};
    facc o2 = {0.f, 0.f, 0.f, 0.f};
    facc o3 = {0.f, 0.f, 0.f, 0.f};

    const int i0 = tid * 8,        r0 = i0 >> 6, cc0 = i0 & 63;
    const int i1 = 2048 + tid * 8, r1 = i1 >> 6, cc1 = i1 & 63;

    bfrag ta0 = *(const bfrag*)(Xh + (size_t)(m0 + r0) * 768 + cc0);
    bfrag ta1 = *(const bfrag*)(Xh + (size_t)(m0 + r1) * 768 + cc1);
    bfrag tb0 = *(const bfrag*)(Xl + (size_t)(m0 + r0) * 768 + cc0);
    bfrag tb1 = *(const bfrag*)(Xl + (size_t)(m0 + r1) * 768 + cc1);
    bfrag tw0 = *(const bfrag*)(Wth + (size_t)(c0 + r0) * 768 + cc0);
    bfrag tw1 = *(const bfrag*)(Wth + (size_t)(c0 + r1) * 768 + cc1);
    bfrag tz0 = *(const bfrag*)(Wtl + (size_t)(c0 + r0) * 768 + cc0);
    bfrag tz1 = *(const bfrag*)(Wtl + (size_t)(c0 + r1) * 768 + cc1);

    for (int ks = 0; ks < 12; ++ks) {
        __syncthreads();
        *(bfrag*)&Ahs[r0][cc0] = ta0;  *(bfrag*)&Ahs[r1][cc1] = ta1;
        *(bfrag*)&Als[r0][cc0] = tb0;  *(bfrag*)&Als[r1][cc1] = tb1;
        *(bfrag*)&Bhs[r0][cc0] = tw0;  *(bfrag*)&Bhs[r1][cc1] = tw1;
        *(bfrag*)&Bls[r0][cc0] = tz0;  *(bfrag*)&Bls[r1][cc1] = tz1;
        if (ks + 1 < 12) {
            const int kn = (ks + 1) * 64;
            ta0 = *(const bfrag*)(Xh + (size_t)(m0 + r0) * 768 + kn + cc0);
            ta1 = *(const bfrag*)(Xh + (size_t)(m0 + r1) * 768 + kn + cc1);
            tb0 = *(const bfrag*)(Xl + (size_t)(m0 + r0) * 768 + kn + cc0);
            tb1 = *(const bfrag*)(Xl + (size_t)(m0 + r1) * 768 + kn + cc1);
            tw0 = *(const bfrag*)(Wth + (size_t)(c0 + r0) * 768 + kn + cc0);
            tw1 = *(const bfrag*)(Wth + (size_t)(c0 + r1) * 768 + kn + cc1);
            tz0 = *(const bfrag*)(Wtl + (size_t)(c0 + r0) * 768 + kn + cc0);
            tz1 = *(const bfrag*)(Wtl + (size_t)(c0 + r1) * 768 + kn + cc1);
        }
        __syncthreads();

        const bfrag ah0 = *(const bfrag*)&Ahs[16 * w + r16][8 * g];
        const bfrag ah1 = *(const bfrag*)&Ahs[16 * w + r16][32 + 8 * g];
        const bfrag al0 = *(const bfrag*)&Als[16 * w + r16][8 * g];
        const bfrag al1 = *(const bfrag*)&Als[16 * w + r16][32 + 8 * g];
        {
            bfrag b0 = *(const bfrag*)&Bhs[r16][8 * g];
            bfrag b1 = *(const bfrag*)&Bhs[r16][32 + 8 * g];
            bfrag c1 = *(const bfrag*)&Bls[r16][8 * g];
            bfrag c2 = *(const bfrag*)&Bls[r16][32 + 8 * g];
            o0 = __builtin_amdgcn_mfma_f32_16x16x32_bf16(ah0, b0, o0, 0, 0, 0);
            o0 = __builtin_amdgcn_mfma_f32_16x16x32_bf16(al0, b0, o0, 0, 0, 0);
            o0 = __builtin_amdgcn_mfma_f32_16x16x32_bf16(ah0, c1, o0, 0, 0, 0);
            o0 = __builtin_amdgcn_mfma_f32_16x16x32_bf16(ah1, b1, o0, 0, 0, 0);
            o0 = __builtin_amdgcn_mfma_f32_16x16x32_bf16(al1, b1, o0, 0, 0, 0);
            o0 = __builtin_amdgcn_mfma_f32_16x16x32_bf16(ah1, c2, o0, 0, 0, 0);
        }
        {
            bfrag b0 = *(const bfrag*)&Bhs[16 + r16][8 * g];
            bfrag b1 = *(const bfrag*)&Bhs[16 + r16][32 + 8 * g];
            bfrag c1 = *(const bfrag*)&Bls[16 + r16][8 * g];
            bfrag c2 = *(const bfrag*)&Bls[16 + r16][32 + 8 * g];
            o1 = __builtin_amdgcn_mfma_f32_16x16x32_bf16(ah0, b0, o1, 0, 0, 0);
            o1 = __builtin_amdgcn_mfma_f32_16x16x32_bf16(al0, b0, o1, 0, 0, 0);
            o1 = __builtin_amdgcn_mfma_f32_16x16x32_bf16(ah0, c1, o1, 0, 0, 0);
            o1 = __builtin_amdgcn_mfma_f32_16x16x32_bf16(ah1, b1, o1, 0, 0, 0);
            o1 = __builtin_amdgcn_mfma_f32_16x16x32_bf16(al1, b1, o1, 0, 0, 0);
            o1 = __builtin_amdgcn_mfma_f32_16x16x32_bf16(ah1, c2, o1, 0, 0, 0);
        }
        {
            bfrag b0 = *(const bfrag*)&Bhs[32 + r16][8 * g];
            bfrag b1 = *(const bfrag*)&Bhs[32 + r16][32 + 8 * g];
            bfrag c1 = *(const bfrag*)&Bls[32 + r16][8 * g];
            bfrag c2 = *(const bfrag*)&Bls[32 + r16][32 + 8 * g];
            o2 = __builtin_amdgcn_mfma_f32_16x16x32_bf16(ah0, b0, o2, 0, 0, 0);
            o2 = __builtin_amdgcn_mfma_f32_16x16x32_bf16(al0, b0, o2, 0, 0, 0);
            o2 = __builtin_amdgcn_mfma_f32_16x16x32_bf16(ah0, c1, o2, 0, 0, 0);
            o2 = __builtin_amdgcn_mfma_f32_16x16x32_bf16(ah1, b1, o2, 0, 0, 0);
            o2 = __builtin_amdgcn_mfma_f32_16x16x32_bf16(al1, b1, o2, 0, 0, 0);
            o2 = __builtin_amdgcn_mfma_f32_16x16x32_bf16(ah1, c2, o2, 0, 0, 0);
        }
        {
            bfrag b0 = *(const bfrag*)&Bhs[48 + r16][8 * g];
            bfrag b1 = *(const bfrag*)&Bhs[48 + r16][32 + 8 * g];
            bfrag c1 = *(const bfrag*)&Bls[48 + r16][8 * g];
            bfrag c2 = *(const bfrag*)&Bls[48 + r16][32 + 8 * g];
            o3 = __builtin_amdgcn_mfma_f32_16x16x32_bf16(ah0, b0, o3, 0, 0, 0);
            o3 = __builtin_amdgcn_mfma_f32_16x16x32_bf16(al0, b0, o3, 0, 0, 0);
            o3 = __builtin_amdgcn_mfma_f32_16x16x32_bf16(ah0, c1, o3, 0, 0, 0);
            o3 = __builtin_amdgcn_mfma_f32_16x16x32_bf16(ah1, b1, o3, 0, 0, 0);
            o3 = __builtin_amdgcn_mfma_f32_16x16x32_bf16(al1, b1, o3, 0, 0, 0);
            o3 = __builtin_amdgcn_mfma_f32_16x16x32_bf16(ah1, c2, o3, 0, 0, 0);
        }
    }

    const int h = (c0 % C_) >> 6;
    float* tgt = (c0 < C_) ? Kb : Vb;
    const float bb0 = bias[c0 + r16];
    const float bb1 = bias[c0 + 16 + r16];
    const float bb2 = bias[c0 + 32 + r16];
    const float bb3 = bias[c0 + 48 + r16];

    const int mrow = m0 + 16 * w + 4 * g;
    const int bidx = mrow >> 10;
    const int nidx = mrow & 1023;
    float* trow = tgt + ((size_t)(bidx * H_ + h) * N_ + nidx) * HD_ + r16;
    trow[0 * HD_ + 0]  = o0.x + bb0; trow[0 * HD_ + 16] = o1.x + bb1;
    trow[0 * HD_ + 32] = o2.x + bb2; trow[0 * HD_ + 48] = o3.x + bb3;
    trow[1 * HD_ + 0]  = o0.y + bb0; trow[1 * HD_ + 16] = o1.y + bb1;
    trow[1 * HD_ + 32] = o2.y + bb2; trow[1 * HD_ + 48] = o3.y + bb3;
    trow[2 * HD_ + 0]  = o0.z + bb0; trow[2 * HD_ + 16] = o1.z + bb1;
    trow[2 * HD_ + 32] = o2.z + bb2; trow[2 * HD_ + 48] = o3.z + bb3;
    trow[3 * HD_ + 0]  = o0.w + bb0; trow[3 * HD_ + 16] = o1.w + bb1;
    trow[3 * HD_ + 32] = o2.w + bb2; trow[3 * HD_ + 48] = o3.w + bb3;
}

// ---------------------------------------------------------------------------
// K7 proj_mfma (unchanged, verified).
// ---------------------------------------------------------------------------
__global__ __launch_bounds__(256)
void proj_mfma(const unsigned short* __restrict__ Lh, const unsigned short* __restrict__ Ll,
               const unsigned short* __restrict__ Wth, const unsigned short* __restrict__ Wtl,
               const float* __restrict__ bias, float* __restrict__ Out)
{
    __shared__ short Ahs[64][72];
    __shared__ short Als[64][72];
    __shared__ short Bhs[64][72];
    __shared__ short Bls[64][72];

    const int tid  = threadIdx.x;
    const int lane = tid & 63;
    const int w    = tid >> 6;
    const int g    = lane >> 4;
    const int r16  = lane & 15;
    const int m0   = blockIdx.y * 64;
    const int c0   = blockIdx.x * 64;     // [0,768)

    facc o0 = {0.f, 0.f, 0.f, 0.f};
    facc o1 = {0.f, 0.f, 0.f, 0.f};
    facc o2 = {0.f, 0.f, 0.f, 0.f};
    facc o3 = {0.f, 0.f, 0.f, 0.f};

    const int i0 = tid * 8,        r0 = i0 >> 6, cc0 = i0 & 63;
    const int i1 = 2048 + tid * 8, r1 = i1 >> 6, cc1 = i1 & 63;
    const int t0 = m0 + r0, ab0 = t0 >> 10, an0 = t0 & 1023;
    const int t1 = m0 + r1, ab1 = t1 >> 10, an1 = t1 & 1023;

    bfrag ta0 = *(const bfrag*)(Lh + ((size_t)(ab0 * H_) * N_ + an0) * HD_ + cc0);
    bfrag ta1 = *(const bfrag*)(Lh + ((size_t)(ab1 * H_) * N_ + an1) * HD_ + cc1);
    bfrag tb0 = *(const bfrag*)(Ll + ((size_t)(ab0 * H_) * N_ + an0) * HD_ + cc0);
    bfrag tb1 = *(const bfrag*)(Ll + ((size_t)(ab1 * H_) * N_ + an1) * HD_ + cc1);
    bfrag tw0 = *(const bfrag*)(Wth + (size_t)(c0 + r0) * 768 + cc0);
    bfrag tw1 = *(const bfrag*)(Wth + (size_t)(c0 + r1) * 768 + cc1);
    bfrag tz0 = *(const bfrag*)(Wtl + (size_t)(c0 + r0) * 768 + cc0);
    bfrag tz1 = *(const bfrag*)(Wtl + (size_t)(c0 + r1) * 768 + cc1);

    for (int ks = 0; ks < 12; ++ks) {
        __syncthreads();
        *(bfrag*)&Ahs[r0][cc0] = ta0;  *(bfrag*)&Ahs[r1][cc1] = ta1;
        *(bfrag*)&Als[r0][cc0] = tb0;  *(bfrag*)&Als[r1][cc1] = tb1;
        *(bfrag*)&Bhs[r0][cc0] = tw0;  *(bfrag*)&Bhs[r1][cc1] = tw1;
        *(bfrag*)&Bls[r0][cc0] = tz0;  *(bfrag*)&Bls[r1][cc1] = tz1;
        if (ks + 1 < 12) {
            const int kn = ks + 1;
            const size_t ga0 = ((size_t)(ab0 * H_ + kn) * N_ + an0) * HD_ + cc0;
            const size_t ga1 = ((size_t)(ab1 * H_ + kn) * N_ + an1) * HD_ + cc1;
            ta0 = *(const bfrag*)(Lh + ga0);
            ta1 = *(const bfrag*)(Lh + ga1);
            tb0 = *(const bfrag*)(Ll + ga0);
            tb1 = *(const bfrag*)(Ll + ga1);
            tw0 = *(const bfrag*)(Wth + (size_t)(c0 + r0) * 768 + kn * 64 + cc0);
            tw1 = *(const bfrag*)(Wth + (size_t)(c0 + r1) * 768 + kn * 64 + cc1);
            tz0 = *(const bfrag*)(Wtl + (size_t)(c0 + r0) * 768 + kn * 64 + cc0);
            tz1 = *(const bfrag*)(Wtl + (size_t)(c0 + r1) * 768 + kn * 64 + cc1);
        }
        __syncthreads();

        const bfrag ah0 = *(const bfrag*)&Ahs[16 * w + r16][8 * g];
        const bfrag ah1 = *(const bfrag*)&Ahs[16 * w + r16][32 + 8 * g];
        const bfrag al0 = *(const bfrag*)&Als[16 * w + r16][8 * g];
        const bfrag al1 = *(const bfrag*)&Als[16 * w + r16][32 + 8 * g];
        {
            bfrag b0 = *(const bfrag*)&Bhs[r16][8 * g];
            bfrag b1 = *(const bfrag*)&Bhs[r16][32 + 8 * g];
            bfrag c1 = *(const bfrag*)&Bls[r16][8 * g];
            bfrag c2 = *(const bfrag*)&Bls[r16][32 + 8 * g];
            o0 = __builtin_amdgcn_mfma_f32_16x16x32_bf16(ah0, b0, o0, 0, 0, 0);
            o0 = __builtin_amdgcn_mfma_f32_16x16x32_bf16(al0, b0, o0, 0, 0, 0);
            o0 = __builtin_amdgcn_mfma_f32_16x16x32_bf16(ah0, c1, o0, 0, 0, 0);
            o0 = __builtin_amdgcn_mfma_f32_16x16x32_bf16(ah1, b1, o0, 0, 0, 0);
            o0 = __builtin_amdgcn_mfma_f32_16x16x32_bf16(al1, b1, o0, 0, 0, 0);
            o0 = __builtin_amdgcn_mfma_f32_16x16x32_bf16(ah1, c2, o0, 0, 0, 0);
        }
        {
            bfrag b0 = *(const bfrag*)&Bhs[16 + r16][8 * g];
            bfrag b1 = *(const bfrag*)&Bhs[16 + r16][32 + 8 * g];
            bfrag c1 = *(const bfrag*)&Bls[16 + r16][8 * g];
            bfrag c2 = *(const bfrag*)&Bls[16 + r16][32 + 8 * g];
            o1 = __builtin_amdgcn_mfma_f32_16x16x32_bf16(ah0, b0, o1, 0, 0, 0);
            o1 = __builtin_amdgcn_mfma_f32_16x16x32_bf16(al0, b0, o1, 0, 0, 0);
            o1 = __builtin_amdgcn_mfma_f32_16x16x32_bf16(ah0, c1, o1, 0, 0, 0);
            o1 = __builtin_amdgcn_mfma_f32_16x16x32_bf16(ah1, b1, o1, 0, 0, 0);
            o1 = __builtin_amdgcn_mfma_f32_16x16x32_bf16(al1, b1, o1, 0, 0, 0);
            o1 = __builtin_amdgcn_mfma_f32_16x16x32_bf16(ah1, c2, o1, 0, 0, 0);
        }
        {
            bfrag b0 = *(const bfrag*)&Bhs[32 + r16][8 * g];
            bfrag b1 = *(const bfrag*)&Bhs[32 + r16][32 + 8 * g];
            bfrag c1 = *(const bfrag*)&Bls[32 + r16][8 * g];
            bfrag c2 = *(const bfrag*)&Bls[32 + r16][32 + 8 * g];
            o2 = __builtin_amdgcn_mfma_f32_16x16x32_bf16(ah0, b0, o2, 0, 0, 0);
            o2 = __builtin_amdgcn_mfma_f32_16x16x32_bf16(al0, b0, o2, 0, 0, 0);
            o2 = __builtin_amdgcn_mfma_f32_16x16x32_bf16(ah0, c1, o2, 0, 0, 0);
            o2 = __builtin_amdgcn_mfma_f32_16x16x32_bf16(ah1, b1, o2, 0, 0, 0);
            o2 = __builtin_amdgcn_mfma_f32_16x16x32_bf16(al1, b1, o2, 0, 0, 0);
            o2 = __builtin_amdgcn_mfma_f32_16x16x32_bf16(ah1, c2, o2, 0, 0, 0);
        }
        {
            bfrag b0 = *(const bfrag*)&Bhs[48 + r16][8 * g];
            bfrag b1 = *(const bfrag*)&Bhs[48 + r16][32 + 8 * g];
            bfrag c1 = *(const bfrag*)&Bls[48 + r16][8 * g];
            bfrag c2 = *(const bfrag*)&Bls[48 + r16][32 + 8 * g];
            o3 = __builtin_amdgcn_mfma_f32_16x16x32_bf16(ah0, b0, o3, 0, 0, 0);
            o3 = __builtin_amdgcn_mfma_f32_16x16x32_bf16(al0, b0, o3, 0, 0, 0);
            o3 = __builtin_amdgcn_mfma_f32_16x16x32_bf16(ah0, c1, o3, 0, 0, 0);
            o3 = __builtin_amdgcn_mfma_f32_16x16x32_bf16(ah1, b1, o3, 0, 0, 0);
            o3 = __builtin_amdgcn_mfma_f32_16x16x32_bf16(al1, b1, o3, 0, 0, 0);
            o3 = __builtin_amdgcn_mfma_f32_16x16x32_bf16(ah1, c2, o3, 0, 0, 0);
        }
    }

    const float bb0 = bias[c0 + r16];
    const float bb1 = bias[c0 + 16 + r16];
    const float bb2 = bias[c0 + 32 + r16];
    const float bb3 = bias[c0 + 48 + r16];
    float* orow = Out + (size_t)(m0 + 16 * w + 4 * g) * C_ + c0 + r16;
    orow[0 * C_ + 0]  = o0.x + bb0; orow[0 * C_ + 16] = o1.x + bb1;
    orow[0 * C_ + 32] = o2.x + bb2; orow[0 * C_ + 48] = o3.x + bb3;
    orow[1 * C_ + 0]  = o0.y + bb0; orow[1 * C_ + 16] = o1.y + bb1;
    orow[1 * C_ + 32] = o2.y + bb2; orow[1 * C_ + 48] = o3.y + bb3;
    orow[2 * C_ + 0]  = o0.z + bb0; orow[2 * C_ + 16] = o1.z + bb1;
    orow[2 * C_ + 32] = o2.z + bb2; orow[2 * C_ + 48] = o3.z + bb3;
    orow[3 * C_ + 0]  = o0.w + bb0; orow[3 * C_ + 16] = o1.w + bb1;
    orow[3 * C_ + 32] = o2.w + bb2; orow[3 * C_ + 48] = o3.w + bb3;
}

// ---------------------------------------------------------------------------
// K2: mu[bh] = (N*C/4) / sum|k| per (b,h).
// ---------------------------------------------------------------------------
__global__ __launch_bounds__(256)
void musum(const float* __restrict__ Kb, float* __restrict__ mu)
{
    const int bh = blockIdx.x;
    const int tid = threadIdx.x;
    const float* p = Kb + (size_t)bh * (N_ * HD_);
    float s = 0.0f;
    for (int i = tid; i < N_ * HD_; i += 256) s += fabsf(p[i]);
    for (int off = 32; off; off >>= 1) s += __shfl_down(s, off, 64);
    __shared__ float red[4];
    if ((tid & 63) == 0) red[tid >> 6] = s;
    __syncthreads();
    if (tid == 0)
        mu[bh] = (float)(N_ * C_ / 4.0) / (red[0] + red[1] + red[2] + red[3]);
}

// ---------------------------------------------------------------------------
// K3/K5 fused.  upd==0: l=y=0 exactly, init Yb.  upd==1: full.  upd==2:
// same math as 1 but skips the dead Yb store (final iteration).
// ---------------------------------------------------------------------------
__global__ __launch_bounds__(256)
void ew_fused(const float* __restrict__ Kb, const float* __restrict__ Lb,
              float* __restrict__ Yb, const float* __restrict__ mu,
              float* __restrict__ K2b,
              unsigned short* __restrict__ K2h, unsigned short* __restrict__ K2l,
              int upd)
{
    const int i = blockIdx.x * 256 + threadIdx.x;
    const int bh = i >> 16;
    const float m = mu[bh];
    const float lm = 4.0f * m;
    const float kv = Kb[i];
    float k2;
    if (upd) {
        const float lv = Lb[i];
        const float y = 2.0f * Yb[i] + m * (K2b[i] - lv);
        if (upd == 1) Yb[i] = y;
        const float yom = y / m;
        const float t = kv - lv + yom;
        const float s = (t >= lm) ? (t - lm) : ((t <= -lm) ? (t + lm) : 0.0f);
        k2 = kv - s - yom;
    } else {
        Yb[i] = 0.0f;
        const float t = kv;
        const float s = (t >= lm) ? (t - lm) : ((t <= -lm) ? (t + lm) : 0.0f);
        k2 = kv - s;
    }
    K2b[i] = k2;
    K2h[i] = bfhi(k2);
    K2l[i] = bflo(k2);
}

// ---------------------------------------------------------------------------
// K3c: Vt hi/lo bf16, transposed to [bh][d][n].  Run ONCE.
// ---------------------------------------------------------------------------
__global__ __launch_bounds__(256)
void vt_split(const float* __restrict__ Vb,
              unsigned short* __restrict__ Vth, unsigned short* __restrict__ Vtl)
{
    __shared__ float Ts[64][68];
    const int tid = threadIdx.x;
    const int bh = blockIdx.y;
    const int n0 = blockIdx.x * 64;
    const float* vb = Vb + ((size_t)bh * N_ + n0) * HD_;

    {
        int e = tid;
#pragma unroll
        for (int t = 0; t < 4; ++t, e += 256) {
            const int r = e >> 4, c4 = (e & 15) << 2;
            *(float4*)&Ts[r][c4] = *(const float4*)(vb + r * HD_ + c4);
        }
    }
    __syncthreads();

#pragma unroll
    for (int t = 0; t < 2; ++t) {
        const int idx = t * 2048 + tid * 8;
        const int d = idx >> 6, c = idx & 63;
        bfrag h8, l8;
#pragma unroll
        for (int q = 0; q < 8; ++q) {
            const float v = Ts[c + q][d];
            h8[q] = (short)bfhi(v);
            l8[q] = (short)bflo(v);
        }
        const size_t go = ((size_t)bh * HD_ + d) * N_ + n0 + c;
        *(bfrag*)(Vth + go) = h8;
        *(bfrag*)(Vtl + go) = l8;
    }
}

// De-interleave 4 packed uint4 (hi|lo<<16) into hi/lo bfrag pairs.
#define DEINT(PU0, PU1, PH, PL) do {                                          \
    uint4 _uh, _ul;                                                           \
    _uh.x = (PU0.x & 0xffffu) | (PU0.y << 16);                                \
    _uh.y = (PU0.z & 0xffffu) | (PU0.w << 16);                                \
    _uh.z = (PU1.x & 0xffffu) | (PU1.y << 16);                                \
    _uh.w = (PU1.z & 0xffffu) | (PU1.w << 16);                                \
    _ul.x = (PU0.x >> 16) | (PU0.y & 0xffff0000u);                            \
    _ul.y = (PU0.z >> 16) | (PU0.w & 0xffff0000u);                            \
    _ul.z = (PU1.x >> 16) | (PU1.y & 0xffff0000u);                            \
    _ul.w = (PU1.z >> 16) | (PU1.w & 0xffff0000u);                            \
    PH = *(const bfrag*)&_uh;                                                 \
    PL = *(const bfrag*)&_ul;                                                 \
} while (0)

// ---------------------------------------------------------------------------
// K4 flash-MFMA v6: V removed from LDS (all waves read IDENTICAL V B-frags;
// L2 serves the broadcast).  V quadrant frags loaded from global as named
// scalars with distance-1 quadrant prefetch; quadrant-0 loads issued in the
// stage window (held across both barriers).  Both packed P-sets resident in
// the 34.8 KB K-aliased buffer -> one PV sweep covers A and B per quadrant.
// LDS ops/tile/wave ~140 -> ~60.  Per-accumulator MFMA operand order
// unchanged -> absmax bit-exact 0.09179688.  grid (8, 96) x 256.
// ---------------------------------------------------------------------------
__global__ __launch_bounds__(256)
void flash(const unsigned short* __restrict__ K2h, const unsigned short* __restrict__ K2l,
           const unsigned short* __restrict__ Vth, const unsigned short* __restrict__ Vtl,
           float* __restrict__ Lout, float* __restrict__ Mrow, float* __restrict__ Zrow,
           unsigned short* __restrict__ Lbh, unsigned short* __restrict__ Lbl, int wsplit)
{
    __shared__ __attribute__((aligned(16))) unsigned int PuBuf[2 * 64 * 68]; // 34816 B
    short (*Kh)[72] = (short(*)[72])PuBuf;
    short (*Kl)[72] = (short(*)[72])((short*)PuBuf + 64 * 72);
    unsigned int (*PuA)[68] = (unsigned int(*)[68])PuBuf;          // aliases K
    unsigned int (*PuB)[68] = (unsigned int(*)[68])(PuBuf + 64 * 68);

    const int tid  = threadIdx.x;
    const int lane = tid & 63;
    const int w    = tid >> 6;
    const int g    = lane >> 4;
    const int r16  = lane & 15;
    const int bh   = blockIdx.y;
    const int q0   = blockIdx.x * 128;

    const unsigned short* kh = K2h + (size_t)bh * (N_ * HD_);
    const unsigned short* kl = K2l + (size_t)bh * (N_ * HD_);
    const unsigned short* vh = Vth + (size_t)bh * (N_ * HD_);
    const unsigned short* vl = Vtl + (size_t)bh * (N_ * HD_);

    const size_t qoffA = (size_t)(q0 + 16 * w + r16) * HD_ + 8 * g;
    const size_t qoffB = (size_t)(q0 + 64 + 16 * w + r16) * HD_ + 8 * g;
    const bfrag qhA0 = *(const bfrag*)(kh + qoffA);
    const bfrag qhA1 = *(const bfrag*)(kh + qoffA + 32);
    const bfrag qlA0 = *(const bfrag*)(kl + qoffA);
    const bfrag qlA1 = *(const bfrag*)(kl + qoffA + 32);
    const bfrag qhB0 = *(const bfrag*)(kh + qoffB);
    const bfrag qhB1 = *(const bfrag*)(kh + qoffB + 32);
    const bfrag qlB0 = *(const bfrag*)(kl + qoffB);
    const bfrag qlB1 = *(const bfrag*)(kl + qoffB + 32);

    const int i0 = tid * 8,        r0 = i0 >> 6, cc0 = i0 & 63;
    const int i1 = 2048 + tid * 8, r1 = i1 >> 6, cc1 = i1 & 63;

    bfrag pk0 = *(const bfrag*)(kh + i0);
    bfrag pk1 = *(const bfrag*)(kh + i1);
    bfrag pm0 = *(const bfrag*)(kl + i0);
    bfrag pm1 = *(const bfrag*)(kl + i1);

    // V row bases for this lane's B-frags (rows 16q + r16, q = quadrant)
    const size_t vrow0 = (size_t)(r16)      * N_ + 8 * g;
    const size_t vrow1 = (size_t)(16 + r16) * N_ + 8 * g;
    const size_t vrow2 = (size_t)(32 + r16) * N_ + 8 * g;
    const size_t vrow3 = (size_t)(48 + r16) * N_ + 8 * g;

    float mrA0 = -1e30f, mrA1 = -1e30f, mrA2 = -1e30f, mrA3 = -1e30f;
    float zrA0 = 0.0f,  zrA1 = 0.0f,  zrA2 = 0.0f,  zrA3 = 0.0f;
    float mrB0 = -1e30f, mrB1 = -1e30f, mrB2 = -1e30f, mrB3 = -1e30f;
    float zrB0 = 0.0f,  zrB1 = 0.0f,  zrB2 = 0.0f,  zrB3 = 0.0f;
    facc oA0 = {0.f, 0.f, 0.f, 0.f};
    facc oA1 = {0.f, 0.f, 0.f, 0.f};
    facc oA2 = {0.f, 0.f, 0.f, 0.f};
    facc oA3 = {0.f, 0.f, 0.f, 0.f};
    facc oB0 = {0.f, 0.f, 0.f, 0.f};
    facc oB1 = {0.f, 0.f, 0.f, 0.f};
    facc oB2 = {0.f, 0.f, 0.f, 0.f};
    facc oB3 = {0.f, 0.f, 0.f, 0.f};

    for (int kt = 0; kt < 16; ++kt) {
        const int ko = kt * 64;
        __syncthreads();   // bar1: prev tile's P reads done (P aliases K)
        *(bfrag*)&Kh[r0][cc0] = pk0;  *(bfrag*)&Kh[r1][cc1] = pk1;
        *(bfrag*)&Kl[r0][cc0] = pm0;  *(bfrag*)&Kl[r1][cc1] = pm1;
        // V quadrant-0 frags: issued now, consumed after bar3 (deep cover)
        const bfrag v0b0 = *(const bfrag*)(vh + vrow0 + ko);
        const bfrag v0b1 = *(const bfrag*)(vh + vrow0 + ko + 32);
        const bfrag v0c0 = *(const bfrag*)(vl + vrow0 + ko);
        const bfrag v0c1 = *(const bfrag*)(vl + vrow0 + ko + 32);
        if (kt + 1 < 16) {
            const size_t gn = (size_t)(kt + 1) * 4096;
            pk0 = *(const bfrag*)(kh + gn + i0);
            pk1 = *(const bfrag*)(kh + gn + i1);
            pm0 = *(const bfrag*)(kl + gn + i0);
            pm1 = *(const bfrag*)(kl + gn + i1);
        }
        __syncthreads();   // bar2: K tile visible

        facc sA0 = {0.f, 0.f, 0.f, 0.f};
        facc sA1 = {0.f, 0.f, 0.f, 0.f};
        facc sA2 = {0.f, 0.f, 0.f, 0.f};
        facc sA3 = {0.f, 0.f, 0.f, 0.f};
        facc sB0 = {0.f, 0.f, 0.f, 0.f};
        facc sB1 = {0.f, 0.f, 0.f, 0.f};
        facc sB2 = {0.f, 0.f, 0.f, 0.f};
        facc sB3 = {0.f, 0.f, 0.f, 0.f};
        {
            bfrag b0 = *(const bfrag*)&Kh[r16][8 * g];
            bfrag b1 = *(const bfrag*)&Kh[r16][32 + 8 * g];
            bfrag c0 = *(const bfrag*)&Kl[r16][8 * g];
            bfrag c1 = *(const bfrag*)&Kl[r16][32 + 8 * g];
            sA0 = __builtin_amdgcn_mfma_f32_16x16x32_bf16(qhA0, b0, sA0, 0, 0, 0);
            sA0 = __builtin_amdgcn_mfma_f32_16x16x32_bf16(qlA0, b0, sA0, 0, 0, 0);
            sA0 = __builtin_amdgcn_mfma_f32_16x16x32_bf16(qhA0, c0, sA0, 0, 0, 0);
            sA0 = __builtin_amdgcn_mfma_f32_16x16x32_bf16(qhA1, b1, sA0, 0, 0, 0);
            sA0 = __builtin_amdgcn_mfma_f32_16x16x32_bf16(qlA1, b1, sA0, 0, 0, 0);
            sA0 = __builtin_amdgcn_mfma_f32_16x16x32_bf16(qhA1, c1, sA0, 0, 0, 0);
            sB0 = __builtin_amdgcn_mfma_f32_16x16x32_bf16(qhB0, b0, sB0, 0, 0, 0);
            sB0 = __builtin_amdgcn_mfma_f32_16x16x32_bf16(qlB0, b0, sB0, 0, 0, 0);
            sB0 = __builtin_amdgcn_mfma_f32_16x16x32_bf16(qhB0, c0, sB0, 0, 0, 0);
            sB0 = __builtin_amdgcn_mfma_f32_16x16x32_bf16(qhB1, b1, sB0, 0, 0, 0);
            sB0 = __builtin_amdgcn_mfma_f32_16x16x32_bf16(qlB1, b1, sB0, 0, 0, 0);
            sB0 = __builtin_amdgcn_mfma_f32_16x16x32_bf16(qhB1, c1, sB0, 0, 0, 0);
        }
        {
            bfrag b0 = *(const bfrag*)&Kh[16 + r16][8 * g];
            bfrag b1 = *(const bfrag*)&Kh[16 + r16][32 + 8 * g];
            bfrag c0 = *(const bfrag*)&Kl[16 + r16][8 * g];
            bfrag c1 = *(const bfrag*)&Kl[16 + r16][32 + 8 * g];
            sA1 = __builtin_amdgcn_mfma_f32_16x16x32_bf16(qhA0, b0, sA1, 0, 0, 0);
            sA1 = __builtin_amdgcn_mfma_f32_16x16x32_bf16(qlA0, b0, sA1, 0, 0, 0);
            sA1 = __builtin_amdgcn_mfma_f32_16x16x32_bf16(qhA0, c0, sA1, 0, 0, 0);
            sA1 = __builtin_amdgcn_mfma_f32_16x16x32_bf16(qhA1, b1, sA1, 0, 0, 0);
            sA1 = __builtin_amdgcn_mfma_f32_16x16x32_bf16(qlA1, b1, sA1, 0, 0, 0);
            sA1 = __builtin_amdgcn_mfma_f32_16x16x32_bf16(qhA1, c1, sA1, 0, 0, 0);
            sB1 = __builtin_amdgcn_mfma_f32_16x16x32_bf16(qhB0, b0, sB1, 0, 0, 0);
            sB1 = __builtin_amdgcn_mfma_f32_16x16x32_bf16(qlB0, b0, sB1, 0, 0, 0);
            sB1 = __builtin_amdgcn_mfma_f32_16x16x32_bf16(qhB0, c0, sB1, 0, 0, 0);
            sB1 = __builtin_amdgcn_mfma_f32_16x16x32_bf16(qhB1, b1, sB1, 0, 0, 0);
            sB1 = __builtin_amdgcn_mfma_f32_16x16x32_bf16(qlB1, b1, sB1, 0, 0, 0);
            sB1 = __builtin_amdgcn_mfma_f32_16x16x32_bf16(qhB1, c1, sB1, 0, 0, 0);
        }
        {
            bfrag b0 = *(const bfrag*)&Kh[32 + r16][8 * g];
            bfrag b1 = *(const bfrag*)&Kh[32 + r16][32 + 8 * g];
            bfrag c0 = *(const bfrag*)&Kl[32 + r16][8 * g];
            bfrag c1 = *(const bfrag*)&Kl[32 + r16][32 + 8 * g];
            sA2 = __builtin_amdgcn_mfma_f32_16x16x32_bf16(qhA0, b0, sA2, 0, 0, 0);
            sA2 = __builtin_amdgcn_mfma_f32_16x16x32_bf16(qlA0, b0, sA2, 0, 0, 0);
            sA2 = __builtin_amdgcn_mfma_f32_16x16x32_bf16(qhA0, c0, sA2, 0, 0, 0);
            sA2 = __builtin_amdgcn_mfma_f32_16x16x32_bf16(qhA1, b1, sA2, 0, 0, 0);
            sA2 = __builtin_amdgcn_mfma_f32_16x16x32_bf16(qlA1, b1, sA2, 0, 0, 0);
            sA2 = __builtin_amdgcn_mfma_f32_16x16x32_bf16(qhA1, c1, sA2, 0, 0, 0);
            sB2 = __builtin_amdgcn_mfma_f32_16x16x32_bf16(qhB0, b0, sB2, 0, 0, 0);
            sB2 = __builtin_amdgcn_mfma_f32_16x16x32_bf16(qlB0, b0, sB2, 0, 0, 0);
            sB2 = __builtin_amdgcn_mfma_f32_16x16x32_bf16(qhB0, c0, sB2, 0, 0, 0);
            sB2 = __builtin_amdgcn_mfma_f32_16x16x32_bf16(qhB1, b1, sB2, 0, 0, 0);
            sB2 = __builtin_amdgcn_mfma_f32_16x16x32_bf16(qlB1, b1, sB2, 0, 0, 0);
            sB2 = __builtin_amdgcn_mfma_f32_16x16x32_bf16(qhB1, c1, sB2, 0, 0, 0);
        }
        {
            bfrag b0 = *(const bfrag*)&Kh[48 + r16][8 * g];
            bfrag b1 = *(const bfrag*)&Kh[48 + r16][32 + 8 * g];
            bfrag c0 = *(const bfrag*)&Kl[48 + r16][8 * g];
            bfrag c1 = *(const bfrag*)&Kl[48 + r16][32 + 8 * g];
            sA3 = __builtin_amdgcn_mfma_f32_16x16x32_bf16(qhA0, b0, sA3, 0, 0, 0);
            sA3 = __builtin_amdgcn_mfma_f32_16x16x32_bf16(qlA0, b0, sA3, 0, 0, 0);
            sA3 = __builtin_amdgcn_mfma_f32_16x16x32_bf16(qhA0, c0, sA3, 0, 0, 0);
            sA3 = __builtin_amdgcn_mfma_f32_16x16x32_bf16(qhA1, b1, sA3, 0, 0, 0);
            sA3 = __builtin_amdgcn_mfma_f32_16x16x32_bf16(qlA1, b1, sA3, 0, 0, 0);
            sA3 = __builtin_amdgcn_mfma_f32_16x16x32_bf16(qhA1, c1, sA3, 0, 0, 0);
            sB3 = __builtin_amdgcn_mfma_f32_16x16x32_bf16(qhB0, b0, sB3, 0, 0, 0);
            sB3 = __builtin_amdgcn_mfma_f32_16x16x32_bf16(qlB0, b0, sB3, 0, 0, 0);
            sB3 = __builtin_amdgcn_mfma_f32_16x16x32_bf16(qhB0, c0, sB3, 0, 0, 0);
            sB3 = __builtin_amdgcn_mfma_f32_16x16x32_bf16(qhB1, b1, sB3, 0, 0, 0);
            sB3 = __builtin_amdgcn_mfma_f32_16x16x32_bf16(qlB1, b1, sB3, 0, 0, 0);
            sB3 = __builtin_amdgcn_mfma_f32_16x16x32_bf16(qhB1, c1, sB3, 0, 0, 0);
        }

        sA0 = sA0 * SCALE_;  sA1 = sA1 * SCALE_;  sA2 = sA2 * SCALE_;  sA3 = sA3 * SCALE_;
        sB0 = sB0 * SCALE_;  sB1 = sB1 * SCALE_;  sB2 = sB2 * SCALE_;  sB3 = sB3 * SCALE_;

        // ---- softmax A ----
        float mt0 = fmaxf(fmaxf(sA0.x, sA1.x), fmaxf(sA2.x, sA3.x));
        float mt1 = fmaxf(fmaxf(sA0.y, sA1.y), fmaxf(sA2.y, sA3.y));
        float mt2 = fmaxf(fmaxf(sA0.z, sA1.z), fmaxf(sA2.z, sA3.z));
        float mt3 = fmaxf(fmaxf(sA0.w, sA1.w), fmaxf(sA2.w, sA3.w));
        for (int off = 8; off; off >>= 1) {
            mt0 = fmaxf(mt0, __shfl_xor(mt0, off, 16));
            mt1 = fmaxf(mt1, __shfl_xor(mt1, off, 16));
            mt2 = fmaxf(mt2, __shfl_xor(mt2, off, 16));
            mt3 = fmaxf(mt3, __shfl_xor(mt3, off, 16));
        }
        const float mnA0 = fmaxf(mrA0, mt0), mnA1 = fmaxf(mrA1, mt1);
        const float mnA2 = fmaxf(mrA2, mt2), mnA3 = fmaxf(mrA3, mt3);
        const float aA0 = __expf(mrA0 - mnA0), aA1 = __expf(mrA1 - mnA1);
        const float aA2 = __expf(mrA2 - mnA2), aA3 = __expf(mrA3 - mnA3);
        mrA0 = mnA0; mrA1 = mnA1; mrA2 = mnA2; mrA3 = mnA3;

        const float paA0 = __expf(sA0.x - mnA0), paA1 = __expf(sA0.y - mnA1);
        const float paA2 = __expf(sA0.z - mnA2), paA3 = __expf(sA0.w - mnA3);
        const float pbA0 = __expf(sA1.x - mnA0), pbA1 = __expf(sA1.y - mnA1);
        const float pbA2 = __expf(sA1.z - mnA2), pbA3 = __expf(sA1.w - mnA3);
        const float pcA0 = __expf(sA2.x - mnA0), pcA1 = __expf(sA2.y - mnA1);
        const float pcA2 = __expf(sA2.z - mnA2), pcA3 = __expf(sA2.w - mnA3);
        const float pdA0 = __expf(sA3.x - mnA0), pdA1 = __expf(sA3.y - mnA1);
        const float pdA2 = __expf(sA3.z - mnA2), pdA3 = __expf(sA3.w - mnA3);

        float zsA0 = paA0 + pbA0 + pcA0 + pdA0;
        float zsA1 = paA1 + pbA1 + pcA1 + pdA1;
        float zsA2 = paA2 + pbA2 + pcA2 + pdA2;
        float zsA3 = paA3 + pbA3 + pcA3 + pdA3;
        for (int off = 8; off; off >>= 1) {
            zsA0 += __shfl_xor(zsA0, off, 16);
            zsA1 += __shfl_xor(zsA1, off, 16);
            zsA2 += __shfl_xor(zsA2, off, 16);
            zsA3 += __shfl_xor(zsA3, off, 16);
        }
        zrA0 = zrA0 * aA0 + zsA0;  zrA1 = zrA1 * aA1 + zsA1;
        zrA2 = zrA2 * aA2 + zsA2;  zrA3 = zrA3 * aA3 + zsA3;
        oA0.x *= aA0; oA0.y *= aA1; oA0.z *= aA2; oA0.w *= aA3;
        oA1.x *= aA0; oA1.y *= aA1; oA1.z *= aA2; oA1.w *= aA3;
        oA2.x *= aA0; oA2.y *= aA1; oA2.z *= aA2; oA2.w *= aA3;
        oA3.x *= aA0; oA3.y *= aA1; oA3.z *= aA2; oA3.w *= aA3;

        // ---- softmax B ----
        mt0 = fmaxf(fmaxf(sB0.x, sB1.x), fmaxf(sB2.x, sB3.x));
        mt1 = fmaxf(fmaxf(sB0.y, sB1.y), fmaxf(sB2.y, sB3.y));
        mt2 = fmaxf(fmaxf(sB0.z, sB1.z), fmaxf(sB2.z, sB3.z));
        mt3 = fmaxf(fmaxf(sB0.w, sB1.w), fmaxf(sB2.w, sB3.w));
        for (int off = 8; off; off >>= 1) {
            mt0 = fmaxf(mt0, __shfl_xor(mt0, off, 16));
            mt1 = fmaxf(mt1, __shfl_xor(mt1, off, 16));
            mt2 = fmaxf(mt2, __shfl_xor(mt2, off, 16));
            mt3 = fmaxf(mt3, __shfl_xor(mt3, off, 16));
        }
        const float mnB0 = fmaxf(mrB0, mt0), mnB1 = fmaxf(mrB1, mt1);
        const float mnB2 = fmaxf(mrB2, mt2), mnB3 = fmaxf(mrB3, mt3);
        const float aB0 = __expf(mrB0 - mnB0), aB1 = __expf(mrB1 - mnB1);
        const float aB2 = __expf(mrB2 - mnB2), aB3 = __expf(mrB3 - mnB3);
        mrB0 = mnB0; mrB1 = mnB1; mrB2 = mnB2; mrB3 = mnB3;

        const float paB0 = __expf(sB0.x - mnB0), paB1 = __expf(sB0.y - mnB1);
        const float paB2 = __expf(sB0.z - mnB2), paB3 = __expf(sB0.w - mnB3);
        const float pbB0 = __expf(sB1.x - mnB0), pbB1 = __expf(sB1.y - mnB1);
        const float pbB2 = __expf(sB1.z - mnB2), pbB3 = __expf(sB1.w - mnB3);
        const float pcB0 = __expf(sB2.x - mnB0), pcB1 = __expf(sB2.y - mnB1);
        const float pcB2 = __expf(sB2.z - mnB2), pcB3 = __expf(sB2.w - mnB3);
        const float pdB0 = __expf(sB3.x - mnB0), pdB1 = __expf(sB3.y - mnB1);
        const float pdB2 = __expf(sB3.z - mnB2), pdB3 = __expf(sB3.w - mnB3);

        float zsB0 = paB0 + pbB0 + pcB0 + pdB0;
        float zsB1 = paB1 + pbB1 + pcB1 + pdB1;
        float zsB2 = paB2 + pbB2 + pcB2 + pdB2;
        float zsB3 = paB3 + pbB3 + pcB3 + pdB3;
        for (int off = 8; off; off >>= 1) {
            zsB0 += __shfl_xor(zsB0, off, 16);
            zsB1 += __shfl_xor(zsB1, off, 16);
            zsB2 += __shfl_xor(zsB2, off, 16);
            zsB3 += __shfl_xor(zsB3, off, 16);
        }
        zrB0 = zrB0 * aB0 + zsB0;  zrB1 = zrB1 * aB1 + zsB1;
        zrB2 = zrB2 * aB2 + zsB2;  zrB3 = zrB3 * aB3 + zsB3;
        oB0.x *= aB0; oB0.y *= aB1; oB0.z *= aB2; oB0.w *= aB3;
        oB1.x *= aB0; oB1.y *= aB1; oB1.z *= aB2; oB1.w *= aB3;
        oB2.x *= aB0; oB2.y *= aB1; oB2.z *= aB2; oB2.w *= aB3;
        oB3.x *= aB0; oB3.y *= aB1; oB3.z *= aB2; oB3.w *= aB3;

        __syncthreads();   // bar3: all K reads done before P overwrites K

        const int pr = 16 * w + 4 * g;
        const int prow = 16 * w + r16;
        // ---- both P-sets -> LDS (packed) ----
        PuA[pr + 0][r16]      = packhl(paA0);
        PuA[pr + 1][r16]      = packhl(paA1);
        PuA[pr + 2][r16]      = packhl(paA2);
        PuA[pr + 3][r16]      = packhl(paA3);
        PuA[pr + 0][16 + r16] = packhl(pbA0);
        PuA[pr + 1][16 + r16] = packhl(pbA1);
        PuA[pr + 2][16 + r16] = packhl(pbA2);
        PuA[pr + 3][16 + r16] = packhl(pbA3);
        PuA[pr + 0][32 + r16] = packhl(pcA0);
        PuA[pr + 1][32 + r16] = packhl(pcA1);
        PuA[pr + 2][32 + r16] = packhl(pcA2);
        PuA[pr + 3][32 + r16] = packhl(pcA3);
        PuA[pr + 0][48 + r16] = packhl(pdA0);
        PuA[pr + 1][48 + r16] = packhl(pdA1);
        PuA[pr + 2][48 + r16] = packhl(pdA2);
        PuA[pr + 3][48 + r16] = packhl(pdA3);
        PuB[pr + 0][r16]      = packhl(paB0);
        PuB[pr + 1][r16]      = packhl(paB1);
        PuB[pr + 2][r16]      = packhl(paB2);
        PuB[pr + 3][r16]      = packhl(paB3);
        PuB[pr + 0][16 + r16] = packhl(pbB0);
        PuB[pr + 1][16 + r16] = packhl(pbB1);
        PuB[pr + 2][16 + r16] = packhl(pbB2);
        PuB[pr + 3][16 + r16] = packhl(pbB3);
        PuB[pr + 0][32 + r16] = packhl(pcB0);
        PuB[pr + 1][32 + r16] = packhl(pcB1);
        PuB[pr + 2][32 + r16] = packhl(pcB2);
        PuB[pr + 3][32 + r16] = packhl(pcB3);
        PuB[pr + 0][48 + r16] = packhl(pdB0);
        PuB[pr + 1][48 + r16] = packhl(pdB1);
        PuB[pr + 2][48 + r16] = packhl(pdB2);
        PuB[pr + 3][48 + r16] = packhl(pdB3);
        __builtin_amdgcn_wave_barrier();   // P bands are wave-private

        // ---- P frags (A and B) ----
        bfrag phA0, plA0, phA1, plA1, phB0, plB0, phB1, plB1;
        {
            const uint4 a0 = *(const uint4*)&PuA[prow][8 * g];
            const uint4 a1 = *(const uint4*)&PuA[prow][8 * g + 4];
            const uint4 a2 = *(const uint4*)&PuA[prow][32 + 8 * g];
            const uint4 a3 = *(const uint4*)&PuA[prow][32 + 8 * g + 4];
            DEINT(a0, a1, phA0, plA0);
            DEINT(a2, a3, phA1, plA1);
            const uint4 b0 = *(const uint4*)&PuB[prow][8 * g];
            const uint4 b1 = *(const uint4*)&PuB[prow][8 * g + 4];
            const uint4 b2 = *(const uint4*)&PuB[prow][32 + 8 * g];
            const uint4 b3 = *(const uint4*)&PuB[prow][32 + 8 * g + 4];
            DEINT(b0, b1, phB0, plB0);
            DEINT(b2, b3, phB1, plB1);
        }

        // ---- PV quadrant 0 (V frags from stage window); prefetch Q1 ----
        const bfrag v1b0 = *(const bfrag*)(vh + vrow1 + ko);
        const bfrag v1b1 = *(const bfrag*)(vh + vrow1 + ko + 32);
        const bfrag v1c0 = *(const bfrag*)(vl + vrow1 + ko);
        const bfrag v1c1 = *(const bfrag*)(vl + vrow1 + ko + 32);
        oA0 = __builtin_amdgcn_mfma_f32_16x16x32_bf16(phA0, v0b0, oA0, 0, 0, 0);
        oA0 = __builtin_amdgcn_mfma_f32_16x16x32_bf16(plA0, v0b0, oA0, 0, 0, 0);
        oA0 = __builtin_amdgcn_mfma_f32_16x16x32_bf16(phA0, v0c0, oA0, 0, 0, 0);
        oA0 = __builtin_amdgcn_mfma_f32_16x16x32_bf16(phA1, v0b1, oA0, 0, 0, 0);
        oA0 = __builtin_amdgcn_mfma_f32_16x16x32_bf16(plA1, v0b1, oA0, 0, 0, 0);
        oA0 = __builtin_amdgcn_mfma_f32_16x16x32_bf16(phA1, v0c1, oA0, 0, 0, 0);
        oB0 = __builtin_amdgcn_mfma_f32_16x16x32_bf16(phB0, v0b0, oB0, 0, 0, 0);
        oB0 = __builtin_amdgcn_mfma_f32_16x16x32_bf16(plB0, v0b0, oB0, 0, 0, 0);
        oB0 = __builtin_amdgcn_mfma_f32_16x16x32_bf16(phB0, v0c0, oB0, 0, 0, 0);
        oB0 = __builtin_amdgcn_mfma_f32_16x16x32_bf16(phB1, v0b1, oB0, 0, 0, 0);
        oB0 = __builtin_amdgcn_mfma_f32_16x16x32_bf16(plB1, v0b1, oB0, 0, 0, 0);
        oB0 = __builtin_amdgcn_mfma_f32_16x16x32_bf16(phB1, v0c1, oB0, 0, 0, 0);

        // ---- PV quadrant 1; prefetch Q2 ----
        const bfrag v2b0 = *(const bfrag*)(vh + vrow2 + ko);
        const bfrag v2b1 = *(const bfrag*)(vh + vrow2 + ko + 32);
        const bfrag v2c0 = *(const bfrag*)(vl + vrow2 + ko);
        const bfrag v2c1 = *(const bfrag*)(vl + vrow2 + ko + 32);
        oA1 = __builtin_amdgcn_mfma_f32_16x16x32_bf16(phA0, v1b0, oA1, 0, 0, 0);
        oA1 = __builtin_amdgcn_mfma_f32_16x16x32_bf16(plA0, v1b0, oA1, 0, 0, 0);
        oA1 = __builtin_amdgcn_mfma_f32_16x16x32_bf16(phA0, v1c0, oA1, 0, 0, 0);
        oA1 = __builtin_amdgcn_mfma_f32_16x16x32_bf16(phA1, v1b1, oA1, 0, 0, 0);
        oA1 = __builtin_amdgcn_mfma_f32_16x16x32_bf16(plA1, v1b1, oA1, 0, 0, 0);
        oA1 = __builtin_amdgcn_mfma_f32_16x16x32_bf16(phA1, v1c1, oA1, 0, 0, 0);
        oB1 = __builtin_amdgcn_mfma_f32_16x16x32_bf16(phB0, v1b0, oB1, 0, 0, 0);
        oB1 = __builtin_amdgcn_mfma_f32_16x16x32_bf16(plB0, v1b0, oB1, 0, 0, 0);
        oB1 = __builtin_amdgcn_mfma_f32_16x16x32_bf16(phB0, v1c0, oB1, 0, 0, 0);
        oB1 = __builtin_amdgcn_mfma_f32_16x16x32_bf16(phB1, v1b1, oB1, 0, 0, 0);
        oB1 = __builtin_amdgcn_mfma_f32_16x16x32_bf16(plB1, v1b1, oB1, 0, 0, 0);
        oB1 = __builtin_amdgcn_mfma_f32_16x16x32_bf16(phB1, v1c1, oB1, 0, 0, 0);

        // ---- PV quadrant 2; prefetch Q3 ----
        const bfrag v3b0 = *(const bfrag*)(vh + vrow3 + ko);
        const bfrag v3b1 = *(const bfrag*)(vh + vrow3 + ko + 32);
        const bfrag v3c0 = *(const bfrag*)(vl + vrow3 + ko);
        const bfrag v3c1 = *(const bfrag*)(vl + vrow3 + ko + 32);
        oA2 = __builtin_amdgcn_mfma_f32_16x16x32_bf16(phA0, v2b0, oA2, 0, 0, 0);
        oA2 = __builtin_amdgcn_mfma_f32_16x16x32_bf16(plA0, v2b0, oA2, 0, 0, 0);
        oA2 = __builtin_amdgcn_mfma_f32_16x16x32_bf16(phA0, v2c0, oA2, 0, 0, 0);
        oA2 = __builtin_amdgcn_mfma_f32_16x16x32_bf16(phA1, v2b1, oA2, 0, 0, 0);
        oA2 = __builtin_amdgcn_mfma_f32_16x16x32_bf16(plA1, v2b1, oA2, 0, 0, 0);
        oA2 = __builtin_amdgcn_mfma_f32_16x16x32_bf16(phA1, v2c1, oA2, 0, 0, 0);
        oB2 = __builtin_amdgcn_mfma_f32_16x16x32_bf16(phB0, v2b0, oB2, 0, 0, 0);
        oB2 = __builtin_amdgcn_mfma_f32_16x16x32_bf16(plB0, v2b0, oB2, 0, 0, 0);
        oB2 = __builtin_amdgcn_mfma_f32_16x16x32_bf16(phB0, v2c0, oB2, 0, 0, 0);
        oB2 = __builtin_amdgcn_mfma_f32_16x16x32_bf16(phB1, v2b1, oB2, 0, 0, 0);
        oB2 = __builtin_amdgcn_mfma_f32_16x16x32_bf16(plB1, v2b1, oB2, 0, 0, 0);
        oB2 = __builtin_amdgcn_mfma_f32_16x16x32_bf16(phB1, v2c1, oB2, 0, 0, 0);

        // ---- PV quadrant 3 ----
        oA3 = __builtin_amdgcn_mfma_f32_16x16x32_bf16(phA0, v3b0, oA3, 0, 0, 0);
        oA3 = __builtin_amdgcn_mfma_f32_16x16x32_bf16(plA0, v3b0, oA3, 0, 0, 0);
        oA3 = __builtin_amdgcn_mfma_f32_16x16x32_bf16(phA0, v3c0, oA3, 0, 0, 0);
        oA3 = __builtin_amdgcn_mfma_f32_16x16x32_bf16(phA1, v3b1, oA3, 0, 0, 0);
        oA3 = __builtin_amdgcn_mfma_f32_16x16x32_bf16(plA1, v3b1, oA3, 0, 0, 0);
        oA3 = __builtin_amdgcn_mfma_f32_16x16x32_bf16(phA1, v3c1, oA3, 0, 0, 0);
        oB3 = __builtin_amdgcn_mfma_f32_16x16x32_bf16(phB0, v3b0, oB3, 0, 0, 0);
        oB3 = __builtin_amdgcn_mfma_f32_16x16x32_bf16(plB0, v3b0, oB3, 0, 0, 0);
        oB3 = __builtin_amdgcn_mfma_f32_16x16x32_bf16(phB0, v3c0, oB3, 0, 0, 0);
        oB3 = __builtin_amdgcn_mfma_f32_16x16x32_bf16(phB1, v3b1, oB3, 0, 0, 0);
        oB3 = __builtin_amdgcn_mfma_f32_16x16x32_bf16(plB1, v3b1, oB3, 0, 0, 0);
        oB3 = __builtin_amdgcn_mfma_f32_16x16x32_bf16(phB1, v3c1, oB3, 0, 0, 0);
    }

    // ---- epilogue A ----
    {
        const float zi0 = 1.0f / zrA0, zi1 = 1.0f / zrA1;
        const float zi2 = 1.0f / zrA2, zi3 = 1.0f / zrA3;
        const size_t base = ((size_t)bh * N_ + q0 + 16 * w + 4 * g) * HD_ + r16;
        float* lrow = Lout + base;
        const float v00 = oA0.x * zi0, v01 = oA1.x * zi0, v02 = oA2.x * zi0, v03 = oA3.x * zi0;
        const float v10 = oA0.y * zi1, v11 = oA1.y * zi1, v12 = oA2.y * zi1, v13 = oA3.y * zi1;
        const float v20 = oA0.z * zi2, v21 = oA1.z * zi2, v22 = oA2.z * zi2, v23 = oA3.z * zi2;
        const float v30 = oA0.w * zi3, v31 = oA1.w * zi3, v32 = oA2.w * zi3, v33 = oA3.w * zi3;
        lrow[0 * HD_ + 0] = v00; lrow[0 * HD_ + 16] = v01; lrow[0 * HD_ + 32] = v02; lrow[0 * HD_ + 48] = v03;
        lrow[1 * HD_ + 0] = v10; lrow[1 * HD_ + 16] = v11; lrow[1 * HD_ + 32] = v12; lrow[1 * HD_ + 48] = v13;
        lrow[2 * HD_ + 0] = v20; lrow[2 * HD_ + 16] = v21; lrow[2 * HD_ + 32] = v22; lrow[2 * HD_ + 48] = v23;
        lrow[3 * HD_ + 0] = v30; lrow[3 * HD_ + 16] = v31; lrow[3 * HD_ + 32] = v32; lrow[3 * HD_ + 48] = v33;
        if (wsplit) {
            Lbh[base + 0 * HD_ + 0] = bfhi(v00); Lbl[base + 0 * HD_ + 0] = bflo(v00);
            Lbh[base + 0 * HD_ + 16] = bfhi(v01); Lbl[base + 0 * HD_ + 16] = bflo(v01);
            Lbh[base + 0 * HD_ + 32] = bfhi(v02); Lbl[base + 0 * HD_ + 32] = bflo(v02);
            Lbh[base + 0 * HD_ + 48] = bfhi(v03); Lbl[base + 0 * HD_ + 48] = bflo(v03);
            Lbh[base + 1 * HD_ + 0] = bfhi(v10); Lbl[base + 1 * HD_ + 0] = bflo(v10);
            Lbh[base + 1 * HD_ + 16] = bfhi(v11); Lbl[base + 1 * HD_ + 16] = bflo(v11);
            Lbh[base + 1 * HD_ + 32] = bfhi(v12); Lbl[base + 1 * HD_ + 32] = bflo(v12);
            Lbh[base + 1 * HD_ + 48] = bfhi(v13); Lbl[base + 1 * HD_ + 48] = bflo(v13);
            Lbh[base + 2 * HD_ + 0] = bfhi(v20); Lbl[base + 2 * HD_ + 0] = bflo(v20);
            Lbh[base + 2 * HD_ + 16] = bfhi(v21); Lbl[base + 2 * HD_ + 16] = bflo(v21);
            Lbh[base + 2 * HD_ + 32] = bfhi(v22); Lbl[base + 2 * HD_ + 32] = bflo(v22);
            Lbh[base + 2 * HD_ + 48] = bfhi(v23); Lbl[base + 2 * HD_ + 48] = bflo(v23);
            Lbh[base + 3 * HD_ + 0] = bfhi(v30); Lbl[base + 3 * HD_ + 0] = bflo(v30);
            Lbh[base + 3 * HD_ + 16] = bfhi(v31); Lbl[base + 3 * HD_ + 16] = bflo(v31);
            Lbh[base + 3 * HD_ + 32] = bfhi(v32); Lbl[base + 3 * HD_ + 32] = bflo(v32);
            Lbh[base + 3 * HD_ + 48] = bfhi(v33); Lbl[base + 3 * HD_ + 48] = bflo(v33);
        }
        if (r16 == 0) {
            const size_t rb = (size_t)bh * N_ + q0 + 16 * w + 4 * g;
            Mrow[rb + 0] = mrA0; Mrow[rb + 1] = mrA1;
            Mrow[rb + 2] = mrA2; Mrow[rb + 3] = mrA3;
            Zrow[rb + 0] = zrA0; Zrow[rb + 1] = zrA1;
            Zrow[rb + 2] = zrA2; Zrow[rb + 3] = zrA3;
        }
    }
    // ---- epilogue B ----
    {
        const float zi0 = 1.0f / zrB0, zi1 = 1.0f / zrB1;
        const float zi2 = 1.0f / zrB2, zi3 = 1.0f / zrB3;
        const size_t base = ((size_t)bh * N_ + q0 + 64 + 16 * w + 4 * g) * HD_ + r16;
        float* lrow = Lout + base;
        const float v00 = oB0.x * zi0, v01 = oB1.x * zi0, v02 = oB2.x * zi0, v03 = oB3.x * zi0;
        const float v10 = oB0.y * zi1, v11 = oB1.y * zi1, v12 = oB2.y * zi1, v13 = oB3.y * zi1;
        const float v20 = oB0.z * zi2, v21 = oB1.z * zi2, v22 = oB2.z * zi2, v23 = oB3.z * zi2;
        const float v30 = oB0.w * zi3, v31 = oB1.w * zi3, v32 = oB2.w * zi3, v33 = oB3.w * zi3;
        lrow[0 * HD_ + 0] = v00; lrow[0 * HD_ + 16] = v01; lrow[0 * HD_ + 32] = v02; lrow[0 * HD_ + 48] = v03;
        lrow[1 * HD_ + 0] = v10; lrow[1 * HD_ + 16] = v11; lrow[1 * HD_ + 32] = v12; lrow[1 * HD_ + 48] = v13;
        lrow[2 * HD_ + 0] = v20; lrow[2 * HD_ + 16] = v21; lrow[2 * HD_ + 32] = v22; lrow[2 * HD_ + 48] = v23;
        lrow[3 * HD_ + 0] = v30; lrow[3 * HD_ + 16] = v31; lrow[3 * HD_ + 32] = v32; lrow[3 * HD_ + 48] = v33;
        if (wsplit) {
            Lbh[base + 0 * HD_ + 0] = bfhi(v00); Lbl[base + 0 * HD_ + 0] = bflo(v00);
            Lbh[base + 0 * HD_ + 16] = bfhi(v01); Lbl[base + 0 * HD_ + 16] = bflo(v01);
            Lbh[base + 0 * HD_ + 32] = bfhi(v02); Lbl[base + 0 * HD_ + 32] = bflo(v02);
            Lbh[base + 0 * HD_ + 48] = bfhi(v03); Lbl[base + 0 * HD_ + 48] = bflo(v03);
            Lbh[base + 1 * HD_ + 0] = bfhi(v10); Lbl[base + 1 * HD_ + 0] = bflo(v10);
            Lbh[base + 1 * HD_ + 16] = bfhi(v11); Lbl[base + 1 * HD_ + 16] = bflo(v11);
            Lbh[base + 1 * HD_ + 32] = bfhi(v12); Lbl[base + 1 * HD_ + 32] = bflo(v12);
            Lbh[base + 1 * HD_ + 48] = bfhi(v13); Lbl[base + 1 * HD_ + 48] = bflo(v13);
            Lbh[base + 2 * HD_ + 0] = bfhi(v20); Lbl[base + 2 * HD_ + 0] = bflo(v20);
            Lbh[base + 2 * HD_ + 16] = bfhi(v21); Lbl[base + 2 * HD_ + 16] = bflo(v21);
            Lbh[base + 2 * HD_ + 32] = bfhi(v22); Lbl[base + 2 * HD_ + 32] = bflo(v22);
            Lbh[base + 2 * HD_ + 48] = bfhi(v23); Lbl[base + 2 * HD_ + 48] = bflo(v23);
            Lbh[base + 3 * HD_ + 0] = bfhi(v30); Lbl[base + 3 * HD_ + 0] = bflo(v30);
            Lbh[base + 3 * HD_ + 16] = bfhi(v31); Lbl[base + 3 * HD_ + 16] = bflo(v31);
            Lbh[base + 3 * HD_ + 32] = bfhi(v32); Lbl[base + 3 * HD_ + 32] = bflo(v32);
            Lbh[base + 3 * HD_ + 48] = bfhi(v33); Lbl[base + 3 * HD_ + 48] = bflo(v33);
        }
        if (r16 == 0) {
            const size_t rb = (size_t)bh * N_ + q0 + 64 + 16 * w + 4 * g;
            Mrow[rb + 0] = mrB0; Mrow[rb + 1] = mrB1;
            Mrow[rb + 2] = mrB2; Mrow[rb + 3] = mrB3;
            Zrow[rb + 0] = zrB0; Zrow[rb + 1] = zrB1;
            Zrow[rb + 2] = zrB2; Zrow[rb + 3] = zrB3;
        }
    }
}

// ---------------------------------------------------------------------------
// K6 attn_out_mfma (unchanged, verified).
// ---------------------------------------------------------------------------
__global__ __launch_bounds__(256)
void attn_out_mfma(const float* __restrict__ K2v, const float* __restrict__ Mrow,
                   const float* __restrict__ Zrow, float* __restrict__ A)
{
    __shared__ short Kh[64][72];
    __shared__ short Kl[64][72];

    const int tid  = threadIdx.x;
    const int lane = tid & 63;
    const int w    = tid >> 6;
    const int g    = lane >> 4;
    const int r16  = lane & 15;
    const int bh   = blockIdx.y;
    const int q0   = blockIdx.x * 64;
    const float* k2b = K2v + (size_t)bh * N_ * HD_;

    const int qrow = q0 + 16 * w + r16;
    const float4 f0 = *(const float4*)(k2b + (size_t)qrow * HD_ + 8 * g);
    const float4 f1 = *(const float4*)(k2b + (size_t)qrow * HD_ + 8 * g + 4);
    const float4 f2 = *(const float4*)(k2b + (size_t)qrow * HD_ + 32 + 8 * g);
    const float4 f3 = *(const float4*)(k2b + (size_t)qrow * HD_ + 32 + 8 * g + 4);
    const bfrag qh0 = pack_hi(f0, f1), ql0 = pack_lo(f0, f1);
    const bfrag qh1 = pack_hi(f2, f3), ql1 = pack_lo(f2, f3);

    const size_t mb = (size_t)bh * N_ + q0 + 16 * w + 4 * g;
    const float mi0 = Mrow[mb + 0], mi1 = Mrow[mb + 1];
    const float mi2 = Mrow[mb + 2], mi3 = Mrow[mb + 3];
    const float zi0 = 1.0f / Zrow[mb + 0], zi1 = 1.0f / Zrow[mb + 1];
    const float zi2 = 1.0f / Zrow[mb + 2], zi3 = 1.0f / Zrow[mb + 3];

    const int i0 = tid * 8,        r0 = i0 >> 6, cc0 = i0 & 63;
    const int i1 = 2048 + tid * 8, r1 = i1 >> 6, cc1 = i1 & 63;

    float4 a0 = *(const float4*)(k2b + (size_t)r0 * HD_ + cc0);
    float4 a1 = *(const float4*)(k2b + (size_t)r0 * HD_ + cc0 + 4);
    float4 b0v = *(const float4*)(k2b + (size_t)r1 * HD_ + cc1);
    float4 b1v = *(const float4*)(k2b + (size_t)r1 * HD_ + cc1 + 4);

    for (int kt = 0; kt < 16; ++kt) {
        __syncthreads();
        *(bfrag*)&Kh[r0][cc0] = pack_hi(a0, a1);
        *(bfrag*)&Kl[r0][cc0] = pack_lo(a0, a1);
        *(bfrag*)&Kh[r1][cc1] = pack_hi(b0v, b1v);
        *(bfrag*)&Kl[r1][cc1] = pack_lo(b0v, b1v);
        if (kt + 1 < 16) {
            const size_t gn = (size_t)(kt + 1) * 64;
            a0  = *(const float4*)(k2b + (gn + r0) * HD_ + cc0);
            a1  = *(const float4*)(k2b + (gn + r0) * HD_ + cc0 + 4);
            b0v = *(const float4*)(k2b + (gn + r1) * HD_ + cc1);
            b1v = *(const float4*)(k2b + (gn + r1) * HD_ + cc1 + 4);
        }
        __syncthreads();

        facc s0 = {0.f, 0.f, 0.f, 0.f};
        facc s1 = {0.f, 0.f, 0.f, 0.f};
        facc s2 = {0.f, 0.f, 0.f, 0.f};
        facc s3 = {0.f, 0.f, 0.f, 0.f};
        {
            bfrag b0 = *(const bfrag*)&Kh[r16][8 * g];
            bfrag b1 = *(const bfrag*)&Kh[r16][32 + 8 * g];
            bfrag c0 = *(const bfrag*)&Kl[r16][8 * g];
            bfrag c1 = *(const bfrag*)&Kl[r16][32 + 8 * g];
            s0 = __builtin_amdgcn_mfma_f32_16x16x32_bf16(qh0, b0, s0, 0, 0, 0);
            s0 = __builtin_amdgcn_mfma_f32_16x16x32_bf16(ql0, b0, s0, 0, 0, 0);
            s0 = __builtin_amdgcn_mfma_f32_16x16x32_bf16(qh0, c0, s0, 0, 0, 0);
            s0 = __builtin_amdgcn_mfma_f32_16x16x32_bf16(qh1, b1, s0, 0, 0, 0);
            s0 = __builtin_amdgcn_mfma_f32_16x16x32_bf16(ql1, b1, s0, 0, 0, 0);
            s0 = __builtin_amdgcn_mfma_f32_16x16x32_bf16(qh1, c1, s0, 0, 0, 0);
        }
        {
            bfrag b0 = *(const bfrag*)&Kh[16 + r16][8 * g];
            bfrag b1 = *(const bfrag*)&Kh[16 + r16][32 + 8 * g];
            bfrag c0 = *(const bfrag*)&Kl[16 + r16][8 * g];
            bfrag c1 = *(const bfrag*)&Kl[16 + r16][32 + 8 * g];
            s1 = __builtin_amdgcn_mfma_f32_16x16x32_bf16(qh0, b0, s1, 0, 0, 0);
            s1 = __builtin_amdgcn_mfma_f32_16x16x32_bf16(ql0, b0, s1, 0, 0, 0);
            s1 = __builtin_amdgcn_mfma_f32_16x16x32_bf16(qh0, c0, s1, 0, 0, 0);
            s1 = __builtin_amdgcn_mfma_f32_16x16x32_bf16(qh1, b1, s1, 0, 0, 0);
            s1 = __builtin_amdgcn_mfma_f32_16x16x32_bf16(ql1, b1, s1, 0, 0, 0);
            s1 = __builtin_amdgcn_mfma_f32_16x16x32_bf16(qh1, c1, s1, 0, 0, 0);
        }
        {
            bfrag b0 = *(const bfrag*)&Kh[32 + r16][8 * g];
            bfrag b1 = *(const bfrag*)&Kh[32 + r16][32 + 8 * g];
            bfrag c0 = *(const bfrag*)&Kl[32 + r16][8 * g];
            bfrag c1 = *(const bfrag*)&Kl[32 + r16][32 + 8 * g];
            s2 = __builtin_amdgcn_mfma_f32_16x16x32_bf16(qh0, b0, s2, 0, 0, 0);
            s2 = __builtin_amdgcn_mfma_f32_16x16x32_bf16(ql0, b0, s2, 0, 0, 0);
            s2 = __builtin_amdgcn_mfma_f32_16x16x32_bf16(qh0, c0, s2, 0, 0, 0);
            s2 = __builtin_amdgcn_mfma_f32_16x16x32_bf16(qh1, b1, s2, 0, 0, 0);
            s2 = __builtin_amdgcn_mfma_f32_16x16x32_bf16(ql1, b1, s2, 0, 0, 0);
            s2 = __builtin_amdgcn_mfma_f32_16x16x32_bf16(qh1, c1, s2, 0, 0, 0);
        }
        {
            bfrag b0 = *(const bfrag*)&Kh[48 + r16][8 * g];
            bfrag b1 = *(const bfrag*)&Kh[48 + r16][32 + 8 * g];
            bfrag c0 = *(const bfrag*)&Kl[48 + r16][8 * g];
            bfrag c1 = *(const bfrag*)&Kl[48 + r16][32 + 8 * g];
            s3 = __builtin_amdgcn_mfma_f32_16x16x32_bf16(qh0, b0, s3, 0, 0, 0);
            s3 = __builtin_amdgcn_mfma_f32_16x16x32_bf16(ql0, b0, s3, 0, 0, 0);
            s3 = __builtin_amdgcn_mfma_f32_16x16x32_bf16(qh0, c0, s3, 0, 0, 0);
            s3 = __builtin_amdgcn_mfma_f32_16x16x32_bf16(qh1, b1, s3, 0, 0, 0);
            s3 = __builtin_amdgcn_mfma_f32_16x16x32_bf16(ql1, b1, s3, 0, 0, 0);
            s3 = __builtin_amdgcn_mfma_f32_16x16x32_bf16(qh1, c1, s3, 0, 0, 0);
        }

        s0 = s0 * SCALE_;  s1 = s1 * SCALE_;  s2 = s2 * SCALE_;  s3 = s3 * SCALE_;

        float* ar0 = A + (mb + 0) * N_ + kt * 64;
        float* ar1 = A + (mb + 1) * N_ + kt * 64;
        float* ar2 = A + (mb + 2) * N_ + kt * 64;
        float* ar3 = A + (mb + 3) * N_ + kt * 64;
        ar0[r16]      = __expf(s0.x - mi0) * zi0;
        ar0[16 + r16] = __expf(s1.x - mi0) * zi0;
        ar0[32 + r16] = __expf(s2.x - mi0) * zi0;
        ar0[48 + r16] = __expf(s3.x - mi0) * zi0;
        ar1[r16]      = __expf(s0.y - mi1) * zi1;
        ar1[16 + r16] = __expf(s1.y - mi1) * zi1;
        ar1[32 + r16] = __expf(s2.y - mi1) * zi1;
        ar1[48 + r16] = __expf(s3.y - mi1) * zi1;
        ar2[r16]      = __expf(s0.z - mi2) * zi2;
        ar2[16 + r16] = __expf(s1.z - mi2) * zi2;
        ar2[32 + r16] = __expf(s2.z - mi2) * zi2;
        ar2[48 + r16] = __expf(s3.z - mi2) * zi2;
        ar3[r16]      = __expf(s0.w - mi3) * zi3;
        ar3[16 + r16] = __expf(s1.w - mi3) * zi3;
        ar3[32 + r16] = __expf(s2.w - mi3) * zi3;
        ar3[48 + r16] = __expf(s3.w - mi3) * zi3;
    }
}

// ---------------------------------------------------------------------------
// d_out FLOAT32: out = d_out[0..6291456), attn = d_out[6291456..).
// ws (floats): kb@0, vb@SZ, lb@2SZ, yb@3SZ, k2b@4SZ, mu@5SZ(128), rowm, rowz.
// bf16 scratch lives in the attn output region; proj runs BEFORE attn_out.
// ---------------------------------------------------------------------------
extern "C" void kernel_launch(void* const* d_in, const int* in_sizes, int n_in,
                              void* d_out, int out_size, void* d_ws, size_t ws_size,
                              hipStream_t stream)
{
    (void)in_sizes; (void)n_in; (void)out_size; (void)ws_size;

    const float* x  = (const float*)d_in[0];
    const float* Wq = (const float*)d_in[1];
    const float* bq = (const float*)d_in[2];
    const float* Wp = (const float*)d_in[3];
    const float* bp = (const float*)d_in[4];

    float* out_f  = (float*)d_out;
    float* attn_f = out_f + (size_t)B_ * N_ * C_;

    const size_t SZ = (size_t)BH_ * N_ * HD_;   // 6,291,456
    float* ws   = (float*)d_ws;
    float* kb   = ws;
    float* vb   = ws + SZ;
    float* lb   = ws + 2 * SZ;
    float* yb   = ws + 3 * SZ;
    float* k2b  = ws + 4 * SZ;
    float* mu   = ws + 5 * SZ;
    float* rowm = mu + 128;
    float* rowz = rowm + (size_t)BH_ * N_;

    unsigned short* k2h  = (unsigned short*)attn_f;
    unsigned short* k2l  = k2h + SZ;
    unsigned short* vth  = k2h + 2 * SZ;
    unsigned short* vtl  = k2h + 3 * SZ;
    unsigned short* xh   = k2h + 4 * SZ;
    unsigned short* xl   = k2h + 5 * SZ;
    unsigned short* wqth = k2h + 6 * SZ;
    unsigned short* wqtl = k2h + 7 * SZ;
    unsigned short* wpth = k2h + 8 * SZ;
    unsigned short* wptl = k2h + 9 * SZ;
    unsigned short* lbh  = k2h + 10 * SZ;
    unsigned short* lbl  = k2h + 11 * SZ;

    split_flat<<<3072, 256, 0, stream>>>(x, xh, xl);
    split_wt<<<dim3(24, 12), 256, 0, stream>>>(Wq, 2 * C_, wqth, wqtl);
    split_wt<<<dim3(12, 12), 256, 0, stream>>>(Wp, C_, wpth, wptl);

    qkv_mfma<<<dim3(24, 128), 256, 0, stream>>>(xh, xl, wqth, wqtl, bq, kb, vb);
    vt_split<<<dim3(16, 96), 256, 0, stream>>>(vb, vth, vtl);
    musum<<<96, 256, 0, stream>>>(kb, mu);

    for (int it = 0; it <= NIT_; ++it) {
        const int upd = (it == 0) ? 0 : (it == NIT_ ? 2 : 1);
        ew_fused<<<24576, 256, 0, stream>>>(kb, lb, yb, mu, k2b, k2h, k2l, upd);
        flash<<<dim3(8, 96), 256, 0, stream>>>(k2h, k2l, vth, vtl, lb, rowm, rowz,
                                               lbh, lbl, it == NIT_ ? 1 : 0);
    }

    proj_mfma<<<dim3(12, 128), 256, 0, stream>>>(lbh, lbl, wpth, wptl, bp, out_f);
    attn_out_mfma<<<dim3(16, 96), 256, 0, stream>>>(k2b, rowm, rowz, attn_f);
}

// Round 14
// 1626.516 us; speedup vs baseline: 1.1482x; 1.1482x over previous
//
#include <hip/hip_runtime.h>

#define B_   8
#define N_   1024
#define C_   768
#define H_   12
#define HD_  64
#define BH_  96
#define SCALE_ 0.125f
#define NIT_ 5

typedef __attribute__((ext_vector_type(8))) short bfrag;   // 8 bf16 (4 VGPR)
typedef __attribute__((ext_vector_type(4))) float facc;    // 4 f32  (4 VGPR)

__device__ __forceinline__ unsigned short bfhi(float x)
{
    return (unsigned short)(__float_as_uint(x) >> 16);
}
__device__ __forceinline__ unsigned short bflo(float x)
{
    const unsigned hu = __float_as_uint(x) & 0xffff0000u;
    return (unsigned short)(__float_as_uint(x - __uint_as_float(hu)) >> 16);
}
__device__ __forceinline__ unsigned int packhl(float v)
{
    return (unsigned int)bfhi(v) | ((unsigned int)bflo(v) << 16);
}
__device__ __forceinline__ bfrag pack_hi(float4 a, float4 b)
{
    bfrag r;
    r[0] = (short)bfhi(a.x); r[1] = (short)bfhi(a.y);
    r[2] = (short)bfhi(a.z); r[3] = (short)bfhi(a.w);
    r[4] = (short)bfhi(b.x); r[5] = (short)bfhi(b.y);
    r[6] = (short)bfhi(b.z); r[7] = (short)bfhi(b.w);
    return r;
}
__device__ __forceinline__ bfrag pack_lo(float4 a, float4 b)
{
    bfrag r;
    r[0] = (short)bflo(a.x); r[1] = (short)bflo(a.y);
    r[2] = (short)bflo(a.z); r[3] = (short)bflo(a.w);
    r[4] = (short)bflo(b.x); r[5] = (short)bflo(b.y);
    r[6] = (short)bflo(b.z); r[7] = (short)bflo(b.w);
    return r;
}

// ---------------------------------------------------------------------------
// split_flat: fp32 array -> bf16 hi/lo arrays, same layout.  grid 3072 x 256.
// ---------------------------------------------------------------------------
__global__ __launch_bounds__(256)
void split_flat(const float* __restrict__ In,
                unsigned short* __restrict__ Oh, unsigned short* __restrict__ Ol)
{
    const size_t i = ((size_t)blockIdx.x * 256 + threadIdx.x) * 8;
    const float4 a = *(const float4*)(In + i);
    const float4 b = *(const float4*)(In + i + 4);
    *(bfrag*)(Oh + i) = pack_hi(a, b);
    *(bfrag*)(Ol + i) = pack_lo(a, b);
}

// ---------------------------------------------------------------------------
// split_wt: W [768][ncols] fp32 -> Wt hi/lo [ncols][768] bf16 (transposed).
// grid (ncols/64, 768/64=12) x 256.  Run once per weight.
// ---------------------------------------------------------------------------
__global__ __launch_bounds__(256)
void split_wt(const float* __restrict__ W, int ncols,
              unsigned short* __restrict__ Th, unsigned short* __restrict__ Tl)
{
    __shared__ float Ts[64][68];
    const int tid = threadIdx.x;
    const int c0 = blockIdx.x * 64;
    const int k0 = blockIdx.y * 64;

    {
        int e = tid;
#pragma unroll
        for (int t = 0; t < 4; ++t, e += 256) {
            const int r = e >> 4, c4 = (e & 15) << 2;
            *(float4*)&Ts[r][c4] =
                *(const float4*)(W + (size_t)(k0 + r) * ncols + c0 + c4);
        }
    }
    __syncthreads();

#pragma unroll
    for (int t = 0; t < 2; ++t) {
        const int idx = t * 2048 + tid * 8;
        const int cr = idx >> 6, ck = idx & 63;
        bfrag h8, l8;
#pragma unroll
        for (int q = 0; q < 8; ++q) {
            const float v = Ts[ck + q][cr];
            h8[q] = (short)bfhi(v);
            l8[q] = (short)bflo(v);
        }
        const size_t go = (size_t)(c0 + cr) * 768 + k0 + ck;
        *(bfrag*)(Th + go) = h8;
        *(bfrag*)(Tl + go) = l8;
    }
}

// ---------------------------------------------------------------------------
// K1 qkv_mfma (unchanged from R10/R11, verified).
// ---------------------------------------------------------------------------
__global__ __launch_bounds__(256)
void qkv_mfma(const unsigned short* __restrict__ Xh, const unsigned short* __restrict__ Xl,
              const unsigned short* __restrict__ Wth, const unsigned short* __restrict__ Wtl,
              const float* __restrict__ bias,
              float* __restrict__ Kb, float* __restrict__ Vb)
{
    __shared__ short Ahs[64][72];
    __shared__ short Als[64][72];
    __shared__ short Bhs[64][72];
    __shared__ short Bls[64][72];

    const int tid  = threadIdx.x;
    const int lane = tid & 63;
    const int w    = tid >> 6;
    const int g    = lane >> 4;
    const int r16  = lane & 15;
    const int m0   = blockIdx.y * 64;
    const int c0   = blockIdx.x * 64;     // [0,1536)

    facc o0 = {0.f, 0.f, 0.f, 0.f};
    facc o1 = {0.f, 0.f, 0.f, 0.f};
    facc o2 = {0.f, 0.f, 0.f, 0.f};
    facc o3 = {0.f, 0.f, 0.f, 0.f};

    const int i0 = tid * 8,        r0 = i0 >> 6, cc0 = i0 & 63;
    const int i1 = 2048 + tid * 8, r1 = i1 >> 6, cc1 = i1 & 63;

    bfrag ta0 = *(const bfrag*)(Xh + (size_t)(m0 + r0) * 768 + cc0);
    bfrag ta1 = *(const bfrag*)(Xh + (size_t)(m0 + r1) * 768 + cc1);
    bfrag tb0 = *(const bfrag*)(Xl + (size_t)(m0 + r0) * 768 + cc0);
    bfrag tb1 = *(const bfrag*)(Xl + (size_t)(m0 + r1) * 768 + cc1);
    bfrag tw0 = *(const bfrag*)(Wth + (size_t)(c0 + r0) * 768 + cc0);
    bfrag tw1 = *(const bfrag*)(Wth + (size_t)(c0 + r1) * 768 + cc1);
    bfrag tz0 = *(const bfrag*)(Wtl + (size_t)(c0 + r0) * 768 + cc0);
    bfrag tz1 = *(const bfrag*)(Wtl + (size_t)(c0 + r1) * 768 + cc1);

    for (int ks = 0; ks < 12; ++ks) {
        __syncthreads();
        *(bfrag*)&Ahs[r0][cc0] = ta0;  *(bfrag*)&Ahs[r1][cc1] = ta1;
        *(bfrag*)&Als[r0][cc0] = tb0;  *(bfrag*)&Als[r1][cc1] = tb1;
        *(bfrag*)&Bhs[r0][cc0] = tw0;  *(bfrag*)&Bhs[r1][cc1] = tw1;
        *(bfrag*)&Bls[r0][cc0] = tz0;  *(bfrag*)&Bls[r1][cc1] = tz1;
        if (ks + 1 < 12) {
            const int kn = (ks + 1) * 64;
            ta0 = *(const bfrag*)(Xh + (size_t)(m0 + r0) * 768 + kn + cc0);
            ta1 = *(const bfrag*)(Xh + (size_t)(m0 + r1) * 768 + kn + cc1);
            tb0 = *(const bfrag*)(Xl + (size_t)(m0 + r0) * 768 + kn + cc0);
            tb1 = *(const bfrag*)(Xl + (size_t)(m0 + r1) * 768 + kn + cc1);
            tw0 = *(const bfrag*)(Wth + (size_t)(c0 + r0) * 768 + kn + cc0);
            tw1 = *(const bfrag*)(Wth + (size_t)(c0 + r1) * 768 + kn + cc1);
            tz0 = *(const bfrag*)(Wtl + (size_t)(c0 + r0) * 768 + kn + cc0);
            tz1 = *(const bfrag*)(Wtl + (size_t)(c0 + r1) * 768 + kn + cc1);
        }
        __syncthreads();

        const bfrag ah0 = *(const bfrag*)&Ahs[16 * w + r16][8 * g];
        const bfrag ah1 = *(const bfrag*)&Ahs[16 * w + r16][32 + 8 * g];
        const bfrag al0 = *(const bfrag*)&Als[16 * w + r16][8 * g];
        const bfrag al1 = *(const bfrag*)&Als[16 * w + r16][32 + 8 * g];
        {
            bfrag b0 = *(const bfrag*)&Bhs[r16][8 * g];
            bfrag b1 = *(const bfrag*)&Bhs[r16][32 + 8 * g];
            bfrag c1 = *(const bfrag*)&Bls[r16][8 * g];
            bfrag c2 = *(const bfrag*)&Bls[r16][32 + 8 * g];
            o0 = __builtin_amdgcn_mfma_f32_16x16x32_bf16(ah0, b0, o0, 0, 0, 0);
            o0 = __builtin_amdgcn_mfma_f32_16x16x32_bf16(al0, b0, o0, 0, 0, 0);
            o0 = __builtin_amdgcn_mfma_f32_16x16x32_bf16(ah0, c1, o0, 0, 0, 0);
            o0 = __builtin_amdgcn_mfma_f32_16x16x32_bf16(ah1, b1, o0, 0, 0, 0);
            o0 = __builtin_amdgcn_mfma_f32_16x16x32_bf16(al1, b1, o0, 0, 0, 0);
            o0 = __builtin_amdgcn_mfma_f32_16x16x32_bf16(ah1, c2, o0, 0, 0, 0);
        }
        {
            bfrag b0 = *(const bfrag*)&Bhs[16 + r16][8 * g];
            bfrag b1 = *(const bfrag*)&Bhs[16 + r16][32 + 8 * g];
            bfrag c1 = *(const bfrag*)&Bls[16 + r16][8 * g];
            bfrag c2 = *(const bfrag*)&Bls[16 + r16][32 + 8 * g];
            o1 = __builtin_amdgcn_mfma_f32_16x16x32_bf16(ah0, b0, o1, 0, 0, 0);
            o1 = __builtin_amdgcn_mfma_f32_16x16x32_bf16(al0, b0, o1, 0, 0, 0);
            o1 = __builtin_amdgcn_mfma_f32_16x16x32_bf16(ah0, c1, o1, 0, 0, 0);
            o1 = __builtin_amdgcn_mfma_f32_16x16x32_bf16(ah1, b1, o1, 0, 0, 0);
            o1 = __builtin_amdgcn_mfma_f32_16x16x32_bf16(al1, b1, o1, 0, 0, 0);
            o1 = __builtin_amdgcn_mfma_f32_16x16x32_bf16(ah1, c2, o1, 0, 0, 0);
        }
        {
            bfrag b0 = *(const bfrag*)&Bhs[32 + r16][8 * g];
            bfrag b1 = *(const bfrag*)&Bhs[32 + r16][32 + 8 * g];
            bfrag c1 = *(const bfrag*)&Bls[32 + r16][8 * g];
            bfrag c2 = *(const bfrag*)&Bls[32 + r16][32 + 8 * g];
            o2 = __builtin_amdgcn_mfma_f32_16x16x32_bf16(ah0, b0, o2, 0, 0, 0);
            o2 = __builtin_amdgcn_mfma_f32_16x16x32_bf16(al0, b0, o2, 0, 0, 0);
            o2 = __builtin_amdgcn_mfma_f32_16x16x32_bf16(ah0, c1, o2, 0, 0, 0);
            o2 = __builtin_amdgcn_mfma_f32_16x16x32_bf16(ah1, b1, o2, 0, 0, 0);
            o2 = __builtin_amdgcn_mfma_f32_16x16x32_bf16(al1, b1, o2, 0, 0, 0);
            o2 = __builtin_amdgcn_mfma_f32_16x16x32_bf16(ah1, c2, o2, 0, 0, 0);
        }
        {
            bfrag b0 = *(const bfrag*)&Bhs[48 + r16][8 * g];
            bfrag b1 = *(const bfrag*)&Bhs[48 + r16][32 + 8 * g];
            bfrag c1 = *(const bfrag*)&Bls[48 + r16][8 * g];
            bfrag c2 = *(const bfrag*)&Bls[48 + r16][32 + 8 * g];
            o3 = __builtin_amdgcn_mfma_f32_16x16x32_bf16(ah0, b0, o3, 0, 0, 0);
            o3 = __builtin_amdgcn_mfma_f32_16x16x32_bf16(al0, b0, o3, 0, 0, 0);
            o3 = __builtin_amdgcn_mfma_f32_16x16x32_bf16(ah0, c1, o3, 0, 0, 0);
            o3 = __builtin_amdgcn_mfma_f32_16x16x32_bf16(ah1, b1, o3, 0, 0, 0);
            o3 = __builtin_amdgcn_mfma_f32_16x16x32_bf16(al1, b1, o3, 0, 0, 0);
            o3 = __builtin_amdgcn_mfma_f32_16x16x32_bf16(ah1, c2, o3, 0, 0, 0);
        }
    }

    const int h = (c0 % C_) >> 6;
    float* tgt = (c0 < C_) ? Kb : Vb;
    const float bb0 = bias[c0 + r16];
    const float bb1 = bias[c0 + 16 + r16];
    const float bb2 = bias[c0 + 32 + r16];
    const float bb3 = bias[c0 + 48 + r16];

    const int mrow = m0 + 16 * w + 4 * g;
    const int bidx = mrow >> 10;
    const int nidx = mrow & 1023;
    float* trow = tgt + ((size_t)(bidx * H_ + h) * N_ + nidx) * HD_ + r16;
    trow[0 * HD_ + 0]  = o0.x + bb0; trow[0 * HD_ + 16] = o1.x + bb1;
    trow[0 * HD_ + 32] = o2.x + bb2; trow[0 * HD_ + 48] = o3.x + bb3;
    trow[1 * HD_ + 0]  = o0.y + bb0; trow[1 * HD_ + 16] = o1.y + bb1;
    trow[1 * HD_ + 32] = o2.y + bb2; trow[1 * HD_ + 48] = o3.y + bb3;
    trow[2 * HD_ + 0]  = o0.z + bb0; trow[2 * HD_ + 16] = o1.z + bb1;
    trow[2 * HD_ + 32] = o2.z + bb2; trow[2 * HD_ + 48] = o3.z + bb3;
    trow[3 * HD_ + 0]  = o0.w + bb0; trow[3 * HD_ + 16] = o1.w + bb1;
    trow[3 * HD_ + 32] = o2.w + bb2; trow[3 * HD_ + 48] = o3.w + bb3;
}

// ---------------------------------------------------------------------------
// K7 proj_mfma (unchanged from R10/R11, verified).
// ---------------------------------------------------------------------------
__global__ __launch_bounds__(256)
void proj_mfma(const unsigned short* __restrict__ Lh, const unsigned short* __restrict__ Ll,
               const unsigned short* __restrict__ Wth, const unsigned short* __restrict__ Wtl,
               const float* __restrict__ bias, float* __restrict__ Out)
{
    __shared__ short Ahs[64][72];
    __shared__ short Als[64][72];
    __shared__ short Bhs[64][72];
    __shared__ short Bls[64][72];

    const int tid  = threadIdx.x;
    const int lane = tid & 63;
    const int w    = tid >> 6;
    const int g    = lane >> 4;
    const int r16  = lane & 15;
    const int m0   = blockIdx.y * 64;
    const int c0   = blockIdx.x * 64;     // [0,768)

    facc o0 = {0.f, 0.f, 0.f, 0.f};
    facc o1 = {0.f, 0.f, 0.f, 0.f};
    facc o2 = {0.f, 0.f, 0.f, 0.f};
    facc o3 = {0.f, 0.f, 0.f, 0.f};

    const int i0 = tid * 8,        r0 = i0 >> 6, cc0 = i0 & 63;
    const int i1 = 2048 + tid * 8, r1 = i1 >> 6, cc1 = i1 & 63;
    const int t0 = m0 + r0, ab0 = t0 >> 10, an0 = t0 & 1023;
    const int t1 = m0 + r1, ab1 = t1 >> 10, an1 = t1 & 1023;

    bfrag ta0 = *(const bfrag*)(Lh + ((size_t)(ab0 * H_) * N_ + an0) * HD_ + cc0);
    bfrag ta1 = *(const bfrag*)(Lh + ((size_t)(ab1 * H_) * N_ + an1) * HD_ + cc1);
    bfrag tb0 = *(const bfrag*)(Ll + ((size_t)(ab0 * H_) * N_ + an0) * HD_ + cc0);
    bfrag tb1 = *(const bfrag*)(Ll + ((size_t)(ab1 * H_) * N_ + an1) * HD_ + cc1);
    bfrag tw0 = *(const bfrag*)(Wth + (size_t)(c0 + r0) * 768 + cc0);
    bfrag tw1 = *(const bfrag*)(Wth + (size_t)(c0 + r1) * 768 + cc1);
    bfrag tz0 = *(const bfrag*)(Wtl + (size_t)(c0 + r0) * 768 + cc0);
    bfrag tz1 = *(const bfrag*)(Wtl + (size_t)(c0 + r1) * 768 + cc1);

    for (int ks = 0; ks < 12; ++ks) {
        __syncthreads();
        *(bfrag*)&Ahs[r0][cc0] = ta0;  *(bfrag*)&Ahs[r1][cc1] = ta1;
        *(bfrag*)&Als[r0][cc0] = tb0;  *(bfrag*)&Als[r1][cc1] = tb1;
        *(bfrag*)&Bhs[r0][cc0] = tw0;  *(bfrag*)&Bhs[r1][cc1] = tw1;
        *(bfrag*)&Bls[r0][cc0] = tz0;  *(bfrag*)&Bls[r1][cc1] = tz1;
        if (ks + 1 < 12) {
            const int kn = ks + 1;
            const size_t ga0 = ((size_t)(ab0 * H_ + kn) * N_ + an0) * HD_ + cc0;
            const size_t ga1 = ((size_t)(ab1 * H_ + kn) * N_ + an1) * HD_ + cc1;
            ta0 = *(const bfrag*)(Lh + ga0);
            ta1 = *(const bfrag*)(Lh + ga1);
            tb0 = *(const bfrag*)(Ll + ga0);
            tb1 = *(const bfrag*)(Ll + ga1);
            tw0 = *(const bfrag*)(Wth + (size_t)(c0 + r0) * 768 + kn * 64 + cc0);
            tw1 = *(const bfrag*)(Wth + (size_t)(c0 + r1) * 768 + kn * 64 + cc1);
            tz0 = *(const bfrag*)(Wtl + (size_t)(c0 + r0) * 768 + kn * 64 + cc0);
            tz1 = *(const bfrag*)(Wtl + (size_t)(c0 + r1) * 768 + kn * 64 + cc1);
        }
        __syncthreads();

        const bfrag ah0 = *(const bfrag*)&Ahs[16 * w + r16][8 * g];
        const bfrag ah1 = *(const bfrag*)&Ahs[16 * w + r16][32 + 8 * g];
        const bfrag al0 = *(const bfrag*)&Als[16 * w + r16][8 * g];
        const bfrag al1 = *(const bfrag*)&Als[16 * w + r16][32 + 8 * g];
        {
            bfrag b0 = *(const bfrag*)&Bhs[r16][8 * g];
            bfrag b1 = *(const bfrag*)&Bhs[r16][32 + 8 * g];
            bfrag c1 = *(const bfrag*)&Bls[r16][8 * g];
            bfrag c2 = *(const bfrag*)&Bls[r16][32 + 8 * g];
            o0 = __builtin_amdgcn_mfma_f32_16x16x32_bf16(ah0, b0, o0, 0, 0, 0);
            o0 = __builtin_amdgcn_mfma_f32_16x16x32_bf16(al0, b0, o0, 0, 0, 0);
            o0 = __builtin_amdgcn_mfma_f32_16x16x32_bf16(ah0, c1, o0, 0, 0, 0);
            o0 = __builtin_amdgcn_mfma_f32_16x16x32_bf16(ah1, b1, o0, 0, 0, 0);
            o0 = __builtin_amdgcn_mfma_f32_16x16x32_bf16(al1, b1, o0, 0, 0, 0);
            o0 = __builtin_amdgcn_mfma_f32_16x16x32_bf16(ah1, c2, o0, 0, 0, 0);
        }
        {
            bfrag b0 = *(const bfrag*)&Bhs[16 + r16][8 * g];
            bfrag b1 = *(const bfrag*)&Bhs[16 + r16][32 + 8 * g];
            bfrag c1 = *(const bfrag*)&Bls[16 + r16][8 * g];
            bfrag c2 = *(const bfrag*)&Bls[16 + r16][32 + 8 * g];
            o1 = __builtin_amdgcn_mfma_f32_16x16x32_bf16(ah0, b0, o1, 0, 0, 0);
            o1 = __builtin_amdgcn_mfma_f32_16x16x32_bf16(al0, b0, o1, 0, 0, 0);
            o1 = __builtin_amdgcn_mfma_f32_16x16x32_bf16(ah0, c1, o1, 0, 0, 0);
            o1 = __builtin_amdgcn_mfma_f32_16x16x32_bf16(ah1, b1, o1, 0, 0, 0);
            o1 = __builtin_amdgcn_mfma_f32_16x16x32_bf16(al1, b1, o1, 0, 0, 0);
            o1 = __builtin_amdgcn_mfma_f32_16x16x32_bf16(ah1, c2, o1, 0, 0, 0);
        }
        {
            bfrag b0 = *(const bfrag*)&Bhs[32 + r16][8 * g];
            bfrag b1 = *(const bfrag*)&Bhs[32 + r16][32 + 8 * g];
            bfrag c1 = *(const bfrag*)&Bls[32 + r16][8 * g];
            bfrag c2 = *(const bfrag*)&Bls[32 + r16][32 + 8 * g];
            o2 = __builtin_amdgcn_mfma_f32_16x16x32_bf16(ah0, b0, o2, 0, 0, 0);
            o2 = __builtin_amdgcn_mfma_f32_16x16x32_bf16(al0, b0, o2, 0, 0, 0);
            o2 = __builtin_amdgcn_mfma_f32_16x16x32_bf16(ah0, c1, o2, 0, 0, 0);
            o2 = __builtin_amdgcn_mfma_f32_16x16x32_bf16(ah1, b1, o2, 0, 0, 0);
            o2 = __builtin_amdgcn_mfma_f32_16x16x32_bf16(al1, b1, o2, 0, 0, 0);
            o2 = __builtin_amdgcn_mfma_f32_16x16x32_bf16(ah1, c2, o2, 0, 0, 0);
        }
        {
            bfrag b0 = *(const bfrag*)&Bhs[48 + r16][8 * g];
            bfrag b1 = *(const bfrag*)&Bhs[48 + r16][32 + 8 * g];
            bfrag c1 = *(const bfrag*)&Bls[48 + r16][8 * g];
            bfrag c2 = *(const bfrag*)&Bls[48 + r16][32 + 8 * g];
            o3 = __builtin_amdgcn_mfma_f32_16x16x32_bf16(ah0, b0, o3, 0, 0, 0);
            o3 = __builtin_amdgcn_mfma_f32_16x16x32_bf16(al0, b0, o3, 0, 0, 0);
            o3 = __builtin_amdgcn_mfma_f32_16x16x32_bf16(ah0, c1, o3, 0, 0, 0);
            o3 = __builtin_amdgcn_mfma_f32_16x16x32_bf16(ah1, b1, o3, 0, 0, 0);
            o3 = __builtin_amdgcn_mfma_f32_16x16x32_bf16(al1, b1, o3, 0, 0, 0);
            o3 = __builtin_amdgcn_mfma_f32_16x16x32_bf16(ah1, c2, o3, 0, 0, 0);
        }
    }

    const float bb0 = bias[c0 + r16];
    const float bb1 = bias[c0 + 16 + r16];
    const float bb2 = bias[c0 + 32 + r16];
    const float bb3 = bias[c0 + 48 + r16];
    float* orow = Out + (size_t)(m0 + 16 * w + 4 * g) * C_ + c0 + r16;
    orow[0 * C_ + 0]  = o0.x + bb0; orow[0 * C_ + 16] = o1.x + bb1;
    orow[0 * C_ + 32] = o2.x + bb2; orow[0 * C_ + 48] = o3.x + bb3;
    orow[1 * C_ + 0]  = o0.y + bb0; orow[1 * C_ + 16] = o1.y + bb1;
    orow[1 * C_ + 32] = o2.y + bb2; orow[1 * C_ + 48] = o3.y + bb3;
    orow[2 * C_ + 0]  = o0.z + bb0; orow[2 * C_ + 16] = o1.z + bb1;
    orow[2 * C_ + 32] = o2.z + bb2; orow[2 * C_ + 48] = o3.z + bb3;
    orow[3 * C_ + 0]  = o0.w + bb0; orow[3 * C_ + 16] = o1.w + bb1;
    orow[3 * C_ + 32] = o2.w + bb2; orow[3 * C_ + 48] = o3.w + bb3;
}

// ---------------------------------------------------------------------------
// K2: mu[bh] = (N*C/4) / sum|k| per (b,h).
// ---------------------------------------------------------------------------
__global__ __launch_bounds__(256)
void musum(const float* __restrict__ Kb, float* __restrict__ mu)
{
    const int bh = blockIdx.x;
    const int tid = threadIdx.x;
    const float* p = Kb + (size_t)bh * (N_ * HD_);
    float s = 0.0f;
    for (int i = tid; i < N_ * HD_; i += 256) s += fabsf(p[i]);
    for (int off = 32; off; off >>= 1) s += __shfl_down(s, off, 64);
    __shared__ float red[4];
    if ((tid & 63) == 0) red[tid >> 6] = s;
    __syncthreads();
    if (tid == 0)
        mu[bh] = (float)(N_ * C_ / 4.0) / (red[0] + red[1] + red[2] + red[3]);
}

// ---------------------------------------------------------------------------
// K3/K5 fused.  upd==0 path uses l=y=0 EXACTLY.
// ---------------------------------------------------------------------------
__global__ __launch_bounds__(256)
void ew_fused(const float* __restrict__ Kb, const float* __restrict__ Lb,
              float* __restrict__ Yb, const float* __restrict__ mu,
              float* __restrict__ K2b,
              unsigned short* __restrict__ K2h, unsigned short* __restrict__ K2l,
              int upd)
{
    const int i = blockIdx.x * 256 + threadIdx.x;
    const int bh = i >> 16;
    const float m = mu[bh];
    const float lm = 4.0f * m;
    const float kv = Kb[i];
    float k2;
    if (upd) {
        const float lv = Lb[i];
        const float y = 2.0f * Yb[i] + m * (K2b[i] - lv);
        Yb[i] = y;
        const float yom = y / m;
        const float t = kv - lv + yom;
        const float s = (t >= lm) ? (t - lm) : ((t <= -lm) ? (t + lm) : 0.0f);
        k2 = kv - s - yom;
    } else {
        Yb[i] = 0.0f;
        const float t = kv;
        const float s = (t >= lm) ? (t - lm) : ((t <= -lm) ? (t + lm) : 0.0f);
        k2 = kv - s;
    }
    K2b[i] = k2;
    K2h[i] = bfhi(k2);
    K2l[i] = bflo(k2);
}

// ---------------------------------------------------------------------------
// K3c: Vt hi/lo bf16, transposed to [bh][d][n].  Run ONCE.
// ---------------------------------------------------------------------------
__global__ __launch_bounds__(256)
void vt_split(const float* __restrict__ Vb,
              unsigned short* __restrict__ Vth, unsigned short* __restrict__ Vtl)
{
    __shared__ float Ts[64][68];
    const int tid = threadIdx.x;
    const int bh = blockIdx.y;
    const int n0 = blockIdx.x * 64;
    const float* vb = Vb + ((size_t)bh * N_ + n0) * HD_;

    {
        int e = tid;
#pragma unroll
        for (int t = 0; t < 4; ++t, e += 256) {
            const int r = e >> 4, c4 = (e & 15) << 2;
            *(float4*)&Ts[r][c4] = *(const float4*)(vb + r * HD_ + c4);
        }
    }
    __syncthreads();

#pragma unroll
    for (int t = 0; t < 2; ++t) {
        const int idx = t * 2048 + tid * 8;
        const int d = idx >> 6, c = idx & 63;
        bfrag h8, l8;
#pragma unroll
        for (int q = 0; q < 8; ++q) {
            const float v = Ts[c + q][d];
            h8[q] = (short)bfhi(v);
            l8[q] = (short)bflo(v);
        }
        const size_t go = ((size_t)bh * HD_ + d) * N_ + n0 + c;
        *(bfrag*)(Vth + go) = h8;
        *(bfrag*)(Vtl + go) = l8;
    }
}

// ---------------------------------------------------------------------------
// K4 flash-MFMA v5: R11 structure + PACKED P (hi|lo<<16 in one uint LDS
// array aliased onto K's storage).  P writes per q-set: 32 b16 -> 16 b32;
// PV reads de-interleave with VALU bit-ops (co-issues with MFMA pipe).
// Reconstructed operand bits and MFMA order unchanged -> absmax bit-exact.
// grid (8, 96) x 256.
// ---------------------------------------------------------------------------
__global__ __launch_bounds__(256)
void flash(const unsigned short* __restrict__ K2h, const unsigned short* __restrict__ K2l,
           const unsigned short* __restrict__ Vth, const unsigned short* __restrict__ Vtl,
           float* __restrict__ Lout, float* __restrict__ Mrow, float* __restrict__ Zrow,
           unsigned short* __restrict__ Lbh, unsigned short* __restrict__ Lbl, int wsplit)
{
    __shared__ __attribute__((aligned(16))) short KPbuf[2 * 64 * 72];
    __shared__ short Vh[64][72];
    __shared__ short Vl[64][72];
    short (*Kh)[72] = (short(*)[72])KPbuf;
    short (*Kl)[72] = (short(*)[72])(KPbuf + 64 * 72);
    unsigned int (*Pu)[68] = (unsigned int(*)[68])KPbuf;   // 17.4 KB <= 18.4 KB

    const int tid  = threadIdx.x;
    const int lane = tid & 63;
    const int w    = tid >> 6;
    const int g    = lane >> 4;
    const int r16  = lane & 15;
    const int bh   = blockIdx.y;
    const int q0   = blockIdx.x * 128;

    const unsigned short* kh = K2h + (size_t)bh * (N_ * HD_);
    const unsigned short* kl = K2l + (size_t)bh * (N_ * HD_);
    const unsigned short* vh = Vth + (size_t)bh * (N_ * HD_);
    const unsigned short* vl = Vtl + (size_t)bh * (N_ * HD_);

    const size_t qoffA = (size_t)(q0 + 16 * w + r16) * HD_ + 8 * g;
    const size_t qoffB = (size_t)(q0 + 64 + 16 * w + r16) * HD_ + 8 * g;
    const bfrag qhA0 = *(const bfrag*)(kh + qoffA);
    const bfrag qhA1 = *(const bfrag*)(kh + qoffA + 32);
    const bfrag qlA0 = *(const bfrag*)(kl + qoffA);
    const bfrag qlA1 = *(const bfrag*)(kl + qoffA + 32);
    const bfrag qhB0 = *(const bfrag*)(kh + qoffB);
    const bfrag qhB1 = *(const bfrag*)(kh + qoffB + 32);
    const bfrag qlB0 = *(const bfrag*)(kl + qoffB);
    const bfrag qlB1 = *(const bfrag*)(kl + qoffB + 32);

    const int i0 = tid * 8,        r0 = i0 >> 6, cc0 = i0 & 63;
    const int i1 = 2048 + tid * 8, r1 = i1 >> 6, cc1 = i1 & 63;

    bfrag pk0 = *(const bfrag*)(kh + i0);
    bfrag pk1 = *(const bfrag*)(kh + i1);
    bfrag pm0 = *(const bfrag*)(kl + i0);
    bfrag pm1 = *(const bfrag*)(kl + i1);

    float mrA0 = -1e30f, mrA1 = -1e30f, mrA2 = -1e30f, mrA3 = -1e30f;
    float zrA0 = 0.0f,  zrA1 = 0.0f,  zrA2 = 0.0f,  zrA3 = 0.0f;
    float mrB0 = -1e30f, mrB1 = -1e30f, mrB2 = -1e30f, mrB3 = -1e30f;
    float zrB0 = 0.0f,  zrB1 = 0.0f,  zrB2 = 0.0f,  zrB3 = 0.0f;
    facc oA0 = {0.f, 0.f, 0.f, 0.f};
    facc oA1 = {0.f, 0.f, 0.f, 0.f};
    facc oA2 = {0.f, 0.f, 0.f, 0.f};
    facc oA3 = {0.f, 0.f, 0.f, 0.f};
    facc oB0 = {0.f, 0.f, 0.f, 0.f};
    facc oB1 = {0.f, 0.f, 0.f, 0.f};
    facc oB2 = {0.f, 0.f, 0.f, 0.f};
    facc oB3 = {0.f, 0.f, 0.f, 0.f};

    for (int kt = 0; kt < 16; ++kt) {
        __syncthreads();   // bar1: prev tile's Pu (=K storage) and V reads done
        *(bfrag*)&Kh[r0][cc0] = pk0;  *(bfrag*)&Kh[r1][cc1] = pk1;
        *(bfrag*)&Kl[r0][cc0] = pm0;  *(bfrag*)&Kl[r1][cc1] = pm1;
        const bfrag tv0 = *(const bfrag*)(vh + (size_t)r0 * N_ + kt * 64 + cc0);
        const bfrag tv1 = *(const bfrag*)(vh + (size_t)r1 * N_ + kt * 64 + cc1);
        const bfrag tw0 = *(const bfrag*)(vl + (size_t)r0 * N_ + kt * 64 + cc0);
        const bfrag tw1 = *(const bfrag*)(vl + (size_t)r1 * N_ + kt * 64 + cc1);
        if (kt + 1 < 16) {
            const size_t gn = (size_t)(kt + 1) * 4096;
            pk0 = *(const bfrag*)(kh + gn + i0);
            pk1 = *(const bfrag*)(kh + gn + i1);
            pm0 = *(const bfrag*)(kl + gn + i0);
            pm1 = *(const bfrag*)(kl + gn + i1);
        }
        __syncthreads();   // bar2: K tile visible

        facc sA0 = {0.f, 0.f, 0.f, 0.f};
        facc sA1 = {0.f, 0.f, 0.f, 0.f};
        facc sA2 = {0.f, 0.f, 0.f, 0.f};
        facc sA3 = {0.f, 0.f, 0.f, 0.f};
        facc sB0 = {0.f, 0.f, 0.f, 0.f};
        facc sB1 = {0.f, 0.f, 0.f, 0.f};
        facc sB2 = {0.f, 0.f, 0.f, 0.f};
        facc sB3 = {0.f, 0.f, 0.f, 0.f};
        {
            bfrag b0 = *(const bfrag*)&Kh[r16][8 * g];
            bfrag b1 = *(const bfrag*)&Kh[r16][32 + 8 * g];
            bfrag c0 = *(const bfrag*)&Kl[r16][8 * g];
            bfrag c1 = *(const bfrag*)&Kl[r16][32 + 8 * g];
            sA0 = __builtin_amdgcn_mfma_f32_16x16x32_bf16(qhA0, b0, sA0, 0, 0, 0);
            sA0 = __builtin_amdgcn_mfma_f32_16x16x32_bf16(qlA0, b0, sA0, 0, 0, 0);
            sA0 = __builtin_amdgcn_mfma_f32_16x16x32_bf16(qhA0, c0, sA0, 0, 0, 0);
            sA0 = __builtin_amdgcn_mfma_f32_16x16x32_bf16(qhA1, b1, sA0, 0, 0, 0);
            sA0 = __builtin_amdgcn_mfma_f32_16x16x32_bf16(qlA1, b1, sA0, 0, 0, 0);
            sA0 = __builtin_amdgcn_mfma_f32_16x16x32_bf16(qhA1, c1, sA0, 0, 0, 0);
            sB0 = __builtin_amdgcn_mfma_f32_16x16x32_bf16(qhB0, b0, sB0, 0, 0, 0);
            sB0 = __builtin_amdgcn_mfma_f32_16x16x32_bf16(qlB0, b0, sB0, 0, 0, 0);
            sB0 = __builtin_amdgcn_mfma_f32_16x16x32_bf16(qhB0, c0, sB0, 0, 0, 0);
            sB0 = __builtin_amdgcn_mfma_f32_16x16x32_bf16(qhB1, b1, sB0, 0, 0, 0);
            sB0 = __builtin_amdgcn_mfma_f32_16x16x32_bf16(qlB1, b1, sB0, 0, 0, 0);
            sB0 = __builtin_amdgcn_mfma_f32_16x16x32_bf16(qhB1, c1, sB0, 0, 0, 0);
        }
        {
            bfrag b0 = *(const bfrag*)&Kh[16 + r16][8 * g];
            bfrag b1 = *(const bfrag*)&Kh[16 + r16][32 + 8 * g];
            bfrag c0 = *(const bfrag*)&Kl[16 + r16][8 * g];
            bfrag c1 = *(const bfrag*)&Kl[16 + r16][32 + 8 * g];
            sA1 = __builtin_amdgcn_mfma_f32_16x16x32_bf16(qhA0, b0, sA1, 0, 0, 0);
            sA1 = __builtin_amdgcn_mfma_f32_16x16x32_bf16(qlA0, b0, sA1, 0, 0, 0);
            sA1 = __builtin_amdgcn_mfma_f32_16x16x32_bf16(qhA0, c0, sA1, 0, 0, 0);
            sA1 = __builtin_amdgcn_mfma_f32_16x16x32_bf16(qhA1, b1, sA1, 0, 0, 0);
            sA1 = __builtin_amdgcn_mfma_f32_16x16x32_bf16(qlA1, b1, sA1, 0, 0, 0);
            sA1 = __builtin_amdgcn_mfma_f32_16x16x32_bf16(qhA1, c1, sA1, 0, 0, 0);
            sB1 = __builtin_amdgcn_mfma_f32_16x16x32_bf16(qhB0, b0, sB1, 0, 0, 0);
            sB1 = __builtin_amdgcn_mfma_f32_16x16x32_bf16(qlB0, b0, sB1, 0, 0, 0);
            sB1 = __builtin_amdgcn_mfma_f32_16x16x32_bf16(qhB0, c0, sB1, 0, 0, 0);
            sB1 = __builtin_amdgcn_mfma_f32_16x16x32_bf16(qhB1, b1, sB1, 0, 0, 0);
            sB1 = __builtin_amdgcn_mfma_f32_16x16x32_bf16(qlB1, b1, sB1, 0, 0, 0);
            sB1 = __builtin_amdgcn_mfma_f32_16x16x32_bf16(qhB1, c1, sB1, 0, 0, 0);
        }
        {
            bfrag b0 = *(const bfrag*)&Kh[32 + r16][8 * g];
            bfrag b1 = *(const bfrag*)&Kh[32 + r16][32 + 8 * g];
            bfrag c0 = *(const bfrag*)&Kl[32 + r16][8 * g];
            bfrag c1 = *(const bfrag*)&Kl[32 + r16][32 + 8 * g];
            sA2 = __builtin_amdgcn_mfma_f32_16x16x32_bf16(qhA0, b0, sA2, 0, 0, 0);
            sA2 = __builtin_amdgcn_mfma_f32_16x16x32_bf16(qlA0, b0, sA2, 0, 0, 0);
            sA2 = __builtin_amdgcn_mfma_f32_16x16x32_bf16(qhA0, c0, sA2, 0, 0, 0);
            sA2 = __builtin_amdgcn_mfma_f32_16x16x32_bf16(qhA1, b1, sA2, 0, 0, 0);
            sA2 = __builtin_amdgcn_mfma_f32_16x16x32_bf16(qlA1, b1, sA2, 0, 0, 0);
            sA2 = __builtin_amdgcn_mfma_f32_16x16x32_bf16(qhA1, c1, sA2, 0, 0, 0);
            sB2 = __builtin_amdgcn_mfma_f32_16x16x32_bf16(qhB0, b0, sB2, 0, 0, 0);
            sB2 = __builtin_amdgcn_mfma_f32_16x16x32_bf16(qlB0, b0, sB2, 0, 0, 0);
            sB2 = __builtin_amdgcn_mfma_f32_16x16x32_bf16(qhB0, c0, sB2, 0, 0, 0);
            sB2 = __builtin_amdgcn_mfma_f32_16x16x32_bf16(qhB1, b1, sB2, 0, 0, 0);
            sB2 = __builtin_amdgcn_mfma_f32_16x16x32_bf16(qlB1, b1, sB2, 0, 0, 0);
            sB2 = __builtin_amdgcn_mfma_f32_16x16x32_bf16(qhB1, c1, sB2, 0, 0, 0);
        }
        {
            bfrag b0 = *(const bfrag*)&Kh[48 + r16][8 * g];
            bfrag b1 = *(const bfrag*)&Kh[48 + r16][32 + 8 * g];
            bfrag c0 = *(const bfrag*)&Kl[48 + r16][8 * g];
            bfrag c1 = *(const bfrag*)&Kl[48 + r16][32 + 8 * g];
            sA3 = __builtin_amdgcn_mfma_f32_16x16x32_bf16(qhA0, b0, sA3, 0, 0, 0);
            sA3 = __builtin_amdgcn_mfma_f32_16x16x32_bf16(qlA0, b0, sA3, 0, 0, 0);
            sA3 = __builtin_amdgcn_mfma_f32_16x16x32_bf16(qhA0, c0, sA3, 0, 0, 0);
            sA3 = __builtin_amdgcn_mfma_f32_16x16x32_bf16(qhA1, b1, sA3, 0, 0, 0);
            sA3 = __builtin_amdgcn_mfma_f32_16x16x32_bf16(qlA1, b1, sA3, 0, 0, 0);
            sA3 = __builtin_amdgcn_mfma_f32_16x16x32_bf16(qhA1, c1, sA3, 0, 0, 0);
            sB3 = __builtin_amdgcn_mfma_f32_16x16x32_bf16(qhB0, b0, sB3, 0, 0, 0);
            sB3 = __builtin_amdgcn_mfma_f32_16x16x32_bf16(qlB0, b0, sB3, 0, 0, 0);
            sB3 = __builtin_amdgcn_mfma_f32_16x16x32_bf16(qhB0, c0, sB3, 0, 0, 0);
            sB3 = __builtin_amdgcn_mfma_f32_16x16x32_bf16(qhB1, b1, sB3, 0, 0, 0);
            sB3 = __builtin_amdgcn_mfma_f32_16x16x32_bf16(qlB1, b1, sB3, 0, 0, 0);
            sB3 = __builtin_amdgcn_mfma_f32_16x16x32_bf16(qhB1, c1, sB3, 0, 0, 0);
        }

        sA0 = sA0 * SCALE_;  sA1 = sA1 * SCALE_;  sA2 = sA2 * SCALE_;  sA3 = sA3 * SCALE_;
        sB0 = sB0 * SCALE_;  sB1 = sB1 * SCALE_;  sB2 = sB2 * SCALE_;  sB3 = sB3 * SCALE_;

        // ---- softmax A ----
        float mt0 = fmaxf(fmaxf(sA0.x, sA1.x), fmaxf(sA2.x, sA3.x));
        float mt1 = fmaxf(fmaxf(sA0.y, sA1.y), fmaxf(sA2.y, sA3.y));
        float mt2 = fmaxf(fmaxf(sA0.z, sA1.z), fmaxf(sA2.z, sA3.z));
        float mt3 = fmaxf(fmaxf(sA0.w, sA1.w), fmaxf(sA2.w, sA3.w));
        for (int off = 8; off; off >>= 1) {
            mt0 = fmaxf(mt0, __shfl_xor(mt0, off, 16));
            mt1 = fmaxf(mt1, __shfl_xor(mt1, off, 16));
            mt2 = fmaxf(mt2, __shfl_xor(mt2, off, 16));
            mt3 = fmaxf(mt3, __shfl_xor(mt3, off, 16));
        }
        const float mnA0 = fmaxf(mrA0, mt0), mnA1 = fmaxf(mrA1, mt1);
        const float mnA2 = fmaxf(mrA2, mt2), mnA3 = fmaxf(mrA3, mt3);
        const float aA0 = __expf(mrA0 - mnA0), aA1 = __expf(mrA1 - mnA1);
        const float aA2 = __expf(mrA2 - mnA2), aA3 = __expf(mrA3 - mnA3);
        mrA0 = mnA0; mrA1 = mnA1; mrA2 = mnA2; mrA3 = mnA3;

        const float paA0 = __expf(sA0.x - mnA0), paA1 = __expf(sA0.y - mnA1);
        const float paA2 = __expf(sA0.z - mnA2), paA3 = __expf(sA0.w - mnA3);
        const float pbA0 = __expf(sA1.x - mnA0), pbA1 = __expf(sA1.y - mnA1);
        const float pbA2 = __expf(sA1.z - mnA2), pbA3 = __expf(sA1.w - mnA3);
        const float pcA0 = __expf(sA2.x - mnA0), pcA1 = __expf(sA2.y - mnA1);
        const float pcA2 = __expf(sA2.z - mnA2), pcA3 = __expf(sA2.w - mnA3);
        const float pdA0 = __expf(sA3.x - mnA0), pdA1 = __expf(sA3.y - mnA1);
        const float pdA2 = __expf(sA3.z - mnA2), pdA3 = __expf(sA3.w - mnA3);

        float zsA0 = paA0 + pbA0 + pcA0 + pdA0;
        float zsA1 = paA1 + pbA1 + pcA1 + pdA1;
        float zsA2 = paA2 + pbA2 + pcA2 + pdA2;
        float zsA3 = paA3 + pbA3 + pcA3 + pdA3;
        for (int off = 8; off; off >>= 1) {
            zsA0 += __shfl_xor(zsA0, off, 16);
            zsA1 += __shfl_xor(zsA1, off, 16);
            zsA2 += __shfl_xor(zsA2, off, 16);
            zsA3 += __shfl_xor(zsA3, off, 16);
        }
        zrA0 = zrA0 * aA0 + zsA0;  zrA1 = zrA1 * aA1 + zsA1;
        zrA2 = zrA2 * aA2 + zsA2;  zrA3 = zrA3 * aA3 + zsA3;
        oA0.x *= aA0; oA0.y *= aA1; oA0.z *= aA2; oA0.w *= aA3;
        oA1.x *= aA0; oA1.y *= aA1; oA1.z *= aA2; oA1.w *= aA3;
        oA2.x *= aA0; oA2.y *= aA1; oA2.z *= aA2; oA2.w *= aA3;
        oA3.x *= aA0; oA3.y *= aA1; oA3.z *= aA2; oA3.w *= aA3;

        // ---- softmax B ----
        mt0 = fmaxf(fmaxf(sB0.x, sB1.x), fmaxf(sB2.x, sB3.x));
        mt1 = fmaxf(fmaxf(sB0.y, sB1.y), fmaxf(sB2.y, sB3.y));
        mt2 = fmaxf(fmaxf(sB0.z, sB1.z), fmaxf(sB2.z, sB3.z));
        mt3 = fmaxf(fmaxf(sB0.w, sB1.w), fmaxf(sB2.w, sB3.w));
        for (int off = 8; off; off >>= 1) {
            mt0 = fmaxf(mt0, __shfl_xor(mt0, off, 16));
            mt1 = fmaxf(mt1, __shfl_xor(mt1, off, 16));
            mt2 = fmaxf(mt2, __shfl_xor(mt2, off, 16));
            mt3 = fmaxf(mt3, __shfl_xor(mt3, off, 16));
        }
        const float mnB0 = fmaxf(mrB0, mt0), mnB1 = fmaxf(mrB1, mt1);
        const float mnB2 = fmaxf(mrB2, mt2), mnB3 = fmaxf(mrB3, mt3);
        const float aB0 = __expf(mrB0 - mnB0), aB1 = __expf(mrB1 - mnB1);
        const float aB2 = __expf(mrB2 - mnB2), aB3 = __expf(mrB3 - mnB3);
        mrB0 = mnB0; mrB1 = mnB1; mrB2 = mnB2; mrB3 = mnB3;

        const float paB0 = __expf(sB0.x - mnB0), paB1 = __expf(sB0.y - mnB1);
        const float paB2 = __expf(sB0.z - mnB2), paB3 = __expf(sB0.w - mnB3);
        const float pbB0 = __expf(sB1.x - mnB0), pbB1 = __expf(sB1.y - mnB1);
        const float pbB2 = __expf(sB1.z - mnB2), pbB3 = __expf(sB1.w - mnB3);
        const float pcB0 = __expf(sB2.x - mnB0), pcB1 = __expf(sB2.y - mnB1);
        const float pcB2 = __expf(sB2.z - mnB2), pcB3 = __expf(sB2.w - mnB3);
        const float pdB0 = __expf(sB3.x - mnB0), pdB1 = __expf(sB3.y - mnB1);
        const float pdB2 = __expf(sB3.z - mnB2), pdB3 = __expf(sB3.w - mnB3);

        float zsB0 = paB0 + pbB0 + pcB0 + pdB0;
        float zsB1 = paB1 + pbB1 + pcB1 + pdB1;
        float zsB2 = paB2 + pbB2 + pcB2 + pdB2;
        float zsB3 = paB3 + pbB3 + pcB3 + pdB3;
        for (int off = 8; off; off >>= 1) {
            zsB0 += __shfl_xor(zsB0, off, 16);
            zsB1 += __shfl_xor(zsB1, off, 16);
            zsB2 += __shfl_xor(zsB2, off, 16);
            zsB3 += __shfl_xor(zsB3, off, 16);
        }
        zrB0 = zrB0 * aB0 + zsB0;  zrB1 = zrB1 * aB1 + zsB1;
        zrB2 = zrB2 * aB2 + zsB2;  zrB3 = zrB3 * aB3 + zsB3;
        oB0.x *= aB0; oB0.y *= aB1; oB0.z *= aB2; oB0.w *= aB3;
        oB1.x *= aB0; oB1.y *= aB1; oB1.z *= aB2; oB1.w *= aB3;
        oB2.x *= aB0; oB2.y *= aB1; oB2.z *= aB2; oB2.w *= aB3;
        oB3.x *= aB0; oB3.y *= aB1; oB3.z *= aB2; oB3.w *= aB3;

        // V stage: loads issued before bar2, latency hidden under S+softmax
        *(bfrag*)&Vh[r0][cc0] = tv0;  *(bfrag*)&Vh[r1][cc1] = tv1;
        *(bfrag*)&Vl[r0][cc0] = tw0;  *(bfrag*)&Vl[r1][cc1] = tw1;

        __syncthreads();   // bar3: all K reads done; V visible to all waves

        const int pr = 16 * w + 4 * g;
        const int prow = 16 * w + r16;
        // ---- P_A -> LDS (packed hi|lo uint); PV_A ----
        Pu[pr + 0][r16]      = packhl(paA0);
        Pu[pr + 1][r16]      = packhl(paA1);
        Pu[pr + 2][r16]      = packhl(paA2);
        Pu[pr + 3][r16]      = packhl(paA3);
        Pu[pr + 0][16 + r16] = packhl(pbA0);
        Pu[pr + 1][16 + r16] = packhl(pbA1);
        Pu[pr + 2][16 + r16] = packhl(pbA2);
        Pu[pr + 3][16 + r16] = packhl(pbA3);
        Pu[pr + 0][32 + r16] = packhl(pcA0);
        Pu[pr + 1][32 + r16] = packhl(pcA1);
        Pu[pr + 2][32 + r16] = packhl(pcA2);
        Pu[pr + 3][32 + r16] = packhl(pcA3);
        Pu[pr + 0][48 + r16] = packhl(pdA0);
        Pu[pr + 1][48 + r16] = packhl(pdA1);
        Pu[pr + 2][48 + r16] = packhl(pdA2);
        Pu[pr + 3][48 + r16] = packhl(pdA3);
        __builtin_amdgcn_wave_barrier();
        {
            const uint4 pu0 = *(const uint4*)&Pu[prow][8 * g];
            const uint4 pu1 = *(const uint4*)&Pu[prow][8 * g + 4];
            const uint4 pu2 = *(const uint4*)&Pu[prow][32 + 8 * g];
            const uint4 pu3 = *(const uint4*)&Pu[prow][32 + 8 * g + 4];
            uint4 uh0, ul0, uh1, ul1;
            uh0.x = (pu0.x & 0xffffu) | (pu0.y << 16);
            uh0.y = (pu0.z & 0xffffu) | (pu0.w << 16);
            uh0.z = (pu1.x & 0xffffu) | (pu1.y << 16);
            uh0.w = (pu1.z & 0xffffu) | (pu1.w << 16);
            ul0.x = (pu0.x >> 16) | (pu0.y & 0xffff0000u);
            ul0.y = (pu0.z >> 16) | (pu0.w & 0xffff0000u);
            ul0.z = (pu1.x >> 16) | (pu1.y & 0xffff0000u);
            ul0.w = (pu1.z >> 16) | (pu1.w & 0xffff0000u);
            uh1.x = (pu2.x & 0xffffu) | (pu2.y << 16);
            uh1.y = (pu2.z & 0xffffu) | (pu2.w << 16);
            uh1.z = (pu3.x & 0xffffu) | (pu3.y << 16);
            uh1.w = (pu3.z & 0xffffu) | (pu3.w << 16);
            ul1.x = (pu2.x >> 16) | (pu2.y & 0xffff0000u);
            ul1.y = (pu2.z >> 16) | (pu2.w & 0xffff0000u);
            ul1.z = (pu3.x >> 16) | (pu3.y & 0xffff0000u);
            ul1.w = (pu3.z >> 16) | (pu3.w & 0xffff0000u);
            const bfrag ph0 = *(const bfrag*)&uh0;
            const bfrag pl0 = *(const bfrag*)&ul0;
            const bfrag ph1 = *(const bfrag*)&uh1;
            const bfrag pl1 = *(const bfrag*)&ul1;
            {
                bfrag b0 = *(const bfrag*)&Vh[r16][8 * g];
                bfrag b1 = *(const bfrag*)&Vh[r16][32 + 8 * g];
                bfrag c0 = *(const bfrag*)&Vl[r16][8 * g];
                bfrag c1 = *(const bfrag*)&Vl[r16][32 + 8 * g];
                oA0 = __builtin_amdgcn_mfma_f32_16x16x32_bf16(ph0, b0, oA0, 0, 0, 0);
                oA0 = __builtin_amdgcn_mfma_f32_16x16x32_bf16(pl0, b0, oA0, 0, 0, 0);
                oA0 = __builtin_amdgcn_mfma_f32_16x16x32_bf16(ph0, c0, oA0, 0, 0, 0);
                oA0 = __builtin_amdgcn_mfma_f32_16x16x32_bf16(ph1, b1, oA0, 0, 0, 0);
                oA0 = __builtin_amdgcn_mfma_f32_16x16x32_bf16(pl1, b1, oA0, 0, 0, 0);
                oA0 = __builtin_amdgcn_mfma_f32_16x16x32_bf16(ph1, c1, oA0, 0, 0, 0);
            }
            {
                bfrag b0 = *(const bfrag*)&Vh[16 + r16][8 * g];
                bfrag b1 = *(const bfrag*)&Vh[16 + r16][32 + 8 * g];
                bfrag c0 = *(const bfrag*)&Vl[16 + r16][8 * g];
                bfrag c1 = *(const bfrag*)&Vl[16 + r16][32 + 8 * g];
                oA1 = __builtin_amdgcn_mfma_f32_16x16x32_bf16(ph0, b0, oA1, 0, 0, 0);
                oA1 = __builtin_amdgcn_mfma_f32_16x16x32_bf16(pl0, b0, oA1, 0, 0, 0);
                oA1 = __builtin_amdgcn_mfma_f32_16x16x32_bf16(ph0, c0, oA1, 0, 0, 0);
                oA1 = __builtin_amdgcn_mfma_f32_16x16x32_bf16(ph1, b1, oA1, 0, 0, 0);
                oA1 = __builtin_amdgcn_mfma_f32_16x16x32_bf16(pl1, b1, oA1, 0, 0, 0);
                oA1 = __builtin_amdgcn_mfma_f32_16x16x32_bf16(ph1, c1, oA1, 0, 0, 0);
            }
            {
                bfrag b0 = *(const bfrag*)&Vh[32 + r16][8 * g];
                bfrag b1 = *(const bfrag*)&Vh[32 + r16][32 + 8 * g];
                bfrag c0 = *(const bfrag*)&Vl[32 + r16][8 * g];
                bfrag c1 = *(const bfrag*)&Vl[32 + r16][32 + 8 * g];
                oA2 = __builtin_amdgcn_mfma_f32_16x16x32_bf16(ph0, b0, oA2, 0, 0, 0);
                oA2 = __builtin_amdgcn_mfma_f32_16x16x32_bf16(pl0, b0, oA2, 0, 0, 0);
                oA2 = __builtin_amdgcn_mfma_f32_16x16x32_bf16(ph0, c0, oA2, 0, 0, 0);
                oA2 = __builtin_amdgcn_mfma_f32_16x16x32_bf16(ph1, b1, oA2, 0, 0, 0);
                oA2 = __builtin_amdgcn_mfma_f32_16x16x32_bf16(pl1, b1, oA2, 0, 0, 0);
                oA2 = __builtin_amdgcn_mfma_f32_16x16x32_bf16(ph1, c1, oA2, 0, 0, 0);
            }
            {
                bfrag b0 = *(const bfrag*)&Vh[48 + r16][8 * g];
                bfrag b1 = *(const bfrag*)&Vh[48 + r16][32 + 8 * g];
                bfrag c0 = *(const bfrag*)&Vl[48 + r16][8 * g];
                bfrag c1 = *(const bfrag*)&Vl[48 + r16][32 + 8 * g];
                oA3 = __builtin_amdgcn_mfma_f32_16x16x32_bf16(ph0, b0, oA3, 0, 0, 0);
                oA3 = __builtin_amdgcn_mfma_f32_16x16x32_bf16(pl0, b0, oA3, 0, 0, 0);
                oA3 = __builtin_amdgcn_mfma_f32_16x16x32_bf16(ph0, c0, oA3, 0, 0, 0);
                oA3 = __builtin_amdgcn_mfma_f32_16x16x32_bf16(ph1, b1, oA3, 0, 0, 0);
                oA3 = __builtin_amdgcn_mfma_f32_16x16x32_bf16(pl1, b1, oA3, 0, 0, 0);
                oA3 = __builtin_amdgcn_mfma_f32_16x16x32_bf16(ph1, c1, oA3, 0, 0, 0);
            }
        }
        __builtin_amdgcn_wave_barrier();   // PV_A P-reads done (own wave)

        // ---- P_B -> LDS (same wave-private band); PV_B ----
        Pu[pr + 0][r16]      = packhl(paB0);
        Pu[pr + 1][r16]      = packhl(paB1);
        Pu[pr + 2][r16]      = packhl(paB2);
        Pu[pr + 3][r16]      = packhl(paB3);
        Pu[pr + 0][16 + r16] = packhl(pbB0);
        Pu[pr + 1][16 + r16] = packhl(pbB1);
        Pu[pr + 2][16 + r16] = packhl(pbB2);
        Pu[pr + 3][16 + r16] = packhl(pbB3);
        Pu[pr + 0][32 + r16] = packhl(pcB0);
        Pu[pr + 1][32 + r16] = packhl(pcB1);
        Pu[pr + 2][32 + r16] = packhl(pcB2);
        Pu[pr + 3][32 + r16] = packhl(pcB3);
        Pu[pr + 0][48 + r16] = packhl(pdB0);
        Pu[pr + 1][48 + r16] = packhl(pdB1);
        Pu[pr + 2][48 + r16] = packhl(pdB2);
        Pu[pr + 3][48 + r16] = packhl(pdB3);
        __builtin_amdgcn_wave_barrier();
        {
            const uint4 pu0 = *(const uint4*)&Pu[prow][8 * g];
            const uint4 pu1 = *(const uint4*)&Pu[prow][8 * g + 4];
            const uint4 pu2 = *(const uint4*)&Pu[prow][32 + 8 * g];
            const uint4 pu3 = *(const uint4*)&Pu[prow][32 + 8 * g + 4];
            uint4 uh0, ul0, uh1, ul1;
            uh0.x = (pu0.x & 0xffffu) | (pu0.y << 16);
            uh0.y = (pu0.z & 0xffffu) | (pu0.w << 16);
            uh0.z = (pu1.x & 0xffffu) | (pu1.y << 16);
            uh0.w = (pu1.z & 0xffffu) | (pu1.w << 16);
            ul0.x = (pu0.x >> 16) | (pu0.y & 0xffff0000u);
            ul0.y = (pu0.z >> 16) | (pu0.w & 0xffff0000u);
            ul0.z = (pu1.x >> 16) | (pu1.y & 0xffff0000u);
            ul0.w = (pu1.z >> 16) | (pu1.w & 0xffff0000u);
            uh1.x = (pu2.x & 0xffffu) | (pu2.y << 16);
            uh1.y = (pu2.z & 0xffffu) | (pu2.w << 16);
            uh1.z = (pu3.x & 0xffffu) | (pu3.y << 16);
            uh1.w = (pu3.z & 0xffffu) | (pu3.w << 16);
            ul1.x = (pu2.x >> 16) | (pu2.y & 0xffff0000u);
            ul1.y = (pu2.z >> 16) | (pu2.w & 0xffff0000u);
            ul1.z = (pu3.x >> 16) | (pu3.y & 0xffff0000u);
            ul1.w = (pu3.z >> 16) | (pu3.w & 0xffff0000u);
            const bfrag ph0 = *(const bfrag*)&uh0;
            const bfrag pl0 = *(const bfrag*)&ul0;
            const bfrag ph1 = *(const bfrag*)&uh1;
            const bfrag pl1 = *(const bfrag*)&ul1;
            {
                bfrag b0 = *(const bfrag*)&Vh[r16][8 * g];
                bfrag b1 = *(const bfrag*)&Vh[r16][32 + 8 * g];
                bfrag c0 = *(const bfrag*)&Vl[r16][8 * g];
                bfrag c1 = *(const bfrag*)&Vl[r16][32 + 8 * g];
                oB0 = __builtin_amdgcn_mfma_f32_16x16x32_bf16(ph0, b0, oB0, 0, 0, 0);
                oB0 = __builtin_amdgcn_mfma_f32_16x16x32_bf16(pl0, b0, oB0, 0, 0, 0);
                oB0 = __builtin_amdgcn_mfma_f32_16x16x32_bf16(ph0, c0, oB0, 0, 0, 0);
                oB0 = __builtin_amdgcn_mfma_f32_16x16x32_bf16(ph1, b1, oB0, 0, 0, 0);
                oB0 = __builtin_amdgcn_mfma_f32_16x16x32_bf16(pl1, b1, oB0, 0, 0, 0);
                oB0 = __builtin_amdgcn_mfma_f32_16x16x32_bf16(ph1, c1, oB0, 0, 0, 0);
            }
            {
                bfrag b0 = *(const bfrag*)&Vh[16 + r16][8 * g];
                bfrag b1 = *(const bfrag*)&Vh[16 + r16][32 + 8 * g];
                bfrag c0 = *(const bfrag*)&Vl[16 + r16][8 * g];
                bfrag c1 = *(const bfrag*)&Vl[16 + r16][32 + 8 * g];
                oB1 = __builtin_amdgcn_mfma_f32_16x16x32_bf16(ph0, b0, oB1, 0, 0, 0);
                oB1 = __builtin_amdgcn_mfma_f32_16x16x32_bf16(pl0, b0, oB1, 0, 0, 0);
                oB1 = __builtin_amdgcn_mfma_f32_16x16x32_bf16(ph0, c0, oB1, 0, 0, 0);
                oB1 = __builtin_amdgcn_mfma_f32_16x16x32_bf16(ph1, b1, oB1, 0, 0, 0);
                oB1 = __builtin_amdgcn_mfma_f32_16x16x32_bf16(pl1, b1, oB1, 0, 0, 0);
                oB1 = __builtin_amdgcn_mfma_f32_16x16x32_bf16(ph1, c1, oB1, 0, 0, 0);
            }
            {
                bfrag b0 = *(const bfrag*)&Vh[32 + r16][8 * g];
                bfrag b1 = *(const bfrag*)&Vh[32 + r16][32 + 8 * g];
                bfrag c0 = *(const bfrag*)&Vl[32 + r16][8 * g];
                bfrag c1 = *(const bfrag*)&Vl[32 + r16][32 + 8 * g];
                oB2 = __builtin_amdgcn_mfma_f32_16x16x32_bf16(ph0, b0, oB2, 0, 0, 0);
                oB2 = __builtin_amdgcn_mfma_f32_16x16x32_bf16(pl0, b0, oB2, 0, 0, 0);
                oB2 = __builtin_amdgcn_mfma_f32_16x16x32_bf16(ph0, c0, oB2, 0, 0, 0);
                oB2 = __builtin_amdgcn_mfma_f32_16x16x32_bf16(ph1, b1, oB2, 0, 0, 0);
                oB2 = __builtin_amdgcn_mfma_f32_16x16x32_bf16(pl1, b1, oB2, 0, 0, 0);
                oB2 = __builtin_amdgcn_mfma_f32_16x16x32_bf16(ph1, c1, oB2, 0, 0, 0);
            }
            {
                bfrag b0 = *(const bfrag*)&Vh[48 + r16][8 * g];
                bfrag b1 = *(const bfrag*)&Vh[48 + r16][32 + 8 * g];
                bfrag c0 = *(const bfrag*)&Vl[48 + r16][8 * g];
                bfrag c1 = *(const bfrag*)&Vl[48 + r16][32 + 8 * g];
                oB3 = __builtin_amdgcn_mfma_f32_16x16x32_bf16(ph0, b0, oB3, 0, 0, 0);
                oB3 = __builtin_amdgcn_mfma_f32_16x16x32_bf16(pl0, b0, oB3, 0, 0, 0);
                oB3 = __builtin_amdgcn_mfma_f32_16x16x32_bf16(ph0, c0, oB3, 0, 0, 0);
                oB3 = __builtin_amdgcn_mfma_f32_16x16x32_bf16(ph1, b1, oB3, 0, 0, 0);
                oB3 = __builtin_amdgcn_mfma_f32_16x16x32_bf16(pl1, b1, oB3, 0, 0, 0);
                oB3 = __builtin_amdgcn_mfma_f32_16x16x32_bf16(ph1, c1, oB3, 0, 0, 0);
            }
        }
    }

    // ---- epilogue A ----
    {
        const float zi0 = 1.0f / zrA0, zi1 = 1.0f / zrA1;
        const float zi2 = 1.0f / zrA2, zi3 = 1.0f / zrA3;
        const size_t base = ((size_t)bh * N_ + q0 + 16 * w + 4 * g) * HD_ + r16;
        float* lrow = Lout + base;
        const float v00 = oA0.x * zi0, v01 = oA1.x * zi0, v02 = oA2.x * zi0, v03 = oA3.x * zi0;
        const float v10 = oA0.y * zi1, v11 = oA1.y * zi1, v12 = oA2.y * zi1, v13 = oA3.y * zi1;
        const float v20 = oA0.z * zi2, v21 = oA1.z * zi2, v22 = oA2.z * zi2, v23 = oA3.z * zi2;
        const float v30 = oA0.w * zi3, v31 = oA1.w * zi3, v32 = oA2.w * zi3, v33 = oA3.w * zi3;
        lrow[0 * HD_ + 0] = v00; lrow[0 * HD_ + 16] = v01; lrow[0 * HD_ + 32] = v02; lrow[0 * HD_ + 48] = v03;
        lrow[1 * HD_ + 0] = v10; lrow[1 * HD_ + 16] = v11; lrow[1 * HD_ + 32] = v12; lrow[1 * HD_ + 48] = v13;
        lrow[2 * HD_ + 0] = v20; lrow[2 * HD_ + 16] = v21; lrow[2 * HD_ + 32] = v22; lrow[2 * HD_ + 48] = v23;
        lrow[3 * HD_ + 0] = v30; lrow[3 * HD_ + 16] = v31; lrow[3 * HD_ + 32] = v32; lrow[3 * HD_ + 48] = v33;
        if (wsplit) {
            Lbh[base + 0 * HD_ + 0] = bfhi(v00); Lbl[base + 0 * HD_ + 0] = bflo(v00);
            Lbh[base + 0 * HD_ + 16] = bfhi(v01); Lbl[base + 0 * HD_ + 16] = bflo(v01);
            Lbh[base + 0 * HD_ + 32] = bfhi(v02); Lbl[base + 0 * HD_ + 32] = bflo(v02);
            Lbh[base + 0 * HD_ + 48] = bfhi(v03); Lbl[base + 0 * HD_ + 48] = bflo(v03);
            Lbh[base + 1 * HD_ + 0] = bfhi(v10); Lbl[base + 1 * HD_ + 0] = bflo(v10);
            Lbh[base + 1 * HD_ + 16] = bfhi(v11); Lbl[base + 1 * HD_ + 16] = bflo(v11);
            Lbh[base + 1 * HD_ + 32] = bfhi(v12); Lbl[base + 1 * HD_ + 32] = bflo(v12);
            Lbh[base + 1 * HD_ + 48] = bfhi(v13); Lbl[base + 1 * HD_ + 48] = bflo(v13);
            Lbh[base + 2 * HD_ + 0] = bfhi(v20); Lbl[base + 2 * HD_ + 0] = bflo(v20);
            Lbh[base + 2 * HD_ + 16] = bfhi(v21); Lbl[base + 2 * HD_ + 16] = bflo(v21);
            Lbh[base + 2 * HD_ + 32] = bfhi(v22); Lbl[base + 2 * HD_ + 32] = bflo(v22);
            Lbh[base + 2 * HD_ + 48] = bfhi(v23); Lbl[base + 2 * HD_ + 48] = bflo(v23);
            Lbh[base + 3 * HD_ + 0] = bfhi(v30); Lbl[base + 3 * HD_ + 0] = bflo(v30);
            Lbh[base + 3 * HD_ + 16] = bfhi(v31); Lbl[base + 3 * HD_ + 16] = bflo(v31);
            Lbh[base + 3 * HD_ + 32] = bfhi(v32); Lbl[base + 3 * HD_ + 32] = bflo(v32);
            Lbh[base + 3 * HD_ + 48] = bfhi(v33); Lbl[base + 3 * HD_ + 48] = bflo(v33);
        }
        if (r16 == 0) {
            const size_t rb = (size_t)bh * N_ + q0 + 16 * w + 4 * g;
            Mrow[rb + 0] = mrA0; Mrow[rb + 1] = mrA1;
            Mrow[rb + 2] = mrA2; Mrow[rb + 3] = mrA3;
            Zrow[rb + 0] = zrA0; Zrow[rb + 1] = zrA1;
            Zrow[rb + 2] = zrA2; Zrow[rb + 3] = zrA3;
        }
    }
    // ---- epilogue B ----
    {
        const float zi0 = 1.0f / zrB0, zi1 = 1.0f / zrB1;
        const float zi2 = 1.0f / zrB2, zi3 = 1.0f / zrB3;
        const size_t base = ((size_t)bh * N_ + q0 + 64 + 16 * w + 4 * g) * HD_ + r16;
        float* lrow = Lout + base;
        const float v00 = oB0.x * zi0, v01 = oB1.x * zi0, v02 = oB2.x * zi0, v03 = oB3.x * zi0;
        const float v10 = oB0.y * zi1, v11 = oB1.y * zi1, v12 = oB2.y * zi1, v13 = oB3.y * zi1;
        const float v20 = oB0.z * zi2, v21 = oB1.z * zi2, v22 = oB2.z * zi2, v23 = oB3.z * zi2;
        const float v30 = oB0.w * zi3, v31 = oB1.w * zi3, v32 = oB2.w * zi3, v33 = oB3.w * zi3;
        lrow[0 * HD_ + 0] = v00; lrow[0 * HD_ + 16] = v01; lrow[0 * HD_ + 32] = v02; lrow[0 * HD_ + 48] = v03;
        lrow[1 * HD_ + 0] = v10; lrow[1 * HD_ + 16] = v11; lrow[1 * HD_ + 32] = v12; lrow[1 * HD_ + 48] = v13;
        lrow[2 * HD_ + 0] = v20; lrow[2 * HD_ + 16] = v21; lrow[2 * HD_ + 32] = v22; lrow[2 * HD_ + 48] = v23;
        lrow[3 * HD_ + 0] = v30; lrow[3 * HD_ + 16] = v31; lrow[3 * HD_ + 32] = v32; lrow[3 * HD_ + 48] = v33;
        if (wsplit) {
            Lbh[base + 0 * HD_ + 0] = bfhi(v00); Lbl[base + 0 * HD_ + 0] = bflo(v00);
            Lbh[base + 0 * HD_ + 16] = bfhi(v01); Lbl[base + 0 * HD_ + 16] = bflo(v01);
            Lbh[base + 0 * HD_ + 32] = bfhi(v02); Lbl[base + 0 * HD_ + 32] = bflo(v02);
            Lbh[base + 0 * HD_ + 48] = bfhi(v03); Lbl[base + 0 * HD_ + 48] = bflo(v03);
            Lbh[base + 1 * HD_ + 0] = bfhi(v10); Lbl[base + 1 * HD_ + 0] = bflo(v10);
            Lbh[base + 1 * HD_ + 16] = bfhi(v11); Lbl[base + 1 * HD_ + 16] = bflo(v11);
            Lbh[base + 1 * HD_ + 32] = bfhi(v12); Lbl[base + 1 * HD_ + 32] = bflo(v12);
            Lbh[base + 1 * HD_ + 48] = bfhi(v13); Lbl[base + 1 * HD_ + 48] = bflo(v13);
            Lbh[base + 2 * HD_ + 0] = bfhi(v20); Lbl[base + 2 * HD_ + 0] = bflo(v20);
            Lbh[base + 2 * HD_ + 16] = bfhi(v21); Lbl[base + 2 * HD_ + 16] = bflo(v21);
            Lbh[base + 2 * HD_ + 32] = bfhi(v22); Lbl[base + 2 * HD_ + 32] = bflo(v22);
            Lbh[base + 2 * HD_ + 48] = bfhi(v23); Lbl[base + 2 * HD_ + 48] = bflo(v23);
            Lbh[base + 3 * HD_ + 0] = bfhi(v30); Lbl[base + 3 * HD_ + 0] = bflo(v30);
            Lbh[base + 3 * HD_ + 16] = bfhi(v31); Lbl[base + 3 * HD_ + 16] = bflo(v31);
            Lbh[base + 3 * HD_ + 32] = bfhi(v32); Lbl[base + 3 * HD_ + 32] = bflo(v32);
            Lbh[base + 3 * HD_ + 48] = bfhi(v33); Lbl[base + 3 * HD_ + 48] = bflo(v33);
        }
        if (r16 == 0) {
            const size_t rb = (size_t)bh * N_ + q0 + 64 + 16 * w + 4 * g;
            Mrow[rb + 0] = mrB0; Mrow[rb + 1] = mrB1;
            Mrow[rb + 2] = mrB2; Mrow[rb + 3] = mrB3;
            Zrow[rb + 0] = zrB0; Zrow[rb + 1] = zrB1;
            Zrow[rb + 2] = zrB2; Zrow[rb + 3] = zrB3;
        }
    }
}

// ---------------------------------------------------------------------------
// K6 attn_out_mfma (unchanged, verified).
// ---------------------------------------------------------------------------
__global__ __launch_bounds__(256)
void attn_out_mfma(const float* __restrict__ K2v, const float* __restrict__ Mrow,
                   const float* __restrict__ Zrow, float* __restrict__ A)
{
    __shared__ short Kh[64][72];
    __shared__ short Kl[64][72];

    const int tid  = threadIdx.x;
    const int lane = tid & 63;
    const int w    = tid >> 6;
    const int g    = lane >> 4;
    const int r16  = lane & 15;
    const int bh   = blockIdx.y;
    const int q0   = blockIdx.x * 64;
    const float* k2b = K2v + (size_t)bh * N_ * HD_;

    const int qrow = q0 + 16 * w + r16;
    const float4 f0 = *(const float4*)(k2b + (size_t)qrow * HD_ + 8 * g);
    const float4 f1 = *(const float4*)(k2b + (size_t)qrow * HD_ + 8 * g + 4);
    const float4 f2 = *(const float4*)(k2b + (size_t)qrow * HD_ + 32 + 8 * g);
    const float4 f3 = *(const float4*)(k2b + (size_t)qrow * HD_ + 32 + 8 * g + 4);
    const bfrag qh0 = pack_hi(f0, f1), ql0 = pack_lo(f0, f1);
    const bfrag qh1 = pack_hi(f2, f3), ql1 = pack_lo(f2, f3);

    const size_t mb = (size_t)bh * N_ + q0 + 16 * w + 4 * g;
    const float mi0 = Mrow[mb + 0], mi1 = Mrow[mb + 1];
    const float mi2 = Mrow[mb + 2], mi3 = Mrow[mb + 3];
    const float zi0 = 1.0f / Zrow[mb + 0], zi1 = 1.0f / Zrow[mb + 1];
    const float zi2 = 1.0f / Zrow[mb + 2], zi3 = 1.0f / Zrow[mb + 3];

    const int i0 = tid * 8,        r0 = i0 >> 6, cc0 = i0 & 63;
    const int i1 = 2048 + tid * 8, r1 = i1 >> 6, cc1 = i1 & 63;

    float4 a0 = *(const float4*)(k2b + (size_t)r0 * HD_ + cc0);
    float4 a1 = *(const float4*)(k2b + (size_t)r0 * HD_ + cc0 + 4);
    float4 b0v = *(const float4*)(k2b + (size_t)r1 * HD_ + cc1);
    float4 b1v = *(const float4*)(k2b + (size_t)r1 * HD_ + cc1 + 4);

    for (int kt = 0; kt < 16; ++kt) {
        __syncthreads();
        *(bfrag*)&Kh[r0][cc0] = pack_hi(a0, a1);
        *(bfrag*)&Kl[r0][cc0] = pack_lo(a0, a1);
        *(bfrag*)&Kh[r1][cc1] = pack_hi(b0v, b1v);
        *(bfrag*)&Kl[r1][cc1] = pack_lo(b0v, b1v);
        if (kt + 1 < 16) {
            const size_t gn = (size_t)(kt + 1) * 64;
            a0  = *(const float4*)(k2b + (gn + r0) * HD_ + cc0);
            a1  = *(const float4*)(k2b + (gn + r0) * HD_ + cc0 + 4);
            b0v = *(const float4*)(k2b + (gn + r1) * HD_ + cc1);
            b1v = *(const float4*)(k2b + (gn + r1) * HD_ + cc1 + 4);
        }
        __syncthreads();

        facc s0 = {0.f, 0.f, 0.f, 0.f};
        facc s1 = {0.f, 0.f, 0.f, 0.f};
        facc s2 = {0.f, 0.f, 0.f, 0.f};
        facc s3 = {0.f, 0.f, 0.f, 0.f};
        {
            bfrag b0 = *(const bfrag*)&Kh[r16][8 * g];
            bfrag b1 = *(const bfrag*)&Kh[r16][32 + 8 * g];
            bfrag c0 = *(const bfrag*)&Kl[r16][8 * g];
            bfrag c1 = *(const bfrag*)&Kl[r16][32 + 8 * g];
            s0 = __builtin_amdgcn_mfma_f32_16x16x32_bf16(qh0, b0, s0, 0, 0, 0);
            s0 = __builtin_amdgcn_mfma_f32_16x16x32_bf16(ql0, b0, s0, 0, 0, 0);
            s0 = __builtin_amdgcn_mfma_f32_16x16x32_bf16(qh0, c0, s0, 0, 0, 0);
            s0 = __builtin_amdgcn_mfma_f32_16x16x32_bf16(qh1, b1, s0, 0, 0, 0);
            s0 = __builtin_amdgcn_mfma_f32_16x16x32_bf16(ql1, b1, s0, 0, 0, 0);
            s0 = __builtin_amdgcn_mfma_f32_16x16x32_bf16(qh1, c1, s0, 0, 0, 0);
        }
        {
            bfrag b0 = *(const bfrag*)&Kh[16 + r16][8 * g];
            bfrag b1 = *(const bfrag*)&Kh[16 + r16][32 + 8 * g];
            bfrag c0 = *(const bfrag*)&Kl[16 + r16][8 * g];
            bfrag c1 = *(const bfrag*)&Kl[16 + r16][32 + 8 * g];
            s1 = __builtin_amdgcn_mfma_f32_16x16x32_bf16(qh0, b0, s1, 0, 0, 0);
            s1 = __builtin_amdgcn_mfma_f32_16x16x32_bf16(ql0, b0, s1, 0, 0, 0);
            s1 = __builtin_amdgcn_mfma_f32_16x16x32_bf16(qh0, c0, s1, 0, 0, 0);
            s1 = __builtin_amdgcn_mfma_f32_16x16x32_bf16(qh1, b1, s1, 0, 0, 0);
            s1 = __builtin_amdgcn_mfma_f32_16x16x32_bf16(ql1, b1, s1, 0, 0, 0);
            s1 = __builtin_amdgcn_mfma_f32_16x16x32_bf16(qh1, c1, s1, 0, 0, 0);
        }
        {
            bfrag b0 = *(const bfrag*)&Kh[32 + r16][8 * g];
            bfrag b1 = *(const bfrag*)&Kh[32 + r16][32 + 8 * g];
            bfrag c0 = *(const bfrag*)&Kl[32 + r16][8 * g];
            bfrag c1 = *(const bfrag*)&Kl[32 + r16][32 + 8 * g];
            s2 = __builtin_amdgcn_mfma_f32_16x16x32_bf16(qh0, b0, s2, 0, 0, 0);
            s2 = __builtin_amdgcn_mfma_f32_16x16x32_bf16(ql0, b0, s2, 0, 0, 0);
            s2 = __builtin_amdgcn_mfma_f32_16x16x32_bf16(qh0, c0, s2, 0, 0, 0);
            s2 = __builtin_amdgcn_mfma_f32_16x16x32_bf16(qh1, b1, s2, 0, 0, 0);
            s2 = __builtin_amdgcn_mfma_f32_16x16x32_bf16(ql1, b1, s2, 0, 0, 0);
            s2 = __builtin_amdgcn_mfma_f32_16x16x32_bf16(qh1, c1, s2, 0, 0, 0);
        }
        {
            bfrag b0 = *(const bfrag*)&Kh[48 + r16][8 * g];
            bfrag b1 = *(const bfrag*)&Kh[48 + r16][32 + 8 * g];
            bfrag c0 = *(const bfrag*)&Kl[48 + r16][8 * g];
            bfrag c1 = *(const bfrag*)&Kl[48 + r16][32 + 8 * g];
            s3 = __builtin_amdgcn_mfma_f32_16x16x32_bf16(qh0, b0, s3, 0, 0, 0);
            s3 = __builtin_amdgcn_mfma_f32_16x16x32_bf16(ql0, b0, s3, 0, 0, 0);
            s3 = __builtin_amdgcn_mfma_f32_16x16x32_bf16(qh0, c0, s3, 0, 0, 0);
            s3 = __builtin_amdgcn_mfma_f32_16x16x32_bf16(qh1, b1, s3, 0, 0, 0);
            s3 = __builtin_amdgcn_mfma_f32_16x16x32_bf16(ql1, b1, s3, 0, 0, 0);
            s3 = __builtin_amdgcn_mfma_f32_16x16x32_bf16(qh1, c1, s3, 0, 0, 0);
        }

        s0 = s0 * SCALE_;  s1 = s1 * SCALE_;  s2 = s2 * SCALE_;  s3 = s3 * SCALE_;

        float* ar0 = A + (mb + 0) * N_ + kt * 64;
        float* ar1 = A + (mb + 1) * N_ + kt * 64;
        float* ar2 = A + (mb + 2) * N_ + kt * 64;
        float* ar3 = A + (mb + 3) * N_ + kt * 64;
        ar0[r16]      = __expf(s0.x - mi0) * zi0;
        ar0[16 + r16] = __expf(s1.x - mi0) * zi0;
        ar0[32 + r16] = __expf(s2.x - mi0) * zi0;
        ar0[48 + r16] = __expf(s3.x - mi0) * zi0;
        ar1[r16]      = __expf(s0.y - mi1) * zi1;
        ar1[16 + r16] = __expf(s1.y - mi1) * zi1;
        ar1[32 + r16] = __expf(s2.y - mi1) * zi1;
        ar1[48 + r16] = __expf(s3.y - mi1) * zi1;
        ar2[r16]      = __expf(s0.z - mi2) * zi2;
        ar2[16 + r16] = __expf(s1.z - mi2) * zi2;
        ar2[32 + r16] = __expf(s2.z - mi2) * zi2;
        ar2[48 + r16] = __expf(s3.z - mi2) * zi2;
        ar3[r16]      = __expf(s0.w - mi3) * zi3;
        ar3[16 + r16] = __expf(s1.w - mi3) * zi3;
        ar3[32 + r16] = __expf(s2.w - mi3) * zi3;
        ar3[48 + r16] = __expf(s3.w - mi3) * zi3;
    }
}

// ---------------------------------------------------------------------------
// d_out FLOAT32: out = d_out[0..6291456), attn = d_out[6291456..).
// ws (floats): kb@0, vb@SZ, lb@2SZ, yb@3SZ, k2b@4SZ, mu@5SZ(128), rowm, rowz.
// bf16 scratch lives in the attn output region; proj runs BEFORE attn_out.
// ---------------------------------------------------------------------------
extern "C" void kernel_launch(void* const* d_in, const int* in_sizes, int n_in,
                              void* d_out, int out_size, void* d_ws, size_t ws_size,
                              hipStream_t stream)
{
    (void)in_sizes; (void)n_in; (void)out_size; (void)ws_size;

    const float* x  = (const float*)d_in[0];
    const float* Wq = (const float*)d_in[1];
    const float* bq = (const float*)d_in[2];
    const float* Wp = (const float*)d_in[3];
    const float* bp = (const float*)d_in[4];

    float* out_f  = (float*)d_out;
    float* attn_f = out_f + (size_t)B_ * N_ * C_;

    const size_t SZ = (size_t)BH_ * N_ * HD_;   // 6,291,456
    float* ws   = (float*)d_ws;
    float* kb   = ws;
    float* vb   = ws + SZ;
    float* lb   = ws + 2 * SZ;
    float* yb   = ws + 3 * SZ;
    float* k2b  = ws + 4 * SZ;
    float* mu   = ws + 5 * SZ;
    float* rowm = mu + 128;
    float* rowz = rowm + (size_t)BH_ * N_;

    unsigned short* k2h  = (unsigned short*)attn_f;
    unsigned short* k2l  = k2h + SZ;
    unsigned short* vth  = k2h + 2 * SZ;
    unsigned short* vtl  = k2h + 3 * SZ;
    unsigned short* xh   = k2h + 4 * SZ;
    unsigned short* xl   = k2h + 5 * SZ;
    unsigned short* wqth = k2h + 6 * SZ;
    unsigned short* wqtl = k2h + 7 * SZ;
    unsigned short* wpth = k2h + 8 * SZ;
    unsigned short* wptl = k2h + 9 * SZ;
    unsigned short* lbh  = k2h + 10 * SZ;
    unsigned short* lbl  = k2h + 11 * SZ;

    split_flat<<<3072, 256, 0, stream>>>(x, xh, xl);
    split_wt<<<dim3(24, 12), 256, 0, stream>>>(Wq, 2 * C_, wqth, wqtl);
    split_wt<<<dim3(12, 12), 256, 0, stream>>>(Wp, C_, wpth, wptl);

    qkv_mfma<<<dim3(24, 128), 256, 0, stream>>>(xh, xl, wqth, wqtl, bq, kb, vb);
    vt_split<<<dim3(16, 96), 256, 0, stream>>>(vb, vth, vtl);
    musum<<<96, 256, 0, stream>>>(kb, mu);

    for (int it = 0; it <= NIT_; ++it) {
        ew_fused<<<24576, 256, 0, stream>>>(kb, lb, yb, mu, k2b, k2h, k2l,
                                            it > 0 ? 1 : 0);
        flash<<<dim3(8, 96), 256, 0, stream>>>(k2h, k2l, vth, vtl, lb, rowm, rowz,
                                               lbh, lbl, it == NIT_ ? 1 : 0);
    }

    proj_mfma<<<dim3(12, 128), 256, 0, stream>>>(lbh, lbl, wpth, wptl, bp, out_f);
    attn_out_mfma<<<dim3(16, 96), 256, 0, stream>>>(k2b, rowm, rowz, attn_f);
}

// Round 15
// 1598.577 us; speedup vs baseline: 1.1682x; 1.0175x over previous
//
#include <hip/hip_runtime.h>

#define B_   8
#define N_   1024
#define C_   768
#define H_   12
#define HD_  64
#define BH_  96
#define SCALE_ 0.125f
#define NIT_ 5

typedef __attribute__((ext_vector_type(8))) short bfrag;   // 8 bf16 (4 VGPR)
typedef __attribute__((ext_vector_type(4))) float facc;    // 4 f32  (4 VGPR)

__device__ __forceinline__ unsigned short bfhi(float x)
{
    return (unsigned short)(__float_as_uint(x) >> 16);
}
__device__ __forceinline__ unsigned short bflo(float x)
{
    const unsigned hu = __float_as_uint(x) & 0xffff0000u;
    return (unsigned short)(__float_as_uint(x - __uint_as_float(hu)) >> 16);
}
__device__ __forceinline__ unsigned int packhl(float v)
{
    return (unsigned int)bfhi(v) | ((unsigned int)bflo(v) << 16);
}
__device__ __forceinline__ bfrag pack_hi(float4 a, float4 b)
{
    bfrag r;
    r[0] = (short)bfhi(a.x); r[1] = (short)bfhi(a.y);
    r[2] = (short)bfhi(a.z); r[3] = (short)bfhi(a.w);
    r[4] = (short)bfhi(b.x); r[5] = (short)bfhi(b.y);
    r[6] = (short)bfhi(b.z); r[7] = (short)bfhi(b.w);
    return r;
}
__device__ __forceinline__ bfrag pack_lo(float4 a, float4 b)
{
    bfrag r;
    r[0] = (short)bflo(a.x); r[1] = (short)bflo(a.y);
    r[2] = (short)bflo(a.z); r[3] = (short)bflo(a.w);
    r[4] = (short)bflo(b.x); r[5] = (short)bflo(b.y);
    r[6] = (short)bflo(b.z); r[7] = (short)bflo(b.w);
    return r;
}

// ---------------------------------------------------------------------------
// split_flat: fp32 array -> bf16 hi/lo arrays, same layout.  grid 3072 x 256.
// ---------------------------------------------------------------------------
__global__ __launch_bounds__(256)
void split_flat(const float* __restrict__ In,
                unsigned short* __restrict__ Oh, unsigned short* __restrict__ Ol)
{
    const size_t i = ((size_t)blockIdx.x * 256 + threadIdx.x) * 8;
    const float4 a = *(const float4*)(In + i);
    const float4 b = *(const float4*)(In + i + 4);
    *(bfrag*)(Oh + i) = pack_hi(a, b);
    *(bfrag*)(Ol + i) = pack_lo(a, b);
}

// ---------------------------------------------------------------------------
// split_wt: W [768][ncols] fp32 -> Wt hi/lo [ncols][768] bf16 (transposed).
// grid (ncols/64, 768/64=12) x 256.  Run once per weight.
// ---------------------------------------------------------------------------
__global__ __launch_bounds__(256)
void split_wt(const float* __restrict__ W, int ncols,
              unsigned short* __restrict__ Th, unsigned short* __restrict__ Tl)
{
    __shared__ float Ts[64][68];
    const int tid = threadIdx.x;
    const int c0 = blockIdx.x * 64;
    const int k0 = blockIdx.y * 64;

    {
        int e = tid;
#pragma unroll
        for (int t = 0; t < 4; ++t, e += 256) {
            const int r = e >> 4, c4 = (e & 15) << 2;
            *(float4*)&Ts[r][c4] =
                *(const float4*)(W + (size_t)(k0 + r) * ncols + c0 + c4);
        }
    }
    __syncthreads();

#pragma unroll
    for (int t = 0; t < 2; ++t) {
        const int idx = t * 2048 + tid * 8;
        const int cr = idx >> 6, ck = idx & 63;
        bfrag h8, l8;
#pragma unroll
        for (int q = 0; q < 8; ++q) {
            const float v = Ts[ck + q][cr];
            h8[q] = (short)bfhi(v);
            l8[q] = (short)bflo(v);
        }
        const size_t go = (size_t)(c0 + cr) * 768 + k0 + ck;
        *(bfrag*)(Th + go) = h8;
        *(bfrag*)(Tl + go) = l8;
    }
}

// ---------------------------------------------------------------------------
// K1 qkv_mfma: B (weight) rows staged from PERMUTED global rows
// (kr = 4*(r&15) + (r>>4)) so LDS slot 16q+r16 holds output column
// 4*r16+q -> epilogue becomes float4 stores.  LDS pattern unchanged;
// per-element math bit-identical.  grid (24, 128) x 256.
// ---------------------------------------------------------------------------
__global__ __launch_bounds__(256)
void qkv_mfma(const unsigned short* __restrict__ Xh, const unsigned short* __restrict__ Xl,
              const unsigned short* __restrict__ Wth, const unsigned short* __restrict__ Wtl,
              const float* __restrict__ bias,
              float* __restrict__ Kb, float* __restrict__ Vb)
{
    __shared__ short Ahs[64][72];
    __shared__ short Als[64][72];
    __shared__ short Bhs[64][72];
    __shared__ short Bls[64][72];

    const int tid  = threadIdx.x;
    const int lane = tid & 63;
    const int w    = tid >> 6;
    const int g    = lane >> 4;
    const int r16  = lane & 15;
    const int m0   = blockIdx.y * 64;
    const int c0   = blockIdx.x * 64;     // [0,1536)

    facc o0 = {0.f, 0.f, 0.f, 0.f};
    facc o1 = {0.f, 0.f, 0.f, 0.f};
    facc o2 = {0.f, 0.f, 0.f, 0.f};
    facc o3 = {0.f, 0.f, 0.f, 0.f};

    const int i0 = tid * 8,        r0 = i0 >> 6, cc0 = i0 & 63;
    const int i1 = 2048 + tid * 8, r1 = i1 >> 6, cc1 = i1 & 63;
    // permuted global B rows: slot r holds column 4*(r&15)+(r>>4)
    const int kr0 = 4 * (r0 & 15) + (r0 >> 4);
    const int kr1 = kr0 + 2;                      // r1 = r0+32

    bfrag ta0 = *(const bfrag*)(Xh + (size_t)(m0 + r0) * 768 + cc0);
    bfrag ta1 = *(const bfrag*)(Xh + (size_t)(m0 + r1) * 768 + cc1);
    bfrag tb0 = *(const bfrag*)(Xl + (size_t)(m0 + r0) * 768 + cc0);
    bfrag tb1 = *(const bfrag*)(Xl + (size_t)(m0 + r1) * 768 + cc1);
    bfrag tw0 = *(const bfrag*)(Wth + (size_t)(c0 + kr0) * 768 + cc0);
    bfrag tw1 = *(const bfrag*)(Wth + (size_t)(c0 + kr1) * 768 + cc1);
    bfrag tz0 = *(const bfrag*)(Wtl + (size_t)(c0 + kr0) * 768 + cc0);
    bfrag tz1 = *(const bfrag*)(Wtl + (size_t)(c0 + kr1) * 768 + cc1);

    for (int ks = 0; ks < 12; ++ks) {
        __syncthreads();
        *(bfrag*)&Ahs[r0][cc0] = ta0;  *(bfrag*)&Ahs[r1][cc1] = ta1;
        *(bfrag*)&Als[r0][cc0] = tb0;  *(bfrag*)&Als[r1][cc1] = tb1;
        *(bfrag*)&Bhs[r0][cc0] = tw0;  *(bfrag*)&Bhs[r1][cc1] = tw1;
        *(bfrag*)&Bls[r0][cc0] = tz0;  *(bfrag*)&Bls[r1][cc1] = tz1;
        if (ks + 1 < 12) {
            const int kn = (ks + 1) * 64;
            ta0 = *(const bfrag*)(Xh + (size_t)(m0 + r0) * 768 + kn + cc0);
            ta1 = *(const bfrag*)(Xh + (size_t)(m0 + r1) * 768 + kn + cc1);
            tb0 = *(const bfrag*)(Xl + (size_t)(m0 + r0) * 768 + kn + cc0);
            tb1 = *(const bfrag*)(Xl + (size_t)(m0 + r1) * 768 + kn + cc1);
            tw0 = *(const bfrag*)(Wth + (size_t)(c0 + kr0) * 768 + kn + cc0);
            tw1 = *(const bfrag*)(Wth + (size_t)(c0 + kr1) * 768 + kn + cc1);
            tz0 = *(const bfrag*)(Wtl + (size_t)(c0 + kr0) * 768 + kn + cc0);
            tz1 = *(const bfrag*)(Wtl + (size_t)(c0 + kr1) * 768 + kn + cc1);
        }
        __syncthreads();

        const bfrag ah0 = *(const bfrag*)&Ahs[16 * w + r16][8 * g];
        const bfrag ah1 = *(const bfrag*)&Ahs[16 * w + r16][32 + 8 * g];
        const bfrag al0 = *(const bfrag*)&Als[16 * w + r16][8 * g];
        const bfrag al1 = *(const bfrag*)&Als[16 * w + r16][32 + 8 * g];
        {
            bfrag b0 = *(const bfrag*)&Bhs[r16][8 * g];
            bfrag b1 = *(const bfrag*)&Bhs[r16][32 + 8 * g];
            bfrag c1 = *(const bfrag*)&Bls[r16][8 * g];
            bfrag c2 = *(const bfrag*)&Bls[r16][32 + 8 * g];
            o0 = __builtin_amdgcn_mfma_f32_16x16x32_bf16(ah0, b0, o0, 0, 0, 0);
            o0 = __builtin_amdgcn_mfma_f32_16x16x32_bf16(al0, b0, o0, 0, 0, 0);
            o0 = __builtin_amdgcn_mfma_f32_16x16x32_bf16(ah0, c1, o0, 0, 0, 0);
            o0 = __builtin_amdgcn_mfma_f32_16x16x32_bf16(ah1, b1, o0, 0, 0, 0);
            o0 = __builtin_amdgcn_mfma_f32_16x16x32_bf16(al1, b1, o0, 0, 0, 0);
            o0 = __builtin_amdgcn_mfma_f32_16x16x32_bf16(ah1, c2, o0, 0, 0, 0);
        }
        {
            bfrag b0 = *(const bfrag*)&Bhs[16 + r16][8 * g];
            bfrag b1 = *(const bfrag*)&Bhs[16 + r16][32 + 8 * g];
            bfrag c1 = *(const bfrag*)&Bls[16 + r16][8 * g];
            bfrag c2 = *(const bfrag*)&Bls[16 + r16][32 + 8 * g];
            o1 = __builtin_amdgcn_mfma_f32_16x16x32_bf16(ah0, b0, o1, 0, 0, 0);
            o1 = __builtin_amdgcn_mfma_f32_16x16x32_bf16(al0, b0, o1, 0, 0, 0);
            o1 = __builtin_amdgcn_mfma_f32_16x16x32_bf16(ah0, c1, o1, 0, 0, 0);
            o1 = __builtin_amdgcn_mfma_f32_16x16x32_bf16(ah1, b1, o1, 0, 0, 0);
            o1 = __builtin_amdgcn_mfma_f32_16x16x32_bf16(al1, b1, o1, 0, 0, 0);
            o1 = __builtin_amdgcn_mfma_f32_16x16x32_bf16(ah1, c2, o1, 0, 0, 0);
        }
        {
            bfrag b0 = *(const bfrag*)&Bhs[32 + r16][8 * g];
            bfrag b1 = *(const bfrag*)&Bhs[32 + r16][32 + 8 * g];
            bfrag c1 = *(const bfrag*)&Bls[32 + r16][8 * g];
            bfrag c2 = *(const bfrag*)&Bls[32 + r16][32 + 8 * g];
            o2 = __builtin_amdgcn_mfma_f32_16x16x32_bf16(ah0, b0, o2, 0, 0, 0);
            o2 = __builtin_amdgcn_mfma_f32_16x16x32_bf16(al0, b0, o2, 0, 0, 0);
            o2 = __builtin_amdgcn_mfma_f32_16x16x32_bf16(ah0, c1, o2, 0, 0, 0);
            o2 = __builtin_amdgcn_mfma_f32_16x16x32_bf16(ah1, b1, o2, 0, 0, 0);
            o2 = __builtin_amdgcn_mfma_f32_16x16x32_bf16(al1, b1, o2, 0, 0, 0);
            o2 = __builtin_amdgcn_mfma_f32_16x16x32_bf16(ah1, c2, o2, 0, 0, 0);
        }
        {
            bfrag b0 = *(const bfrag*)&Bhs[48 + r16][8 * g];
            bfrag b1 = *(const bfrag*)&Bhs[48 + r16][32 + 8 * g];
            bfrag c1 = *(const bfrag*)&Bls[48 + r16][8 * g];
            bfrag c2 = *(const bfrag*)&Bls[48 + r16][32 + 8 * g];
            o3 = __builtin_amdgcn_mfma_f32_16x16x32_bf16(ah0, b0, o3, 0, 0, 0);
            o3 = __builtin_amdgcn_mfma_f32_16x16x32_bf16(al0, b0, o3, 0, 0, 0);
            o3 = __builtin_amdgcn_mfma_f32_16x16x32_bf16(ah0, c1, o3, 0, 0, 0);
            o3 = __builtin_amdgcn_mfma_f32_16x16x32_bf16(ah1, b1, o3, 0, 0, 0);
            o3 = __builtin_amdgcn_mfma_f32_16x16x32_bf16(al1, b1, o3, 0, 0, 0);
            o3 = __builtin_amdgcn_mfma_f32_16x16x32_bf16(ah1, c2, o3, 0, 0, 0);
        }
    }

    // Epilogue: lane covers columns c0 + 4*r16 + {0,1,2,3} -> float4 stores.
    const int h = (c0 % C_) >> 6;
    float* tgt = (c0 < C_) ? Kb : Vb;
    const float4 bb = *(const float4*)(bias + c0 + 4 * r16);

    const int mrow = m0 + 16 * w + 4 * g;
    const int bidx = mrow >> 10;
    const int nidx = mrow & 1023;
    float* trow = tgt + ((size_t)(bidx * H_ + h) * N_ + nidx) * HD_ + 4 * r16;
    {
        float4 o;
        o.x = o0.x + bb.x; o.y = o1.x + bb.y; o.z = o2.x + bb.z; o.w = o3.x + bb.w;
        *(float4*)(trow + 0 * HD_) = o;
        o.x = o0.y + bb.x; o.y = o1.y + bb.y; o.z = o2.y + bb.z; o.w = o3.y + bb.w;
        *(float4*)(trow + 1 * HD_) = o;
        o.x = o0.z + bb.x; o.y = o1.z + bb.y; o.z = o2.z + bb.z; o.w = o3.z + bb.w;
        *(float4*)(trow + 2 * HD_) = o;
        o.x = o0.w + bb.x; o.y = o1.w + bb.y; o.z = o2.w + bb.z; o.w = o3.w + bb.w;
        *(float4*)(trow + 3 * HD_) = o;
    }
}

// ---------------------------------------------------------------------------
// K7 proj_mfma: same permuted-B + float4-store epilogue.  grid (12,128)x256.
// ---------------------------------------------------------------------------
__global__ __launch_bounds__(256)
void proj_mfma(const unsigned short* __restrict__ Lh, const unsigned short* __restrict__ Ll,
               const unsigned short* __restrict__ Wth, const unsigned short* __restrict__ Wtl,
               const float* __restrict__ bias, float* __restrict__ Out)
{
    __shared__ short Ahs[64][72];
    __shared__ short Als[64][72];
    __shared__ short Bhs[64][72];
    __shared__ short Bls[64][72];

    const int tid  = threadIdx.x;
    const int lane = tid & 63;
    const int w    = tid >> 6;
    const int g    = lane >> 4;
    const int r16  = lane & 15;
    const int m0   = blockIdx.y * 64;
    const int c0   = blockIdx.x * 64;     // [0,768)

    facc o0 = {0.f, 0.f, 0.f, 0.f};
    facc o1 = {0.f, 0.f, 0.f, 0.f};
    facc o2 = {0.f, 0.f, 0.f, 0.f};
    facc o3 = {0.f, 0.f, 0.f, 0.f};

    const int i0 = tid * 8,        r0 = i0 >> 6, cc0 = i0 & 63;
    const int i1 = 2048 + tid * 8, r1 = i1 >> 6, cc1 = i1 & 63;
    const int t0 = m0 + r0, ab0 = t0 >> 10, an0 = t0 & 1023;
    const int t1 = m0 + r1, ab1 = t1 >> 10, an1 = t1 & 1023;
    const int kr0 = 4 * (r0 & 15) + (r0 >> 4);
    const int kr1 = kr0 + 2;

    bfrag ta0 = *(const bfrag*)(Lh + ((size_t)(ab0 * H_) * N_ + an0) * HD_ + cc0);
    bfrag ta1 = *(const bfrag*)(Lh + ((size_t)(ab1 * H_) * N_ + an1) * HD_ + cc1);
    bfrag tb0 = *(const bfrag*)(Ll + ((size_t)(ab0 * H_) * N_ + an0) * HD_ + cc0);
    bfrag tb1 = *(const bfrag*)(Ll + ((size_t)(ab1 * H_) * N_ + an1) * HD_ + cc1);
    bfrag tw0 = *(const bfrag*)(Wth + (size_t)(c0 + kr0) * 768 + cc0);
    bfrag tw1 = *(const bfrag*)(Wth + (size_t)(c0 + kr1) * 768 + cc1);
    bfrag tz0 = *(const bfrag*)(Wtl + (size_t)(c0 + kr0) * 768 + cc0);
    bfrag tz1 = *(const bfrag*)(Wtl + (size_t)(c0 + kr1) * 768 + cc1);

    for (int ks = 0; ks < 12; ++ks) {
        __syncthreads();
        *(bfrag*)&Ahs[r0][cc0] = ta0;  *(bfrag*)&Ahs[r1][cc1] = ta1;
        *(bfrag*)&Als[r0][cc0] = tb0;  *(bfrag*)&Als[r1][cc1] = tb1;
        *(bfrag*)&Bhs[r0][cc0] = tw0;  *(bfrag*)&Bhs[r1][cc1] = tw1;
        *(bfrag*)&Bls[r0][cc0] = tz0;  *(bfrag*)&Bls[r1][cc1] = tz1;
        if (ks + 1 < 12) {
            const int kn = ks + 1;
            const size_t ga0 = ((size_t)(ab0 * H_ + kn) * N_ + an0) * HD_ + cc0;
            const size_t ga1 = ((size_t)(ab1 * H_ + kn) * N_ + an1) * HD_ + cc1;
            ta0 = *(const bfrag*)(Lh + ga0);
            ta1 = *(const bfrag*)(Lh + ga1);
            tb0 = *(const bfrag*)(Ll + ga0);
            tb1 = *(const bfrag*)(Ll + ga1);
            tw0 = *(const bfrag*)(Wth + (size_t)(c0 + kr0) * 768 + kn * 64 + cc0);
            tw1 = *(const bfrag*)(Wth + (size_t)(c0 + kr1) * 768 + kn * 64 + cc1);
            tz0 = *(const bfrag*)(Wtl + (size_t)(c0 + kr0) * 768 + kn * 64 + cc0);
            tz1 = *(const bfrag*)(Wtl + (size_t)(c0 + kr1) * 768 + kn * 64 + cc1);
        }
        __syncthreads();

        const bfrag ah0 = *(const bfrag*)&Ahs[16 * w + r16][8 * g];
        const bfrag ah1 = *(const bfrag*)&Ahs[16 * w + r16][32 + 8 * g];
        const bfrag al0 = *(const bfrag*)&Als[16 * w + r16][8 * g];
        const bfrag al1 = *(const bfrag*)&Als[16 * w + r16][32 + 8 * g];
        {
            bfrag b0 = *(const bfrag*)&Bhs[r16][8 * g];
            bfrag b1 = *(const bfrag*)&Bhs[r16][32 + 8 * g];
            bfrag c1 = *(const bfrag*)&Bls[r16][8 * g];
            bfrag c2 = *(const bfrag*)&Bls[r16][32 + 8 * g];
            o0 = __builtin_amdgcn_mfma_f32_16x16x32_bf16(ah0, b0, o0, 0, 0, 0);
            o0 = __builtin_amdgcn_mfma_f32_16x16x32_bf16(al0, b0, o0, 0, 0, 0);
            o0 = __builtin_amdgcn_mfma_f32_16x16x32_bf16(ah0, c1, o0, 0, 0, 0);
            o0 = __builtin_amdgcn_mfma_f32_16x16x32_bf16(ah1, b1, o0, 0, 0, 0);
            o0 = __builtin_amdgcn_mfma_f32_16x16x32_bf16(al1, b1, o0, 0, 0, 0);
            o0 = __builtin_amdgcn_mfma_f32_16x16x32_bf16(ah1, c2, o0, 0, 0, 0);
        }
        {
            bfrag b0 = *(const bfrag*)&Bhs[16 + r16][8 * g];
            bfrag b1 = *(const bfrag*)&Bhs[16 + r16][32 + 8 * g];
            bfrag c1 = *(const bfrag*)&Bls[16 + r16][8 * g];
            bfrag c2 = *(const bfrag*)&Bls[16 + r16][32 + 8 * g];
            o1 = __builtin_amdgcn_mfma_f32_16x16x32_bf16(ah0, b0, o1, 0, 0, 0);
            o1 = __builtin_amdgcn_mfma_f32_16x16x32_bf16(al0, b0, o1, 0, 0, 0);
            o1 = __builtin_amdgcn_mfma_f32_16x16x32_bf16(ah0, c1, o1, 0, 0, 0);
            o1 = __builtin_amdgcn_mfma_f32_16x16x32_bf16(ah1, b1, o1, 0, 0, 0);
            o1 = __builtin_amdgcn_mfma_f32_16x16x32_bf16(al1, b1, o1, 0, 0, 0);
            o1 = __builtin_amdgcn_mfma_f32_16x16x32_bf16(ah1, c2, o1, 0, 0, 0);
        }
        {
            bfrag b0 = *(const bfrag*)&Bhs[32 + r16][8 * g];
            bfrag b1 = *(const bfrag*)&Bhs[32 + r16][32 + 8 * g];
            bfrag c1 = *(const bfrag*)&Bls[32 + r16][8 * g];
            bfrag c2 = *(const bfrag*)&Bls[32 + r16][32 + 8 * g];
            o2 = __builtin_amdgcn_mfma_f32_16x16x32_bf16(ah0, b0, o2, 0, 0, 0);
            o2 = __builtin_amdgcn_mfma_f32_16x16x32_bf16(al0, b0, o2, 0, 0, 0);
            o2 = __builtin_amdgcn_mfma_f32_16x16x32_bf16(ah0, c1, o2, 0, 0, 0);
            o2 = __builtin_amdgcn_mfma_f32_16x16x32_bf16(ah1, b1, o2, 0, 0, 0);
            o2 = __builtin_amdgcn_mfma_f32_16x16x32_bf16(al1, b1, o2, 0, 0, 0);
            o2 = __builtin_amdgcn_mfma_f32_16x16x32_bf16(ah1, c2, o2, 0, 0, 0);
        }
        {
            bfrag b0 = *(const bfrag*)&Bhs[48 + r16][8 * g];
            bfrag b1 = *(const bfrag*)&Bhs[48 + r16][32 + 8 * g];
            bfrag c1 = *(const bfrag*)&Bls[48 + r16][8 * g];
            bfrag c2 = *(const bfrag*)&Bls[48 + r16][32 + 8 * g];
            o3 = __builtin_amdgcn_mfma_f32_16x16x32_bf16(ah0, b0, o3, 0, 0, 0);
            o3 = __builtin_amdgcn_mfma_f32_16x16x32_bf16(al0, b0, o3, 0, 0, 0);
            o3 = __builtin_amdgcn_mfma_f32_16x16x32_bf16(ah0, c1, o3, 0, 0, 0);
            o3 = __builtin_amdgcn_mfma_f32_16x16x32_bf16(ah1, b1, o3, 0, 0, 0);
            o3 = __builtin_amdgcn_mfma_f32_16x16x32_bf16(al1, b1, o3, 0, 0, 0);
            o3 = __builtin_amdgcn_mfma_f32_16x16x32_bf16(ah1, c2, o3, 0, 0, 0);
        }
    }

    const float4 bb = *(const float4*)(bias + c0 + 4 * r16);
    float* orow = Out + (size_t)(m0 + 16 * w + 4 * g) * C_ + c0 + 4 * r16;
    {
        float4 o;
        o.x = o0.x + bb.x; o.y = o1.x + bb.y; o.z = o2.x + bb.z; o.w = o3.x + bb.w;
        *(float4*)(orow + 0 * C_) = o;
        o.x = o0.y + bb.x; o.y = o1.y + bb.y; o.z = o2.y + bb.z; o.w = o3.y + bb.w;
        *(float4*)(orow + 1 * C_) = o;
        o.x = o0.z + bb.x; o.y = o1.z + bb.y; o.z = o2.z + bb.z; o.w = o3.z + bb.w;
        *(float4*)(orow + 2 * C_) = o;
        o.x = o0.w + bb.x; o.y = o1.w + bb.y; o.z = o2.w + bb.z; o.w = o3.w + bb.w;
        *(float4*)(orow + 3 * C_) = o;
    }
}

// ---------------------------------------------------------------------------
// K2: mu[bh] = (N*C/4) / sum|k| per (b,h).
// ---------------------------------------------------------------------------
__global__ __launch_bounds__(256)
void musum(const float* __restrict__ Kb, float* __restrict__ mu)
{
    const int bh = blockIdx.x;
    const int tid = threadIdx.x;
    const float* p = Kb + (size_t)bh * (N_ * HD_);
    float s = 0.0f;
    for (int i = tid; i < N_ * HD_; i += 256) s += fabsf(p[i]);
    for (int off = 32; off; off >>= 1) s += __shfl_down(s, off, 64);
    __shared__ float red[4];
    if ((tid & 63) == 0) red[tid >> 6] = s;
    __syncthreads();
    if (tid == 0)
        mu[bh] = (float)(N_ * C_ / 4.0) / (red[0] + red[1] + red[2] + red[3]);
}

// ---------------------------------------------------------------------------
// K3/K5 fused.  upd==0 path uses l=y=0 EXACTLY.
// ---------------------------------------------------------------------------
__global__ __launch_bounds__(256)
void ew_fused(const float* __restrict__ Kb, const float* __restrict__ Lb,
              float* __restrict__ Yb, const float* __restrict__ mu,
              float* __restrict__ K2b,
              unsigned short* __restrict__ K2h, unsigned short* __restrict__ K2l,
              int upd)
{
    const int i = blockIdx.x * 256 + threadIdx.x;
    const int bh = i >> 16;
    const float m = mu[bh];
    const float lm = 4.0f * m;
    const float kv = Kb[i];
    float k2;
    if (upd) {
        const float lv = Lb[i];
        const float y = 2.0f * Yb[i] + m * (K2b[i] - lv);
        Yb[i] = y;
        const float yom = y / m;
        const float t = kv - lv + yom;
        const float s = (t >= lm) ? (t - lm) : ((t <= -lm) ? (t + lm) : 0.0f);
        k2 = kv - s - yom;
    } else {
        Yb[i] = 0.0f;
        const float t = kv;
        const float s = (t >= lm) ? (t - lm) : ((t <= -lm) ? (t + lm) : 0.0f);
        k2 = kv - s;
    }
    K2b[i] = k2;
    K2h[i] = bfhi(k2);
    K2l[i] = bflo(k2);
}

// ---------------------------------------------------------------------------
// K3c: Vt hi/lo bf16, transposed to [bh][d][n].  Run ONCE.
// ---------------------------------------------------------------------------
__global__ __launch_bounds__(256)
void vt_split(const float* __restrict__ Vb,
              unsigned short* __restrict__ Vth, unsigned short* __restrict__ Vtl)
{
    __shared__ float Ts[64][68];
    const int tid = threadIdx.x;
    const int bh = blockIdx.y;
    const int n0 = blockIdx.x * 64;
    const float* vb = Vb + ((size_t)bh * N_ + n0) * HD_;

    {
        int e = tid;
#pragma unroll
        for (int t = 0; t < 4; ++t, e += 256) {
            const int r = e >> 4, c4 = (e & 15) << 2;
            *(float4*)&Ts[r][c4] = *(const float4*)(vb + r * HD_ + c4);
        }
    }
    __syncthreads();

#pragma unroll
    for (int t = 0; t < 2; ++t) {
        const int idx = t * 2048 + tid * 8;
        const int d = idx >> 6, c = idx & 63;
        bfrag h8, l8;
#pragma unroll
        for (int q = 0; q < 8; ++q) {
            const float v = Ts[c + q][d];
            h8[q] = (short)bfhi(v);
            l8[q] = (short)bflo(v);
        }
        const size_t go = ((size_t)bh * HD_ + d) * N_ + n0 + c;
        *(bfrag*)(Vth + go) = h8;
        *(bfrag*)(Vtl + go) = l8;
    }
}

// ---------------------------------------------------------------------------
// K4 flash-MFMA v5 (unchanged from R12/R14, verified best).
// ---------------------------------------------------------------------------
__global__ __launch_bounds__(256)
void flash(const unsigned short* __restrict__ K2h, const unsigned short* __restrict__ K2l,
           const unsigned short* __restrict__ Vth, const unsigned short* __restrict__ Vtl,
           float* __restrict__ Lout, float* __restrict__ Mrow, float* __restrict__ Zrow,
           unsigned short* __restrict__ Lbh, unsigned short* __restrict__ Lbl, int wsplit)
{
    __shared__ __attribute__((aligned(16))) short KPbuf[2 * 64 * 72];
    __shared__ short Vh[64][72];
    __shared__ short Vl[64][72];
    short (*Kh)[72] = (short(*)[72])KPbuf;
    short (*Kl)[72] = (short(*)[72])(KPbuf + 64 * 72);
    unsigned int (*Pu)[68] = (unsigned int(*)[68])KPbuf;   // 17.4 KB <= 18.4 KB

    const int tid  = threadIdx.x;
    const int lane = tid & 63;
    const int w    = tid >> 6;
    const int g    = lane >> 4;
    const int r16  = lane & 15;
    const int bh   = blockIdx.y;
    const int q0   = blockIdx.x * 128;

    const unsigned short* kh = K2h + (size_t)bh * (N_ * HD_);
    const unsigned short* kl = K2l + (size_t)bh * (N_ * HD_);
    const unsigned short* vh = Vth + (size_t)bh * (N_ * HD_);
    const unsigned short* vl = Vtl + (size_t)bh * (N_ * HD_);

    const size_t qoffA = (size_t)(q0 + 16 * w + r16) * HD_ + 8 * g;
    const size_t qoffB = (size_t)(q0 + 64 + 16 * w + r16) * HD_ + 8 * g;
    const bfrag qhA0 = *(const bfrag*)(kh + qoffA);
    const bfrag qhA1 = *(const bfrag*)(kh + qoffA + 32);
    const bfrag qlA0 = *(const bfrag*)(kl + qoffA);
    const bfrag qlA1 = *(const bfrag*)(kl + qoffA + 32);
    const bfrag qhB0 = *(const bfrag*)(kh + qoffB);
    const bfrag qhB1 = *(const bfrag*)(kh + qoffB + 32);
    const bfrag qlB0 = *(const bfrag*)(kl + qoffB);
    const bfrag qlB1 = *(const bfrag*)(kl + qoffB + 32);

    const int i0 = tid * 8,        r0 = i0 >> 6, cc0 = i0 & 63;
    const int i1 = 2048 + tid * 8, r1 = i1 >> 6, cc1 = i1 & 63;

    bfrag pk0 = *(const bfrag*)(kh + i0);
    bfrag pk1 = *(const bfrag*)(kh + i1);
    bfrag pm0 = *(const bfrag*)(kl + i0);
    bfrag pm1 = *(const bfrag*)(kl + i1);

    float mrA0 = -1e30f, mrA1 = -1e30f, mrA2 = -1e30f, mrA3 = -1e30f;
    float zrA0 = 0.0f,  zrA1 = 0.0f,  zrA2 = 0.0f,  zrA3 = 0.0f;
    float mrB0 = -1e30f, mrB1 = -1e30f, mrB2 = -1e30f, mrB3 = -1e30f;
    float zrB0 = 0.0f,  zrB1 = 0.0f,  zrB2 = 0.0f,  zrB3 = 0.0f;
    facc oA0 = {0.f, 0.f, 0.f, 0.f};
    facc oA1 = {0.f, 0.f, 0.f, 0.f};
    facc oA2 = {0.f, 0.f, 0.f, 0.f};
    facc oA3 = {0.f, 0.f, 0.f, 0.f};
    facc oB0 = {0.f, 0.f, 0.f, 0.f};
    facc oB1 = {0.f, 0.f, 0.f, 0.f};
    facc oB2 = {0.f, 0.f, 0.f, 0.f};
    facc oB3 = {0.f, 0.f, 0.f, 0.f};

    for (int kt = 0; kt < 16; ++kt) {
        __syncthreads();   // bar1: prev tile's Pu (=K storage) and V reads done
        *(bfrag*)&Kh[r0][cc0] = pk0;  *(bfrag*)&Kh[r1][cc1] = pk1;
        *(bfrag*)&Kl[r0][cc0] = pm0;  *(bfrag*)&Kl[r1][cc1] = pm1;
        const bfrag tv0 = *(const bfrag*)(vh + (size_t)r0 * N_ + kt * 64 + cc0);
        const bfrag tv1 = *(const bfrag*)(vh + (size_t)r1 * N_ + kt * 64 + cc1);
        const bfrag tw0 = *(const bfrag*)(vl + (size_t)r0 * N_ + kt * 64 + cc0);
        const bfrag tw1 = *(const bfrag*)(vl + (size_t)r1 * N_ + kt * 64 + cc1);
        if (kt + 1 < 16) {
            const size_t gn = (size_t)(kt + 1) * 4096;
            pk0 = *(const bfrag*)(kh + gn + i0);
            pk1 = *(const bfrag*)(kh + gn + i1);
            pm0 = *(const bfrag*)(kl + gn + i0);
            pm1 = *(const bfrag*)(kl + gn + i1);
        }
        __syncthreads();   // bar2: K tile visible

        facc sA0 = {0.f, 0.f, 0.f, 0.f};
        facc sA1 = {0.f, 0.f, 0.f, 0.f};
        facc sA2 = {0.f, 0.f, 0.f, 0.f};
        facc sA3 = {0.f, 0.f, 0.f, 0.f};
        facc sB0 = {0.f, 0.f, 0.f, 0.f};
        facc sB1 = {0.f, 0.f, 0.f, 0.f};
        facc sB2 = {0.f, 0.f, 0.f, 0.f};
        facc sB3 = {0.f, 0.f, 0.f, 0.f};
        {
            bfrag b0 = *(const bfrag*)&Kh[r16][8 * g];
            bfrag b1 = *(const bfrag*)&Kh[r16][32 + 8 * g];
            bfrag c0 = *(const bfrag*)&Kl[r16][8 * g];
            bfrag c1 = *(const bfrag*)&Kl[r16][32 + 8 * g];
            sA0 = __builtin_amdgcn_mfma_f32_16x16x32_bf16(qhA0, b0, sA0, 0, 0, 0);
            sA0 = __builtin_amdgcn_mfma_f32_16x16x32_bf16(qlA0, b0, sA0, 0, 0, 0);
            sA0 = __builtin_amdgcn_mfma_f32_16x16x32_bf16(qhA0, c0, sA0, 0, 0, 0);
            sA0 = __builtin_amdgcn_mfma_f32_16x16x32_bf16(qhA1, b1, sA0, 0, 0, 0);
            sA0 = __builtin_amdgcn_mfma_f32_16x16x32_bf16(qlA1, b1, sA0, 0, 0, 0);
            sA0 = __builtin_amdgcn_mfma_f32_16x16x32_bf16(qhA1, c1, sA0, 0, 0, 0);
            sB0 = __builtin_amdgcn_mfma_f32_16x16x32_bf16(qhB0, b0, sB0, 0, 0, 0);
            sB0 = __builtin_amdgcn_mfma_f32_16x16x32_bf16(qlB0, b0, sB0, 0, 0, 0);
            sB0 = __builtin_amdgcn_mfma_f32_16x16x32_bf16(qhB0, c0, sB0, 0, 0, 0);
            sB0 = __builtin_amdgcn_mfma_f32_16x16x32_bf16(qhB1, b1, sB0, 0, 0, 0);
            sB0 = __builtin_amdgcn_mfma_f32_16x16x32_bf16(qlB1, b1, sB0, 0, 0, 0);
            sB0 = __builtin_amdgcn_mfma_f32_16x16x32_bf16(qhB1, c1, sB0, 0, 0, 0);
        }
        {
            bfrag b0 = *(const bfrag*)&Kh[16 + r16][8 * g];
            bfrag b1 = *(const bfrag*)&Kh[16 + r16][32 + 8 * g];
            bfrag c0 = *(const bfrag*)&Kl[16 + r16][8 * g];
            bfrag c1 = *(const bfrag*)&Kl[16 + r16][32 + 8 * g];
            sA1 = __builtin_amdgcn_mfma_f32_16x16x32_bf16(qhA0, b0, sA1, 0, 0, 0);
            sA1 = __builtin_amdgcn_mfma_f32_16x16x32_bf16(qlA0, b0, sA1, 0, 0, 0);
            sA1 = __builtin_amdgcn_mfma_f32_16x16x32_bf16(qhA0, c0, sA1, 0, 0, 0);
            sA1 = __builtin_amdgcn_mfma_f32_16x16x32_bf16(qhA1, b1, sA1, 0, 0, 0);
            sA1 = __builtin_amdgcn_mfma_f32_16x16x32_bf16(qlA1, b1, sA1, 0, 0, 0);
            sA1 = __builtin_amdgcn_mfma_f32_16x16x32_bf16(qhA1, c1, sA1, 0, 0, 0);
            sB1 = __builtin_amdgcn_mfma_f32_16x16x32_bf16(qhB0, b0, sB1, 0, 0, 0);
            sB1 = __builtin_amdgcn_mfma_f32_16x16x32_bf16(qlB0, b0, sB1, 0, 0, 0);
            sB1 = __builtin_amdgcn_mfma_f32_16x16x32_bf16(qhB0, c0, sB1, 0, 0, 0);
            sB1 = __builtin_amdgcn_mfma_f32_16x16x32_bf16(qhB1, b1, sB1, 0, 0, 0);
            sB1 = __builtin_amdgcn_mfma_f32_16x16x32_bf16(qlB1, b1, sB1, 0, 0, 0);
            sB1 = __builtin_amdgcn_mfma_f32_16x16x32_bf16(qhB1, c1, sB1, 0, 0, 0);
        }
        {
            bfrag b0 = *(const bfrag*)&Kh[32 + r16][8 * g];
            bfrag b1 = *(const bfrag*)&Kh[32 + r16][32 + 8 * g];
            bfrag c0 = *(const bfrag*)&Kl[32 + r16][8 * g];
            bfrag c1 = *(const bfrag*)&Kl[32 + r16][32 + 8 * g];
            sA2 = __builtin_amdgcn_mfma_f32_16x16x32_bf16(qhA0, b0, sA2, 0, 0, 0);
            sA2 = __builtin_amdgcn_mfma_f32_16x16x32_bf16(qlA0, b0, sA2, 0, 0, 0);
            sA2 = __builtin_amdgcn_mfma_f32_16x16x32_bf16(qhA0, c0, sA2, 0, 0, 0);
            sA2 = __builtin_amdgcn_mfma_f32_16x16x32_bf16(qhA1, b1, sA2, 0, 0, 0);
            sA2 = __builtin_amdgcn_mfma_f32_16x16x32_bf16(qlA1, b1, sA2, 0, 0, 0);
            sA2 = __builtin_amdgcn_mfma_f32_16x16x32_bf16(qhA1, c1, sA2, 0, 0, 0);
            sB2 = __builtin_amdgcn_mfma_f32_16x16x32_bf16(qhB0, b0, sB2, 0, 0, 0);
            sB2 = __builtin_amdgcn_mfma_f32_16x16x32_bf16(qlB0, b0, sB2, 0, 0, 0);
            sB2 = __builtin_amdgcn_mfma_f32_16x16x32_bf16(qhB0, c0, sB2, 0, 0, 0);
            sB2 = __builtin_amdgcn_mfma_f32_16x16x32_bf16(qhB1, b1, sB2, 0, 0, 0);
            sB2 = __builtin_amdgcn_mfma_f32_16x16x32_bf16(qlB1, b1, sB2, 0, 0, 0);
            sB2 = __builtin_amdgcn_mfma_f32_16x16x32_bf16(qhB1, c1, sB2, 0, 0, 0);
        }
        {
            bfrag b0 = *(const bfrag*)&Kh[48 + r16][8 * g];
            bfrag b1 = *(const bfrag*)&Kh[48 + r16][32 + 8 * g];
            bfrag c0 = *(const bfrag*)&Kl[48 + r16][8 * g];
            bfrag c1 = *(const bfrag*)&Kl[48 + r16][32 + 8 * g];
            sA3 = __builtin_amdgcn_mfma_f32_16x16x32_bf16(qhA0, b0, sA3, 0, 0, 0);
            sA3 = __builtin_amdgcn_mfma_f32_16x16x32_bf16(qlA0, b0, sA3, 0, 0, 0);
            sA3 = __builtin_amdgcn_mfma_f32_16x16x32_bf16(qhA0, c0, sA3, 0, 0, 0);
            sA3 = __builtin_amdgcn_mfma_f32_16x16x32_bf16(qhA1, b1, sA3, 0, 0, 0);
            sA3 = __builtin_amdgcn_mfma_f32_16x16x32_bf16(qlA1, b1, sA3, 0, 0, 0);
            sA3 = __builtin_amdgcn_mfma_f32_16x16x32_bf16(qhA1, c1, sA3, 0, 0, 0);
            sB3 = __builtin_amdgcn_mfma_f32_16x16x32_bf16(qhB0, b0, sB3, 0, 0, 0);
            sB3 = __builtin_amdgcn_mfma_f32_16x16x32_bf16(qlB0, b0, sB3, 0, 0, 0);
            sB3 = __builtin_amdgcn_mfma_f32_16x16x32_bf16(qhB0, c0, sB3, 0, 0, 0);
            sB3 = __builtin_amdgcn_mfma_f32_16x16x32_bf16(qhB1, b1, sB3, 0, 0, 0);
            sB3 = __builtin_amdgcn_mfma_f32_16x16x32_bf16(qlB1, b1, sB3, 0, 0, 0);
            sB3 = __builtin_amdgcn_mfma_f32_16x16x32_bf16(qhB1, c1, sB3, 0, 0, 0);
        }

        sA0 = sA0 * SCALE_;  sA1 = sA1 * SCALE_;  sA2 = sA2 * SCALE_;  sA3 = sA3 * SCALE_;
        sB0 = sB0 * SCALE_;  sB1 = sB1 * SCALE_;  sB2 = sB2 * SCALE_;  sB3 = sB3 * SCALE_;

        // ---- softmax A ----
        float mt0 = fmaxf(fmaxf(sA0.x, sA1.x), fmaxf(sA2.x, sA3.x));
        float mt1 = fmaxf(fmaxf(sA0.y, sA1.y), fmaxf(sA2.y, sA3.y));
        float mt2 = fmaxf(fmaxf(sA0.z, sA1.z), fmaxf(sA2.z, sA3.z));
        float mt3 = fmaxf(fmaxf(sA0.w, sA1.w), fmaxf(sA2.w, sA3.w));
        for (int off = 8; off; off >>= 1) {
            mt0 = fmaxf(mt0, __shfl_xor(mt0, off, 16));
            mt1 = fmaxf(mt1, __shfl_xor(mt1, off, 16));
            mt2 = fmaxf(mt2, __shfl_xor(mt2, off, 16));
            mt3 = fmaxf(mt3, __shfl_xor(mt3, off, 16));
        }
        const float mnA0 = fmaxf(mrA0, mt0), mnA1 = fmaxf(mrA1, mt1);
        const float mnA2 = fmaxf(mrA2, mt2), mnA3 = fmaxf(mrA3, mt3);
        const float aA0 = __expf(mrA0 - mnA0), aA1 = __expf(mrA1 - mnA1);
        const float aA2 = __expf(mrA2 - mnA2), aA3 = __expf(mrA3 - mnA3);
        mrA0 = mnA0; mrA1 = mnA1; mrA2 = mnA2; mrA3 = mnA3;

        const float paA0 = __expf(sA0.x - mnA0), paA1 = __expf(sA0.y - mnA1);
        const float paA2 = __expf(sA0.z - mnA2), paA3 = __expf(sA0.w - mnA3);
        const float pbA0 = __expf(sA1.x - mnA0), pbA1 = __expf(sA1.y - mnA1);
        const float pbA2 = __expf(sA1.z - mnA2), pbA3 = __expf(sA1.w - mnA3);
        const float pcA0 = __expf(sA2.x - mnA0), pcA1 = __expf(sA2.y - mnA1);
        const float pcA2 = __expf(sA2.z - mnA2), pcA3 = __expf(sA2.w - mnA3);
        const float pdA0 = __expf(sA3.x - mnA0), pdA1 = __expf(sA3.y - mnA1);
        const float pdA2 = __expf(sA3.z - mnA2), pdA3 = __expf(sA3.w - mnA3);

        float zsA0 = paA0 + pbA0 + pcA0 + pdA0;
        float zsA1 = paA1 + pbA1 + pcA1 + pdA1;
        float zsA2 = paA2 + pbA2 + pcA2 + pdA2;
        float zsA3 = paA3 + pbA3 + pcA3 + pdA3;
        for (int off = 8; off; off >>= 1) {
            zsA0 += __shfl_xor(zsA0, off, 16);
            zsA1 += __shfl_xor(zsA1, off, 16);
            zsA2 += __shfl_xor(zsA2, off, 16);
            zsA3 += __shfl_xor(zsA3, off, 16);
        }
        zrA0 = zrA0 * aA0 + zsA0;  zrA1 = zrA1 * aA1 + zsA1;
        zrA2 = zrA2 * aA2 + zsA2;  zrA3 = zrA3 * aA3 + zsA3;
        oA0.x *= aA0; oA0.y *= aA1; oA0.z *= aA2; oA0.w *= aA3;
        oA1.x *= aA0; oA1.y *= aA1; oA1.z *= aA2; oA1.w *= aA3;
        oA2.x *= aA0; oA2.y *= aA1; oA2.z *= aA2; oA2.w *= aA3;
        oA3.x *= aA0; oA3.y *= aA1; oA3.z *= aA2; oA3.w *= aA3;

        // ---- softmax B ----
        mt0 = fmaxf(fmaxf(sB0.x, sB1.x), fmaxf(sB2.x, sB3.x));
        mt1 = fmaxf(fmaxf(sB0.y, sB1.y), fmaxf(sB2.y, sB3.y));
        mt2 = fmaxf(fmaxf(sB0.z, sB1.z), fmaxf(sB2.z, sB3.z));
        mt3 = fmaxf(fmaxf(sB0.w, sB1.w), fmaxf(sB2.w, sB3.w));
        for (int off = 8; off; off >>= 1) {
            mt0 = fmaxf(mt0, __shfl_xor(mt0, off, 16));
            mt1 = fmaxf(mt1, __shfl_xor(mt1, off, 16));
            mt2 = fmaxf(mt2, __shfl_xor(mt2, off, 16));
            mt3 = fmaxf(mt3, __shfl_xor(mt3, off, 16));
        }
        const float mnB0 = fmaxf(mrB0, mt0), mnB1 = fmaxf(mrB1, mt1);
        const float mnB2 = fmaxf(mrB2, mt2), mnB3 = fmaxf(mrB3, mt3);
        const float aB0 = __expf(mrB0 - mnB0), aB1 = __expf(mrB1 - mnB1);
        const float aB2 = __expf(mrB2 - mnB2), aB3 = __expf(mrB3 - mnB3);
        mrB0 = mnB0; mrB1 = mnB1; mrB2 = mnB2; mrB3 = mnB3;

        const float paB0 = __expf(sB0.x - mnB0), paB1 = __expf(sB0.y - mnB1);
        const float paB2 = __expf(sB0.z - mnB2), paB3 = __expf(sB0.w - mnB3);
        const float pbB0 = __expf(sB1.x - mnB0), pbB1 = __expf(sB1.y - mnB1);
        const float pbB2 = __expf(sB1.z - mnB2), pbB3 = __expf(sB1.w - mnB3);
        const float pcB0 = __expf(sB2.x - mnB0), pcB1 = __expf(sB2.y - mnB1);
        const float pcB2 = __expf(sB2.z - mnB2), pcB3 = __expf(sB2.w - mnB3);
        const float pdB0 = __expf(sB3.x - mnB0), pdB1 = __expf(sB3.y - mnB1);
        const float pdB2 = __expf(sB3.z - mnB2), pdB3 = __expf(sB3.w - mnB3);

        float zsB0 = paB0 + pbB0 + pcB0 + pdB0;
        float zsB1 = paB1 + pbB1 + pcB1 + pdB1;
        float zsB2 = paB2 + pbB2 + pcB2 + pdB2;
        float zsB3 = paB3 + pbB3 + pcB3 + pdB3;
        for (int off = 8; off; off >>= 1) {
            zsB0 += __shfl_xor(zsB0, off, 16);
            zsB1 += __shfl_xor(zsB1, off, 16);
            zsB2 += __shfl_xor(zsB2, off, 16);
            zsB3 += __shfl_xor(zsB3, off, 16);
        }
        zrB0 = zrB0 * aB0 + zsB0;  zrB1 = zrB1 * aB1 + zsB1;
        zrB2 = zrB2 * aB2 + zsB2;  zrB3 = zrB3 * aB3 + zsB3;
        oB0.x *= aB0; oB0.y *= aB1; oB0.z *= aB2; oB0.w *= aB3;
        oB1.x *= aB0; oB1.y *= aB1; oB1.z *= aB2; oB1.w *= aB3;
        oB2.x *= aB0; oB2.y *= aB1; oB2.z *= aB2; oB2.w *= aB3;
        oB3.x *= aB0; oB3.y *= aB1; oB3.z *= aB2; oB3.w *= aB3;

        // V stage: loads issued before bar2, latency hidden under S+softmax
        *(bfrag*)&Vh[r0][cc0] = tv0;  *(bfrag*)&Vh[r1][cc1] = tv1;
        *(bfrag*)&Vl[r0][cc0] = tw0;  *(bfrag*)&Vl[r1][cc1] = tw1;

        __syncthreads();   // bar3: all K reads done; V visible to all waves

        const int pr = 16 * w + 4 * g;
        const int prow = 16 * w + r16;
        // ---- P_A -> LDS (packed hi|lo uint); PV_A ----
        Pu[pr + 0][r16]      = packhl(paA0);
        Pu[pr + 1][r16]      = packhl(paA1);
        Pu[pr + 2][r16]      = packhl(paA2);
        Pu[pr + 3][r16]      = packhl(paA3);
        Pu[pr + 0][16 + r16] = packhl(pbA0);
        Pu[pr + 1][16 + r16] = packhl(pbA1);
        Pu[pr + 2][16 + r16] = packhl(pbA2);
        Pu[pr + 3][16 + r16] = packhl(pbA3);
        Pu[pr + 0][32 + r16] = packhl(pcA0);
        Pu[pr + 1][32 + r16] = packhl(pcA1);
        Pu[pr + 2][32 + r16] = packhl(pcA2);
        Pu[pr + 3][32 + r16] = packhl(pcA3);
        Pu[pr + 0][48 + r16] = packhl(pdA0);
        Pu[pr + 1][48 + r16] = packhl(pdA1);
        Pu[pr + 2][48 + r16] = packhl(pdA2);
        Pu[pr + 3][48 + r16] = packhl(pdA3);
        __builtin_amdgcn_wave_barrier();
        {
            const uint4 pu0 = *(const uint4*)&Pu[prow][8 * g];
            const uint4 pu1 = *(const uint4*)&Pu[prow][8 * g + 4];
            const uint4 pu2 = *(const uint4*)&Pu[prow][32 + 8 * g];
            const uint4 pu3 = *(const uint4*)&Pu[prow][32 + 8 * g + 4];
            uint4 uh0, ul0, uh1, ul1;
            uh0.x = (pu0.x & 0xffffu) | (pu0.y << 16);
            uh0.y = (pu0.z & 0xffffu) | (pu0.w << 16);
            uh0.z = (pu1.x & 0xffffu) | (pu1.y << 16);
            uh0.w = (pu1.z & 0xffffu) | (pu1.w << 16);
            ul0.x = (pu0.x >> 16) | (pu0.y & 0xffff0000u);
            ul0.y = (pu0.z >> 16) | (pu0.w & 0xffff0000u);
            ul0.z = (pu1.x >> 16) | (pu1.y & 0xffff0000u);
            ul0.w = (pu1.z >> 16) | (pu1.w & 0xffff0000u);
            uh1.x = (pu2.x & 0xffffu) | (pu2.y << 16);
            uh1.y = (pu2.z & 0xffffu) | (pu2.w << 16);
            uh1.z = (pu3.x & 0xffffu) | (pu3.y << 16);
            uh1.w = (pu3.z & 0xffffu) | (pu3.w << 16);
            ul1.x = (pu2.x >> 16) | (pu2.y & 0xffff0000u);
            ul1.y = (pu2.z >> 16) | (pu2.w & 0xffff0000u);
            ul1.z = (pu3.x >> 16) | (pu3.y & 0xffff0000u);
            ul1.w = (pu3.z >> 16) | (pu3.w & 0xffff0000u);
            const bfrag ph0 = *(const bfrag*)&uh0;
            const bfrag pl0 = *(const bfrag*)&ul0;
            const bfrag ph1 = *(const bfrag*)&uh1;
            const bfrag pl1 = *(const bfrag*)&ul1;
            {
                bfrag b0 = *(const bfrag*)&Vh[r16][8 * g];
                bfrag b1 = *(const bfrag*)&Vh[r16][32 + 8 * g];
                bfrag c0 = *(const bfrag*)&Vl[r16][8 * g];
                bfrag c1 = *(const bfrag*)&Vl[r16][32 + 8 * g];
                oA0 = __builtin_amdgcn_mfma_f32_16x16x32_bf16(ph0, b0, oA0, 0, 0, 0);
                oA0 = __builtin_amdgcn_mfma_f32_16x16x32_bf16(pl0, b0, oA0, 0, 0, 0);
                oA0 = __builtin_amdgcn_mfma_f32_16x16x32_bf16(ph0, c0, oA0, 0, 0, 0);
                oA0 = __builtin_amdgcn_mfma_f32_16x16x32_bf16(ph1, b1, oA0, 0, 0, 0);
                oA0 = __builtin_amdgcn_mfma_f32_16x16x32_bf16(pl1, b1, oA0, 0, 0, 0);
                oA0 = __builtin_amdgcn_mfma_f32_16x16x32_bf16(ph1, c1, oA0, 0, 0, 0);
            }
            {
                bfrag b0 = *(const bfrag*)&Vh[16 + r16][8 * g];
                bfrag b1 = *(const bfrag*)&Vh[16 + r16][32 + 8 * g];
                bfrag c0 = *(const bfrag*)&Vl[16 + r16][8 * g];
                bfrag c1 = *(const bfrag*)&Vl[16 + r16][32 + 8 * g];
                oA1 = __builtin_amdgcn_mfma_f32_16x16x32_bf16(ph0, b0, oA1, 0, 0, 0);
                oA1 = __builtin_amdgcn_mfma_f32_16x16x32_bf16(pl0, b0, oA1, 0, 0, 0);
                oA1 = __builtin_amdgcn_mfma_f32_16x16x32_bf16(ph0, c0, oA1, 0, 0, 0);
                oA1 = __builtin_amdgcn_mfma_f32_16x16x32_bf16(ph1, b1, oA1, 0, 0, 0);
                oA1 = __builtin_amdgcn_mfma_f32_16x16x32_bf16(pl1, b1, oA1, 0, 0, 0);
                oA1 = __builtin_amdgcn_mfma_f32_16x16x32_bf16(ph1, c1, oA1, 0, 0, 0);
            }
            {
                bfrag b0 = *(const bfrag*)&Vh[32 + r16][8 * g];
                bfrag b1 = *(const bfrag*)&Vh[32 + r16][32 + 8 * g];
                bfrag c0 = *(const bfrag*)&Vl[32 + r16][8 * g];
                bfrag c1 = *(const bfrag*)&Vl[32 + r16][32 + 8 * g];
                oA2 = __builtin_amdgcn_mfma_f32_16x16x32_bf16(ph0, b0, oA2, 0, 0, 0);
                oA2 = __builtin_amdgcn_mfma_f32_16x16x32_bf16(pl0, b0, oA2, 0, 0, 0);
                oA2 = __builtin_amdgcn_mfma_f32_16x16x32_bf16(ph0, c0, oA2, 0, 0, 0);
                oA2 = __builtin_amdgcn_mfma_f32_16x16x32_bf16(ph1, b1, oA2, 0, 0, 0);
                oA2 = __builtin_amdgcn_mfma_f32_16x16x32_bf16(pl1, b1, oA2, 0, 0, 0);
                oA2 = __builtin_amdgcn_mfma_f32_16x16x32_bf16(ph1, c1, oA2, 0, 0, 0);
            }
            {
                bfrag b0 = *(const bfrag*)&Vh[48 + r16][8 * g];
                bfrag b1 = *(const bfrag*)&Vh[48 + r16][32 + 8 * g];
                bfrag c0 = *(const bfrag*)&Vl[48 + r16][8 * g];
                bfrag c1 = *(const bfrag*)&Vl[48 + r16][32 + 8 * g];
                oA3 = __builtin_amdgcn_mfma_f32_16x16x32_bf16(ph0, b0, oA3, 0, 0, 0);
                oA3 = __builtin_amdgcn_mfma_f32_16x16x32_bf16(pl0, b0, oA3, 0, 0, 0);
                oA3 = __builtin_amdgcn_mfma_f32_16x16x32_bf16(ph0, c0, oA3, 0, 0, 0);
                oA3 = __builtin_amdgcn_mfma_f32_16x16x32_bf16(ph1, b1, oA3, 0, 0, 0);
                oA3 = __builtin_amdgcn_mfma_f32_16x16x32_bf16(pl1, b1, oA3, 0, 0, 0);
                oA3 = __builtin_amdgcn_mfma_f32_16x16x32_bf16(ph1, c1, oA3, 0, 0, 0);
            }
        }
        __builtin_amdgcn_wave_barrier();   // PV_A P-reads done (own wave)

        // ---- P_B -> LDS (same wave-private band); PV_B ----
        Pu[pr + 0][r16]      = packhl(paB0);
        Pu[pr + 1][r16]      = packhl(paB1);
        Pu[pr + 2][r16]      = packhl(paB2);
        Pu[pr + 3][r16]      = packhl(paB3);
        Pu[pr + 0][16 + r16] = packhl(pbB0);
        Pu[pr + 1][16 + r16] = packhl(pbB1);
        Pu[pr + 2][16 + r16] = packhl(pbB2);
        Pu[pr + 3][16 + r16] = packhl(pbB3);
        Pu[pr + 0][32 + r16] = packhl(pcB0);
        Pu[pr + 1][32 + r16] = packhl(pcB1);
        Pu[pr + 2][32 + r16] = packhl(pcB2);
        Pu[pr + 3][32 + r16] = packhl(pcB3);
        Pu[pr + 0][48 + r16] = packhl(pdB0);
        Pu[pr + 1][48 + r16] = packhl(pdB1);
        Pu[pr + 2][48 + r16] = packhl(pdB2);
        Pu[pr + 3][48 + r16] = packhl(pdB3);
        __builtin_amdgcn_wave_barrier();
        {
            const uint4 pu0 = *(const uint4*)&Pu[prow][8 * g];
            const uint4 pu1 = *(const uint4*)&Pu[prow][8 * g + 4];
            const uint4 pu2 = *(const uint4*)&Pu[prow][32 + 8 * g];
            const uint4 pu3 = *(const uint4*)&Pu[prow][32 + 8 * g + 4];
            uint4 uh0, ul0, uh1, ul1;
            uh0.x = (pu0.x & 0xffffu) | (pu0.y << 16);
            uh0.y = (pu0.z & 0xffffu) | (pu0.w << 16);
            uh0.z = (pu1.x & 0xffffu) | (pu1.y << 16);
            uh0.w = (pu1.z & 0xffffu) | (pu1.w << 16);
            ul0.x = (pu0.x >> 16) | (pu0.y & 0xffff0000u);
            ul0.y = (pu0.z >> 16) | (pu0.w & 0xffff0000u);
            ul0.z = (pu1.x >> 16) | (pu1.y & 0xffff0000u);
            ul0.w = (pu1.z >> 16) | (pu1.w & 0xffff0000u);
            uh1.x = (pu2.x & 0xffffu) | (pu2.y << 16);
            uh1.y = (pu2.z & 0xffffu) | (pu2.w << 16);
            uh1.z = (pu3.x & 0xffffu) | (pu3.y << 16);
            uh1.w = (pu3.z & 0xffffu) | (pu3.w << 16);
            ul1.x = (pu2.x >> 16) | (pu2.y & 0xffff0000u);
            ul1.y = (pu2.z >> 16) | (pu2.w & 0xffff0000u);
            ul1.z = (pu3.x >> 16) | (pu3.y & 0xffff0000u);
            ul1.w = (pu3.z >> 16) | (pu3.w & 0xffff0000u);
            const bfrag ph0 = *(const bfrag*)&uh0;
            const bfrag pl0 = *(const bfrag*)&ul0;
            const bfrag ph1 = *(const bfrag*)&uh1;
            const bfrag pl1 = *(const bfrag*)&ul1;
            {
                bfrag b0 = *(const bfrag*)&Vh[r16][8 * g];
                bfrag b1 = *(const bfrag*)&Vh[r16][32 + 8 * g];
                bfrag c0 = *(const bfrag*)&Vl[r16][8 * g];
                bfrag c1 = *(const bfrag*)&Vl[r16][32 + 8 * g];
                oB0 = __builtin_amdgcn_mfma_f32_16x16x32_bf16(ph0, b0, oB0, 0, 0, 0);
                oB0 = __builtin_amdgcn_mfma_f32_16x16x32_bf16(pl0, b0, oB0, 0, 0, 0);
                oB0 = __builtin_amdgcn_mfma_f32_16x16x32_bf16(ph0, c0, oB0, 0, 0, 0);
                oB0 = __builtin_amdgcn_mfma_f32_16x16x32_bf16(ph1, b1, oB0, 0, 0, 0);
                oB0 = __builtin_amdgcn_mfma_f32_16x16x32_bf16(pl1, b1, oB0, 0, 0, 0);
                oB0 = __builtin_amdgcn_mfma_f32_16x16x32_bf16(ph1, c1, oB0, 0, 0, 0);
            }
            {
                bfrag b0 = *(const bfrag*)&Vh[16 + r16][8 * g];
                bfrag b1 = *(const bfrag*)&Vh[16 + r16][32 + 8 * g];
                bfrag c0 = *(const bfrag*)&Vl[16 + r16][8 * g];
                bfrag c1 = *(const bfrag*)&Vl[16 + r16][32 + 8 * g];
                oB1 = __builtin_amdgcn_mfma_f32_16x16x32_bf16(ph0, b0, oB1, 0, 0, 0);
                oB1 = __builtin_amdgcn_mfma_f32_16x16x32_bf16(pl0, b0, oB1, 0, 0, 0);
                oB1 = __builtin_amdgcn_mfma_f32_16x16x32_bf16(ph0, c0, oB1, 0, 0, 0);
                oB1 = __builtin_amdgcn_mfma_f32_16x16x32_bf16(ph1, b1, oB1, 0, 0, 0);
                oB1 = __builtin_amdgcn_mfma_f32_16x16x32_bf16(pl1, b1, oB1, 0, 0, 0);
                oB1 = __builtin_amdgcn_mfma_f32_16x16x32_bf16(ph1, c1, oB1, 0, 0, 0);
            }
            {
                bfrag b0 = *(const bfrag*)&Vh[32 + r16][8 * g];
                bfrag b1 = *(const bfrag*)&Vh[32 + r16][32 + 8 * g];
                bfrag c0 = *(const bfrag*)&Vl[32 + r16][8 * g];
                bfrag c1 = *(const bfrag*)&Vl[32 + r16][32 + 8 * g];
                oB2 = __builtin_amdgcn_mfma_f32_16x16x32_bf16(ph0, b0, oB2, 0, 0, 0);
                oB2 = __builtin_amdgcn_mfma_f32_16x16x32_bf16(pl0, b0, oB2, 0, 0, 0);
                oB2 = __builtin_amdgcn_mfma_f32_16x16x32_bf16(ph0, c0, oB2, 0, 0, 0);
                oB2 = __builtin_amdgcn_mfma_f32_16x16x32_bf16(ph1, b1, oB2, 0, 0, 0);
                oB2 = __builtin_amdgcn_mfma_f32_16x16x32_bf16(pl1, b1, oB2, 0, 0, 0);
                oB2 = __builtin_amdgcn_mfma_f32_16x16x32_bf16(ph1, c1, oB2, 0, 0, 0);
            }
            {
                bfrag b0 = *(const bfrag*)&Vh[48 + r16][8 * g];
                bfrag b1 = *(const bfrag*)&Vh[48 + r16][32 + 8 * g];
                bfrag c0 = *(const bfrag*)&Vl[48 + r16][8 * g];
                bfrag c1 = *(const bfrag*)&Vl[48 + r16][32 + 8 * g];
                oB3 = __builtin_amdgcn_mfma_f32_16x16x32_bf16(ph0, b0, oB3, 0, 0, 0);
                oB3 = __builtin_amdgcn_mfma_f32_16x16x32_bf16(pl0, b0, oB3, 0, 0, 0);
                oB3 = __builtin_amdgcn_mfma_f32_16x16x32_bf16(ph0, c0, oB3, 0, 0, 0);
                oB3 = __builtin_amdgcn_mfma_f32_16x16x32_bf16(ph1, b1, oB3, 0, 0, 0);
                oB3 = __builtin_amdgcn_mfma_f32_16x16x32_bf16(pl1, b1, oB3, 0, 0, 0);
                oB3 = __builtin_amdgcn_mfma_f32_16x16x32_bf16(ph1, c1, oB3, 0, 0, 0);
            }
        }
    }

    // ---- epilogue A ----
    {
        const float zi0 = 1.0f / zrA0, zi1 = 1.0f / zrA1;
        const float zi2 = 1.0f / zrA2, zi3 = 1.0f / zrA3;
        const size_t base = ((size_t)bh * N_ + q0 + 16 * w + 4 * g) * HD_ + r16;
        float* lrow = Lout + base;
        const float v00 = oA0.x * zi0, v01 = oA1.x * zi0, v02 = oA2.x * zi0, v03 = oA3.x * zi0;
        const float v10 = oA0.y * zi1, v11 = oA1.y * zi1, v12 = oA2.y * zi1, v13 = oA3.y * zi1;
        const float v20 = oA0.z * zi2, v21 = oA1.z * zi2, v22 = oA2.z * zi2, v23 = oA3.z * zi2;
        const float v30 = oA0.w * zi3, v31 = oA1.w * zi3, v32 = oA2.w * zi3, v33 = oA3.w * zi3;
        lrow[0 * HD_ + 0] = v00; lrow[0 * HD_ + 16] = v01; lrow[0 * HD_ + 32] = v02; lrow[0 * HD_ + 48] = v03;
        lrow[1 * HD_ + 0] = v10; lrow[1 * HD_ + 16] = v11; lrow[1 * HD_ + 32] = v12; lrow[1 * HD_ + 48] = v13;
        lrow[2 * HD_ + 0] = v20; lrow[2 * HD_ + 16] = v21; lrow[2 * HD_ + 32] = v22; lrow[2 * HD_ + 48] = v23;
        lrow[3 * HD_ + 0] = v30; lrow[3 * HD_ + 16] = v31; lrow[3 * HD_ + 32] = v32; lrow[3 * HD_ + 48] = v33;
        if (wsplit) {
            Lbh[base + 0 * HD_ + 0] = bfhi(v00); Lbl[base + 0 * HD_ + 0] = bflo(v00);
            Lbh[base + 0 * HD_ + 16] = bfhi(v01); Lbl[base + 0 * HD_ + 16] = bflo(v01);
            Lbh[base + 0 * HD_ + 32] = bfhi(v02); Lbl[base + 0 * HD_ + 32] = bflo(v02);
            Lbh[base + 0 * HD_ + 48] = bfhi(v03); Lbl[base + 0 * HD_ + 48] = bflo(v03);
            Lbh[base + 1 * HD_ + 0] = bfhi(v10); Lbl[base + 1 * HD_ + 0] = bflo(v10);
            Lbh[base + 1 * HD_ + 16] = bfhi(v11); Lbl[base + 1 * HD_ + 16] = bflo(v11);
            Lbh[base + 1 * HD_ + 32] = bfhi(v12); Lbl[base + 1 * HD_ + 32] = bflo(v12);
            Lbh[base + 1 * HD_ + 48] = bfhi(v13); Lbl[base + 1 * HD_ + 48] = bflo(v13);
            Lbh[base + 2 * HD_ + 0] = bfhi(v20); Lbl[base + 2 * HD_ + 0] = bflo(v20);
            Lbh[base + 2 * HD_ + 16] = bfhi(v21); Lbl[base + 2 * HD_ + 16] = bflo(v21);
            Lbh[base + 2 * HD_ + 32] = bfhi(v22); Lbl[base + 2 * HD_ + 32] = bflo(v22);
            Lbh[base + 2 * HD_ + 48] = bfhi(v23); Lbl[base + 2 * HD_ + 48] = bflo(v23);
            Lbh[base + 3 * HD_ + 0] = bfhi(v30); Lbl[base + 3 * HD_ + 0] = bflo(v30);
            Lbh[base + 3 * HD_ + 16] = bfhi(v31); Lbl[base + 3 * HD_ + 16] = bflo(v31);
            Lbh[base + 3 * HD_ + 32] = bfhi(v32); Lbl[base + 3 * HD_ + 32] = bflo(v32);
            Lbh[base + 3 * HD_ + 48] = bfhi(v33); Lbl[base + 3 * HD_ + 48] = bflo(v33);
        }
        if (r16 == 0) {
            const size_t rb = (size_t)bh * N_ + q0 + 16 * w + 4 * g;
            Mrow[rb + 0] = mrA0; Mrow[rb + 1] = mrA1;
            Mrow[rb + 2] = mrA2; Mrow[rb + 3] = mrA3;
            Zrow[rb + 0] = zrA0; Zrow[rb + 1] = zrA1;
            Zrow[rb + 2] = zrA2; Zrow[rb + 3] = zrA3;
        }
    }
    // ---- epilogue B ----
    {
        const float zi0 = 1.0f / zrB0, zi1 = 1.0f / zrB1;
        const float zi2 = 1.0f / zrB2, zi3 = 1.0f / zrB3;
        const size_t base = ((size_t)bh * N_ + q0 + 64 + 16 * w + 4 * g) * HD_ + r16;
        float* lrow = Lout + base;
        const float v00 = oB0.x * zi0, v01 = oB1.x * zi0, v02 = oB2.x * zi0, v03 = oB3.x * zi0;
        const float v10 = oB0.y * zi1, v11 = oB1.y * zi1, v12 = oB2.y * zi1, v13 = oB3.y * zi1;
        const float v20 = oB0.z * zi2, v21 = oB1.z * zi2, v22 = oB2.z * zi2, v23 = oB3.z * zi2;
        const float v30 = oB0.w * zi3, v31 = oB1.w * zi3, v32 = oB2.w * zi3, v33 = oB3.w * zi3;
        lrow[0 * HD_ + 0] = v00; lrow[0 * HD_ + 16] = v01; lrow[0 * HD_ + 32] = v02; lrow[0 * HD_ + 48] = v03;
        lrow[1 * HD_ + 0] = v10; lrow[1 * HD_ + 16] = v11; lrow[1 * HD_ + 32] = v12; lrow[1 * HD_ + 48] = v13;
        lrow[2 * HD_ + 0] = v20; lrow[2 * HD_ + 16] = v21; lrow[2 * HD_ + 32] = v22; lrow[2 * HD_ + 48] = v23;
        lrow[3 * HD_ + 0] = v30; lrow[3 * HD_ + 16] = v31; lrow[3 * HD_ + 32] = v32; lrow[3 * HD_ + 48] = v33;
        if (wsplit) {
            Lbh[base + 0 * HD_ + 0] = bfhi(v00); Lbl[base + 0 * HD_ + 0] = bflo(v00);
            Lbh[base + 0 * HD_ + 16] = bfhi(v01); Lbl[base + 0 * HD_ + 16] = bflo(v01);
            Lbh[base + 0 * HD_ + 32] = bfhi(v02); Lbl[base + 0 * HD_ + 32] = bflo(v02);
            Lbh[base + 0 * HD_ + 48] = bfhi(v03); Lbl[base + 0 * HD_ + 48] = bflo(v03);
            Lbh[base + 1 * HD_ + 0] = bfhi(v10); Lbl[base + 1 * HD_ + 0] = bflo(v10);
            Lbh[base + 1 * HD_ + 16] = bfhi(v11); Lbl[base + 1 * HD_ + 16] = bflo(v11);
            Lbh[base + 1 * HD_ + 32] = bfhi(v12); Lbl[base + 1 * HD_ + 32] = bflo(v12);
            Lbh[base + 1 * HD_ + 48] = bfhi(v13); Lbl[base + 1 * HD_ + 48] = bflo(v13);
            Lbh[base + 2 * HD_ + 0] = bfhi(v20); Lbl[base + 2 * HD_ + 0] = bflo(v20);
            Lbh[base + 2 * HD_ + 16] = bfhi(v21); Lbl[base + 2 * HD_ + 16] = bflo(v21);
            Lbh[base + 2 * HD_ + 32] = bfhi(v22); Lbl[base + 2 * HD_ + 32] = bflo(v22);
            Lbh[base + 2 * HD_ + 48] = bfhi(v23); Lbl[base + 2 * HD_ + 48] = bflo(v23);
            Lbh[base + 3 * HD_ + 0] = bfhi(v30); Lbl[base + 3 * HD_ + 0] = bflo(v30);
            Lbh[base + 3 * HD_ + 16] = bfhi(v31); Lbl[base + 3 * HD_ + 16] = bflo(v31);
            Lbh[base + 3 * HD_ + 32] = bfhi(v32); Lbl[base + 3 * HD_ + 32] = bflo(v32);
            Lbh[base + 3 * HD_ + 48] = bfhi(v33); Lbl[base + 3 * HD_ + 48] = bflo(v33);
        }
        if (r16 == 0) {
            const size_t rb = (size_t)bh * N_ + q0 + 64 + 16 * w + 4 * g;
            Mrow[rb + 0] = mrB0; Mrow[rb + 1] = mrB1;
            Mrow[rb + 2] = mrB2; Mrow[rb + 3] = mrB3;
            Zrow[rb + 0] = zrB0; Zrow[rb + 1] = zrB1;
            Zrow[rb + 2] = zrB2; Zrow[rb + 3] = zrB3;
        }
    }
}

// ---------------------------------------------------------------------------
// K6 attn_out_mfma: K staged from PERMUTED global rows so lane's 4 outputs
// are columns 4*r16..4*r16+3 -> ONE float4 store each (was 4 scalar).
// Per-element math bit-identical.  grid (16, 96) x 256.
// ---------------------------------------------------------------------------
__global__ __launch_bounds__(256)
void attn_out_mfma(const float* __restrict__ K2v, const float* __restrict__ Mrow,
                   const float* __restrict__ Zrow, float* __restrict__ A)
{
    __shared__ short Kh[64][72];
    __shared__ short Kl[64][72];

    const int tid  = threadIdx.x;
    const int lane = tid & 63;
    const int w    = tid >> 6;
    const int g    = lane >> 4;
    const int r16  = lane & 15;
    const int bh   = blockIdx.y;
    const int q0   = blockIdx.x * 64;
    const float* k2b = K2v + (size_t)bh * N_ * HD_;

    const int qrow = q0 + 16 * w + r16;
    const float4 f0 = *(const float4*)(k2b + (size_t)qrow * HD_ + 8 * g);
    const float4 f1 = *(const float4*)(k2b + (size_t)qrow * HD_ + 8 * g + 4);
    const float4 f2 = *(const float4*)(k2b + (size_t)qrow * HD_ + 32 + 8 * g);
    const float4 f3 = *(const float4*)(k2b + (size_t)qrow * HD_ + 32 + 8 * g + 4);
    const bfrag qh0 = pack_hi(f0, f1), ql0 = pack_lo(f0, f1);
    const bfrag qh1 = pack_hi(f2, f3), ql1 = pack_lo(f2, f3);

    const size_t mb = (size_t)bh * N_ + q0 + 16 * w + 4 * g;
    const float mi0 = Mrow[mb + 0], mi1 = Mrow[mb + 1];
    const float mi2 = Mrow[mb + 2], mi3 = Mrow[mb + 3];
    const float zi0 = 1.0f / Zrow[mb + 0], zi1 = 1.0f / Zrow[mb + 1];
    const float zi2 = 1.0f / Zrow[mb + 2], zi3 = 1.0f / Zrow[mb + 3];

    const int i0 = tid * 8,        r0 = i0 >> 6, cc0 = i0 & 63;
    const int i1 = 2048 + tid * 8, r1 = i1 >> 6, cc1 = i1 & 63;
    // permuted global K rows: LDS slot r holds k-col 4*(r&15)+(r>>4)
    const int kr0 = 4 * (r0 & 15) + (r0 >> 4);
    const int kr1 = kr0 + 2;

    float4 a0 = *(const float4*)(k2b + (size_t)kr0 * HD_ + cc0);
    float4 a1 = *(const float4*)(k2b + (size_t)kr0 * HD_ + cc0 + 4);
    float4 b0v = *(const float4*)(k2b + (size_t)kr1 * HD_ + cc1);
    float4 b1v = *(const float4*)(k2b + (size_t)kr1 * HD_ + cc1 + 4);

    for (int kt = 0; kt < 16; ++kt) {
        __syncthreads();
        *(bfrag*)&Kh[r0][cc0] = pack_hi(a0, a1);
        *(bfrag*)&Kl[r0][cc0] = pack_lo(a0, a1);
        *(bfrag*)&Kh[r1][cc1] = pack_hi(b0v, b1v);
        *(bfrag*)&Kl[r1][cc1] = pack_lo(b0v, b1v);
        if (kt + 1 < 16) {
            const size_t gn = (size_t)(kt + 1) * 64;
            a0  = *(const float4*)(k2b + (gn + kr0) * HD_ + cc0);
            a1  = *(const float4*)(k2b + (gn + kr0) * HD_ + cc0 + 4);
            b0v = *(const float4*)(k2b + (gn + kr1) * HD_ + cc1);
            b1v = *(const float4*)(k2b + (gn + kr1) * HD_ + cc1 + 4);
        }
        __syncthreads();

        facc s0 = {0.f, 0.f, 0.f, 0.f};
        facc s1 = {0.f, 0.f, 0.f, 0.f};
        facc s2 = {0.f, 0.f, 0.f, 0.f};
        facc s3 = {0.f, 0.f, 0.f, 0.f};
        {
            bfrag b0 = *(const bfrag*)&Kh[r16][8 * g];
            bfrag b1 = *(const bfrag*)&Kh[r16][32 + 8 * g];
            bfrag c0 = *(const bfrag*)&Kl[r16][8 * g];
            bfrag c1 = *(const bfrag*)&Kl[r16][32 + 8 * g];
            s0 = __builtin_amdgcn_mfma_f32_16x16x32_bf16(qh0, b0, s0, 0, 0, 0);
            s0 = __builtin_amdgcn_mfma_f32_16x16x32_bf16(ql0, b0, s0, 0, 0, 0);
            s0 = __builtin_amdgcn_mfma_f32_16x16x32_bf16(qh0, c0, s0, 0, 0, 0);
            s0 = __builtin_amdgcn_mfma_f32_16x16x32_bf16(qh1, b1, s0, 0, 0, 0);
            s0 = __builtin_amdgcn_mfma_f32_16x16x32_bf16(ql1, b1, s0, 0, 0, 0);
            s0 = __builtin_amdgcn_mfma_f32_16x16x32_bf16(qh1, c1, s0, 0, 0, 0);
        }
        {
            bfrag b0 = *(const bfrag*)&Kh[16 + r16][8 * g];
            bfrag b1 = *(const bfrag*)&Kh[16 + r16][32 + 8 * g];
            bfrag c0 = *(const bfrag*)&Kl[16 + r16][8 * g];
            bfrag c1 = *(const bfrag*)&Kl[16 + r16][32 + 8 * g];
            s1 = __builtin_amdgcn_mfma_f32_16x16x32_bf16(qh0, b0, s1, 0, 0, 0);
            s1 = __builtin_amdgcn_mfma_f32_16x16x32_bf16(ql0, b0, s1, 0, 0, 0);
            s1 = __builtin_amdgcn_mfma_f32_16x16x32_bf16(qh0, c0, s1, 0, 0, 0);
            s1 = __builtin_amdgcn_mfma_f32_16x16x32_bf16(qh1, b1, s1, 0, 0, 0);
            s1 = __builtin_amdgcn_mfma_f32_16x16x32_bf16(ql1, b1, s1, 0, 0, 0);
            s1 = __builtin_amdgcn_mfma_f32_16x16x32_bf16(qh1, c1, s1, 0, 0, 0);
        }
        {
            bfrag b0 = *(const bfrag*)&Kh[32 + r16][8 * g];
            bfrag b1 = *(const bfrag*)&Kh[32 + r16][32 + 8 * g];
            bfrag c0 = *(const bfrag*)&Kl[32 + r16][8 * g];
            bfrag c1 = *(const bfrag*)&Kl[32 + r16][32 + 8 * g];
            s2 = __builtin_amdgcn_mfma_f32_16x16x32_bf16(qh0, b0, s2, 0, 0, 0);
            s2 = __builtin_amdgcn_mfma_f32_16x16x32_bf16(ql0, b0, s2, 0, 0, 0);
            s2 = __builtin_amdgcn_mfma_f32_16x16x32_bf16(qh0, c0, s2, 0, 0, 0);
            s2 = __builtin_amdgcn_mfma_f32_16x16x32_bf16(qh1, b1, s2, 0, 0, 0);
            s2 = __builtin_amdgcn_mfma_f32_16x16x32_bf16(ql1, b1, s2, 0, 0, 0);
            s2 = __builtin_amdgcn_mfma_f32_16x16x32_bf16(qh1, c1, s2, 0, 0, 0);
        }
        {
            bfrag b0 = *(const bfrag*)&Kh[48 + r16][8 * g];
            bfrag b1 = *(const bfrag*)&Kh[48 + r16][32 + 8 * g];
            bfrag c0 = *(const bfrag*)&Kl[48 + r16][8 * g];
            bfrag c1 = *(const bfrag*)&Kl[48 + r16][32 + 8 * g];
            s3 = __builtin_amdgcn_mfma_f32_16x16x32_bf16(qh0, b0, s3, 0, 0, 0);
            s3 = __builtin_amdgcn_mfma_f32_16x16x32_bf16(ql0, b0, s3, 0, 0, 0);
            s3 = __builtin_amdgcn_mfma_f32_16x16x32_bf16(qh0, c0, s3, 0, 0, 0);
            s3 = __builtin_amdgcn_mfma_f32_16x16x32_bf16(qh1, b1, s3, 0, 0, 0);
            s3 = __builtin_amdgcn_mfma_f32_16x16x32_bf16(ql1, b1, s3, 0, 0, 0);
            s3 = __builtin_amdgcn_mfma_f32_16x16x32_bf16(qh1, c1, s3, 0, 0, 0);
        }

        s0 = s0 * SCALE_;  s1 = s1 * SCALE_;  s2 = s2 * SCALE_;  s3 = s3 * SCALE_;

        // lane covers columns kt*64 + 4*r16 + {0,1,2,3} -> float4 stores
        float* ap = A + mb * N_ + kt * 64 + 4 * r16;
        float4 v;
        v.x = __expf(s0.x - mi0) * zi0; v.y = __expf(s1.x - mi0) * zi0;
        v.z = __expf(s2.x - mi0) * zi0; v.w = __expf(s3.x - mi0) * zi0;
        *(float4*)(ap + 0 * N_) = v;
        v.x = __expf(s0.y - mi1) * zi1; v.y = __expf(s1.y - mi1) * zi1;
        v.z = __expf(s2.y - mi1) * zi1; v.w = __expf(s3.y - mi1) * zi1;
        *(float4*)(ap + 1 * N_) = v;
        v.x = __expf(s0.z - mi2) * zi2; v.y = __expf(s1.z - mi2) * zi2;
        v.z = __expf(s2.z - mi2) * zi2; v.w = __expf(s3.z - mi2) * zi2;
        *(float4*)(ap + 2 * N_) = v;
        v.x = __expf(s0.w - mi3) * zi3; v.y = __expf(s1.w - mi3) * zi3;
        v.z = __expf(s2.w - mi3) * zi3; v.w = __expf(s3.w - mi3) * zi3;
        *(float4*)(ap + 3 * N_) = v;
    }
}

// ---------------------------------------------------------------------------
// d_out FLOAT32: out = d_out[0..6291456), attn = d_out[6291456..).
// ws (floats): kb@0, vb@SZ, lb@2SZ, yb@3SZ, k2b@4SZ, mu@5SZ(128), rowm, rowz.
// bf16 scratch lives in the attn output region; proj runs BEFORE attn_out.
// ---------------------------------------------------------------------------
extern "C" void kernel_launch(void* const* d_in, const int* in_sizes, int n_in,
                              void* d_out, int out_size, void* d_ws, size_t ws_size,
                              hipStream_t stream)
{
    (void)in_sizes; (void)n_in; (void)out_size; (void)ws_size;

    const float* x  = (const float*)d_in[0];
    const float* Wq = (const float*)d_in[1];
    const float* bq = (const float*)d_in[2];
    const float* Wp = (const float*)d_in[3];
    const float* bp = (const float*)d_in[4];

    float* out_f  = (float*)d_out;
    float* attn_f = out_f + (size_t)B_ * N_ * C_;

    const size_t SZ = (size_t)BH_ * N_ * HD_;   // 6,291,456
    float* ws   = (float*)d_ws;
    float* kb   = ws;
    float* vb   = ws + SZ;
    float* lb   = ws + 2 * SZ;
    float* yb   = ws + 3 * SZ;
    float* k2b  = ws + 4 * SZ;
    float* mu   = ws + 5 * SZ;
    float* rowm = mu + 128;
    float* rowz = rowm + (size_t)BH_ * N_;

    unsigned short* k2h  = (unsigned short*)attn_f;
    unsigned short* k2l  = k2h + SZ;
    unsigned short* vth  = k2h + 2 * SZ;
    unsigned short* vtl  = k2h + 3 * SZ;
    unsigned short* xh   = k2h + 4 * SZ;
    unsigned short* xl   = k2h + 5 * SZ;
    unsigned short* wqth = k2h + 6 * SZ;
    unsigned short* wqtl = k2h + 7 * SZ;
    unsigned short* wpth = k2h + 8 * SZ;
    unsigned short* wptl = k2h + 9 * SZ;
    unsigned short* lbh  = k2h + 10 * SZ;
    unsigned short* lbl  = k2h + 11 * SZ;

    split_flat<<<3072, 256, 0, stream>>>(x, xh, xl);
    split_wt<<<dim3(24, 12), 256, 0, stream>>>(Wq, 2 * C_, wqth, wqtl);
    split_wt<<<dim3(12, 12), 256, 0, stream>>>(Wp, C_, wpth, wptl);

    qkv_mfma<<<dim3(24, 128), 256, 0, stream>>>(xh, xl, wqth, wqtl, bq, kb, vb);
    vt_split<<<dim3(16, 96), 256, 0, stream>>>(vb, vth, vtl);
    musum<<<96, 256, 0, stream>>>(kb, mu);

    for (int it = 0; it <= NIT_; ++it) {
        ew_fused<<<24576, 256, 0, stream>>>(kb, lb, yb, mu, k2b, k2h, k2l,
                                            it > 0 ? 1 : 0);
        flash<<<dim3(8, 96), 256, 0, stream>>>(k2h, k2l, vth, vtl, lb, rowm, rowz,
                                               lbh, lbl, it == NIT_ ? 1 : 0);
    }

    proj_mfma<<<dim3(12, 128), 256, 0, stream>>>(lbh, lbl, wpth, wptl, bp, out_f);
    attn_out_mfma<<<dim3(16, 96), 256, 0, stream>>>(k2b, rowm, rowz, attn_f);
}